// Round 15
// baseline (413.101 us; speedup 1.0000x reference)
//
#include <hip/hip_runtime.h>

// ============================================================================
// Swin V2 block, round 15 = R13 GEMM template everywhere (persistA reverted:
// R14 cut FETCH 3.5x but slowed 86->95 - GEMMs are NOT HBM-bound; structure-
// bound) + LN+residual FUSED into proj and fc2 epilogues on the 512-thread /
// 35%-occupancy structure (old gemm_ln failed at 9% occupancy; occupancy was
// the disease, not LN math). Removes ln_resid<0>, ln_resid<1>, and fc2's
// d_out fp32 round-trip.
// MFMA layout (HW-verified): A row=lane%16, k=4*(lane/16)+{0..3}(+16);
// C/D col=lane%16, row=4*(lane/16)+reg. LDS perm col=8*((k%16)/4)+4*(k/16)+k%4.
// ============================================================================

typedef unsigned short ushort_t;
using f32x4  = __attribute__((ext_vector_type(4))) float;
using short8 = __attribute__((ext_vector_type(8))) short;
union LD16 { short8 v; ushort4 h[2]; };

__device__ __forceinline__ ushort_t f2bf(float f) {
  union { float f; unsigned u; } v; v.f = f;
  unsigned r = v.u + 0x7fffu + ((v.u >> 16) & 1u);
  return (ushort_t)(r >> 16);
}
__device__ __forceinline__ float bf2f(ushort_t u) {
  union { unsigned u; float f; } v; v.u = ((unsigned)u) << 16;
  return v.f;
}

// windowed-token index m -> image row index (same map for gather and scatter)
__device__ __forceinline__ int img_pos(int m) {
  int win = m / 49, n = m - win * 49;
  int b = win >> 6, wi = win & 63;
  int nd = n / 7, nm = n - nd * 7;
  int hs = (wi >> 3) * 7 + nd;
  int ws = (wi & 7) * 7 + nm;
  int h = hs + 3; if (h >= 56) h -= 56;
  int w = ws + 3; if (w >= 56) w -= 56;
  return b * 3136 + h * 56 + w;
}

__device__ __forceinline__ int region3(int a) { return a < 49 ? 0 : (a < 53 ? 1 : 2); }

// ---------------------------------------------------------------------------
__global__ void cvt_kernel(const float* __restrict__ in, ushort_t* __restrict__ out, int n) {
  int i = blockIdx.x * 256 + threadIdx.x;
  if (i < n) out[i] = f2bf(in[i]);
}

// gather shifted-window rows + convert to bf16: xw[m][c] = bf16(x[img_pos(m)][c])
__global__ __launch_bounds__(256) void gather_cvt_kernel(
    const float* __restrict__ x, ushort_t* __restrict__ xw) {
  int i8 = blockIdx.x * 256 + threadIdx.x;      // 100352*24 tasks of 8 elems
  int m = i8 / 24, c8 = (i8 - m * 24) * 8;
  const float* p = x + (size_t)img_pos(m) * 192 + c8;
  float4 a = *(const float4*)p, b = *(const float4*)(p + 4);
  ushort_t* q = xw + (size_t)m * 192 + c8;
  *(ushort4*)q       = make_ushort4(f2bf(a.x), f2bf(a.y), f2bf(a.z), f2bf(a.w));
  *(ushort4*)(q + 4) = make_ushort4(f2bf(b.x), f2bf(b.y), f2bf(b.z), f2bf(b.w));
}

// ---------------------------------------------------------------------------
// CPB: tab_s[head][e] = 16*sigmoid( relu(REL_TABLE[e] @ w1.T + b1) @ w2.T )
__global__ __launch_bounds__(256) void cpb_kernel(
    const float* __restrict__ w1, const float* __restrict__ b1,
    const float* __restrict__ w2, float* __restrict__ tab_s) {
  int e = blockIdx.x;            // 0..168
  int t = threadIdx.x;           // 0..255
  int i = e / 13, j = e - 13 * (e / 13);
  auto cval = [](int a) -> float {
    float r = (a - 6) * (8.0f / 6.0f);
    float v = log2f(fabsf(r) + 1.f) * (1.f / 3.f);
    return r < 0.f ? -v : v;
  };
  float ci = cval(i), cj = cval(j);
  float h = fmaxf(ci * w1[2 * t] + cj * w1[2 * t + 1] + b1[t], 0.f);
  __shared__ float red[256];
  for (int head = 0; head < 6; ++head) {
    red[t] = h * w2[head * 256 + t];
    __syncthreads();
    for (int st = 128; st > 0; st >>= 1) {
      if (t < st) red[t] += red[t + st];
      __syncthreads();
    }
    if (t == 0) tab_s[head * 169 + e] = 16.f / (1.f + __expf(-red[0]));
    __syncthreads();
  }
}

// ---------------------------------------------------------------------------
// GEMM, tile 128(M) x 192(N), K-step 32, 512 threads = 8 waves (4x2 of
// 32x96), acc[2][6], T14 reg prefetch on t<256. (R13 proven template)
// MODE 0: qkv  MODE 1: fc1(silu)
template<int KTOT, int MODE>
__global__ __launch_bounds__(512, 4) void gemm_n192(
    const ushort_t* __restrict__ Ab, const ushort_t* __restrict__ W,
    const float* __restrict__ b0, const float* __restrict__ b1,
    ushort_t* __restrict__ out, int NTOT) {
  __shared__ ushort_t Al[128][40];
  __shared__ ushort_t Bl[192][40];
  int t = threadIdx.x;
  int m0 = blockIdx.x * 128, n0 = blockIdx.y * 192;
  int lane = t & 63, wid = t >> 6;
  int wm = wid >> 1, wn = wid & 1;
  int lr = lane & 15, lg = lane >> 4;

  bool stager = (t < 256);
  int arow = (t & 255) >> 1, akoff = (t & 1) << 4;
  const ushort_t* Arowp = Ab + (size_t)(m0 + arow) * KTOT + akoff;
  int colA = akoff ? 4 : 0;
  int bn = (t & 255) >> 2, cB = t & 3;
  const ushort_t* Browp  = W + (size_t)(n0 + bn) * KTOT + (cB << 3);
  const ushort_t* Browp2 = W + (size_t)(n0 + 64 + bn) * KTOT + (cB << 3);
  const ushort_t* Browp3 = W + (size_t)(n0 + 128 + bn) * KTOT + (cB << 3);
  int colB = ((cB & 1) << 4) | ((cB >> 1) << 2);   // {0,16,4,20}

  f32x4 acc[2][6];
#pragma unroll
  for (int a = 0; a < 2; ++a)
#pragma unroll
    for (int b = 0; b < 6; ++b) acc[a][b] = (f32x4){0.f, 0.f, 0.f, 0.f};

  LD16 A01, A23, B0, B1, B2;
  auto LOADREGS = [&](int kt) {
    A01.v = *(const short8*)(Arowp + kt);
    A23.v = *(const short8*)(Arowp + kt + 8);
    B0.v  = *(const short8*)(Browp + kt);
    B1.v  = *(const short8*)(Browp2 + kt);
    B2.v  = *(const short8*)(Browp3 + kt);
  };

  const int NT = KTOT / 32;
  if (stager) LOADREGS(0);
  for (int it = 0; it < NT; ++it) {
    if (stager) {
      ushort_t* Ar = &Al[arow][0];
      *(ushort4*)(Ar + colA +  0) = A01.h[0];
      *(ushort4*)(Ar + colA +  8) = A01.h[1];
      *(ushort4*)(Ar + colA + 16) = A23.h[0];
      *(ushort4*)(Ar + colA + 24) = A23.h[1];
      ushort_t* Br0 = &Bl[bn][0];
      *(ushort4*)(Br0 + colB + 0) = B0.h[0];
      *(ushort4*)(Br0 + colB + 8) = B0.h[1];
      ushort_t* Br1 = &Bl[64 + bn][0];
      *(ushort4*)(Br1 + colB + 0) = B1.h[0];
      *(ushort4*)(Br1 + colB + 8) = B1.h[1];
      ushort_t* Br2 = &Bl[128 + bn][0];
      *(ushort4*)(Br2 + colB + 0) = B2.h[0];
      *(ushort4*)(Br2 + colB + 8) = B2.h[1];
    }
    __syncthreads();
    if (stager && it + 1 < NT) LOADREGS((it + 1) * 32);   // in flight during MFMAs
    short8 af[2], bfv[6];
#pragma unroll
    for (int fm = 0; fm < 2; ++fm)
      af[fm] = *(const short8*)&Al[wm * 32 + fm * 16 + lr][lg * 8];
#pragma unroll
    for (int fn = 0; fn < 6; ++fn)
      bfv[fn] = *(const short8*)&Bl[wn * 96 + fn * 16 + lr][lg * 8];
#pragma unroll
    for (int fm = 0; fm < 2; ++fm)
#pragma unroll
      for (int fn = 0; fn < 6; ++fn)
        acc[fm][fn] = __builtin_amdgcn_mfma_f32_16x16x32_bf16(af[fm], bfv[fn], acc[fm][fn], 0, 0, 0);
    if (it + 1 < NT) __syncthreads();
  }
#pragma unroll
  for (int fm = 0; fm < 2; ++fm) {
#pragma unroll
    for (int fn = 0; fn < 6; ++fn) {
      int col = n0 + wn * 96 + fn * 16 + lr;
      float bias;
      if (MODE == 0) bias = (col < 192) ? b0[col] : ((col < 384) ? 0.f : b1[col - 384]);
      else           bias = b0[col];
#pragma unroll
      for (int r = 0; r < 4; ++r) {
        int row = m0 + wm * 32 + fm * 16 + lg * 4 + r;
        float v = acc[fm][fn][r] + bias;
        if (MODE == 1) v = v / (1.f + __expf(-v));   // silu
        out[(size_t)row * NTOT + col] = f2bf(v);
      }
    }
  }
}

// ---------------------------------------------------------------------------
// GEMM + fused LayerNorm + residual, 512-thread R13 structure. N=192 full row.
// MODE 0: proj (K=192, scatter img_pos, resid = x fp32, out = x1_bf bf16)
// MODE 1: fc2  (K=768, natural, resid = x1_bf bf16, out = d_out fp32)
template<int KTOT, int MODE>
__global__ __launch_bounds__(512, 4) void gemm_ln512(
    const ushort_t* __restrict__ Ab, const ushort_t* __restrict__ W,
    const float* __restrict__ bias, const float* __restrict__ gamma,
    const float* __restrict__ beta, const float* __restrict__ residf,
    const ushort_t* __restrict__ residb, ushort_t* __restrict__ outb,
    float* __restrict__ outf) {
  __shared__ ushort_t Al[128][40];
  __shared__ ushort_t Bl[192][40];
  int t = threadIdx.x;
  int m0 = blockIdx.x * 128;
  int lane = t & 63, wid = t >> 6;
  int wm = wid >> 1, wn = wid & 1;
  int lr = lane & 15, lg = lane >> 4;

  bool stager = (t < 256);
  int arow = (t & 255) >> 1, akoff = (t & 1) << 4;
  const ushort_t* Arowp = Ab + (size_t)(m0 + arow) * KTOT + akoff;
  int colA = akoff ? 4 : 0;
  int bn = (t & 255) >> 2, cB = t & 3;
  const ushort_t* Browp  = W + (size_t)(bn) * KTOT + (cB << 3);
  const ushort_t* Browp2 = W + (size_t)(64 + bn) * KTOT + (cB << 3);
  const ushort_t* Browp3 = W + (size_t)(128 + bn) * KTOT + (cB << 3);
  int colB = ((cB & 1) << 4) | ((cB >> 1) << 2);

  f32x4 acc[2][6];
#pragma unroll
  for (int a = 0; a < 2; ++a)
#pragma unroll
    for (int b = 0; b < 6; ++b) acc[a][b] = (f32x4){0.f, 0.f, 0.f, 0.f};

  LD16 A01, A23, B0, B1, B2;
  auto LOADREGS = [&](int kt) {
    A01.v = *(const short8*)(Arowp + kt);
    A23.v = *(const short8*)(Arowp + kt + 8);
    B0.v  = *(const short8*)(Browp + kt);
    B1.v  = *(const short8*)(Browp2 + kt);
    B2.v  = *(const short8*)(Browp3 + kt);
  };

  const int NT = KTOT / 32;
  if (stager) LOADREGS(0);
  for (int it = 0; it < NT; ++it) {
    if (stager) {
      ushort_t* Ar = &Al[arow][0];
      *(ushort4*)(Ar + colA +  0) = A01.h[0];
      *(ushort4*)(Ar + colA +  8) = A01.h[1];
      *(ushort4*)(Ar + colA + 16) = A23.h[0];
      *(ushort4*)(Ar + colA + 24) = A23.h[1];
      ushort_t* Br0 = &Bl[bn][0];
      *(ushort4*)(Br0 + colB + 0) = B0.h[0];
      *(ushort4*)(Br0 + colB + 8) = B0.h[1];
      ushort_t* Br1 = &Bl[64 + bn][0];
      *(ushort4*)(Br1 + colB + 0) = B1.h[0];
      *(ushort4*)(Br1 + colB + 8) = B1.h[1];
      ushort_t* Br2 = &Bl[128 + bn][0];
      *(ushort4*)(Br2 + colB + 0) = B2.h[0];
      *(ushort4*)(Br2 + colB + 8) = B2.h[1];
    }
    __syncthreads();
    if (stager && it + 1 < NT) LOADREGS((it + 1) * 32);
    short8 af[2], bfv[6];
#pragma unroll
    for (int fm = 0; fm < 2; ++fm)
      af[fm] = *(const short8*)&Al[wm * 32 + fm * 16 + lr][lg * 8];
#pragma unroll
    for (int fn = 0; fn < 6; ++fn)
      bfv[fn] = *(const short8*)&Bl[wn * 96 + fn * 16 + lr][lg * 8];
#pragma unroll
    for (int fm = 0; fm < 2; ++fm)
#pragma unroll
      for (int fn = 0; fn < 6; ++fn)
        acc[fm][fn] = __builtin_amdgcn_mfma_f32_16x16x32_bf16(af[fm], bfv[fn], acc[fm][fn], 0, 0, 0);
    __syncthreads();   // all iters: Bl reads done (also guards part aliasing)
  }

  // LN epilogue. part aliases dead Bl: [2][128][2] floats = 2KB
  float* part = (float*)&Bl[0][0];
#pragma unroll
  for (int fm = 0; fm < 2; ++fm) {
#pragma unroll
    for (int r = 0; r < 4; ++r) {
      float s1 = 0.f, s2 = 0.f;
#pragma unroll
      for (int fn = 0; fn < 6; ++fn) {
        int col = wn * 96 + fn * 16 + lr;
        float v = acc[fm][fn][r] + bias[col];
        acc[fm][fn][r] = v;
        s1 += v; s2 += v * v;
      }
#pragma unroll
      for (int off = 1; off < 16; off <<= 1) {
        s1 += __shfl_xor(s1, off);
        s2 += __shfl_xor(s2, off);
      }
      if (lr == 0) {
        int lrow = wm * 32 + fm * 16 + lg * 4 + r;
        part[(wn * 128 + lrow) * 2 + 0] = s1;
        part[(wn * 128 + lrow) * 2 + 1] = s2;
      }
    }
  }
  __syncthreads();
#pragma unroll
  for (int fm = 0; fm < 2; ++fm) {
#pragma unroll
    for (int r = 0; r < 4; ++r) {
      int lrow = wm * 32 + fm * 16 + lg * 4 + r;
      float s1 = part[lrow * 2 + 0] + part[(128 + lrow) * 2 + 0];
      float s2 = part[lrow * 2 + 1] + part[(128 + lrow) * 2 + 1];
      float mean = s1 * (1.f / 192.f);
      float var  = s2 * (1.f / 192.f) - mean * mean;
      float rstd = rsqrtf(fmaxf(var, 0.f) + 1e-5f);
      int rg = m0 + lrow;
      size_t og = (MODE == 0 ? (size_t)img_pos(rg) : (size_t)rg) * 192;
#pragma unroll
      for (int fn = 0; fn < 6; ++fn) {
        int col = wn * 96 + fn * 16 + lr;
        float l = (acc[fm][fn][r] - mean) * rstd * gamma[col] + beta[col];
        if (MODE == 0) outb[og + col] = f2bf(residf[og + col] + l);
        else           outf[og + col] = bf2f(residb[og + col]) + l;
      }
    }
  }
}

// ---------------------------------------------------------------------------
// Attention (MFMA): block = (window, head), 256 threads = 4 waves. (R13 verbatim)
__global__ __launch_bounds__(256) void attn_kernel(
    const ushort_t* __restrict__ qkv, const float* __restrict__ logit_scale,
    const float* __restrict__ tab_s, ushort_t* __restrict__ attn_out) {
  __shared__ ushort_t qs[64][40];
  __shared__ ushort_t ksl[64][40];
  __shared__ ushort_t vsl[32][80];
  __shared__ ushort_t ps[64][80];
  __shared__ float tab_l[169];
  int win = blockIdx.x, head = blockIdx.y;
  int t = threadIdx.x;
  int wi = win & 63;
  int wh0 = (wi >> 3) * 7, ww0 = (wi & 7) * 7;
  size_t base = (size_t)win * 49 * 576 + head * 32;

  for (int u = t; u < 169; u += 256) tab_l[u] = tab_s[head * 169 + u];

  for (int u = t; u < 240; u += 256) {
    int arr = u / 120, v = u - arr * 120;
    int r = 49 + (v >> 3), c4 = (v & 7) << 2;
    ushort_t* p = arr ? &ksl[r][c4] : &qs[r][c4];
    *(ushort4*)p = make_ushort4(0, 0, 0, 0);
  }

  for (int u = t; u < 2048; u += 256) {
    int key = u >> 5, d = u & 31;
    ushort_t val = 0;
    if (key < 49) val = qkv[base + (size_t)key * 576 + 384 + d];
    int kk = key & 31;
    int pc = ((key >> 5) << 5) + 8 * ((kk >> 2) & 3) + 4 * (kk >> 4) + (kk & 3);
    vsl[d][pc] = val;
  }

  float scale = __expf(fminf(logit_scale[head], 4.605170186f));  // ln(100)

  if (t < 196) {
    int r = t >> 2, c = t & 3;
    const ushort_t* qp = qkv + base + (size_t)r * 576 + c * 8;
    ushort4 qa = *(const ushort4*)qp,         qb = *(const ushort4*)(qp + 4);
    ushort4 ka = *(const ushort4*)(qp + 192), kb = *(const ushort4*)(qp + 196);
    float qf[8] = {bf2f(qa.x), bf2f(qa.y), bf2f(qa.z), bf2f(qa.w),
                   bf2f(qb.x), bf2f(qb.y), bf2f(qb.z), bf2f(qb.w)};
    float kf[8] = {bf2f(ka.x), bf2f(ka.y), bf2f(ka.z), bf2f(ka.w),
                   bf2f(kb.x), bf2f(kb.y), bf2f(kb.z), bf2f(kb.w)};
    float sq = 0.f, sk = 0.f;
#pragma unroll
    for (int d = 0; d < 8; ++d) { sq += qf[d] * qf[d]; sk += kf[d] * kf[d]; }
    sq += __shfl_xor(sq, 1); sq += __shfl_xor(sq, 2);
    sk += __shfl_xor(sk, 1); sk += __shfl_xor(sk, 2);
    float rq = scale / fmaxf(sqrtf(sq), 1e-12f);
    float rk = 1.f   / fmaxf(sqrtf(sk), 1e-12f);
    int c0 = ((c & 1) << 4) | ((c >> 1) << 2);   // {0,16,4,20}
    ushort_t* qd = &qs[r][c0];
    *(ushort4*)(qd + 0) = make_ushort4(f2bf(qf[0]*rq), f2bf(qf[1]*rq), f2bf(qf[2]*rq), f2bf(qf[3]*rq));
    *(ushort4*)(qd + 8) = make_ushort4(f2bf(qf[4]*rq), f2bf(qf[5]*rq), f2bf(qf[6]*rq), f2bf(qf[7]*rq));
    ushort_t* kd = &ksl[r][c0];
    *(ushort4*)(kd + 0) = make_ushort4(f2bf(kf[0]*rk), f2bf(kf[1]*rk), f2bf(kf[2]*rk), f2bf(kf[3]*rk));
    *(ushort4*)(kd + 8) = make_ushort4(f2bf(kf[4]*rk), f2bf(kf[5]*rk), f2bf(kf[6]*rk), f2bf(kf[7]*rk));
  }
  __syncthreads();

  int lane = t & 63, w = t >> 6;
  int lr = lane & 15, lg = lane >> 4;

  short8 aq = *(const short8*)&qs[w * 16 + lr][lg * 8];
  f32x4 acc[4];
#pragma unroll
  for (int fn = 0; fn < 4; ++fn) {
    acc[fn] = (f32x4){0.f, 0.f, 0.f, 0.f};
    short8 bk = *(const short8*)&ksl[fn * 16 + lr][lg * 8];
    acc[fn] = __builtin_amdgcn_mfma_f32_16x16x32_bf16(aq, bk, acc[fn], 0, 0, 0);
  }

  float rsum[4];
#pragma unroll
  for (int r = 0; r < 4; ++r) {
    int row = w * 16 + lg * 4 + r;
    int rd = (row * 9363) >> 16, rm = row - 7 * rd;
    int gr = region3(wh0 + rd) * 3 + region3(ww0 + rm);
    bool rv = row < 49;
    float sv[4];
#pragma unroll
    for (int fn = 0; fn < 4; ++fn) {
      int col = fn * 16 + lr;
      int jd = (col * 9363) >> 16, jm = col - 7 * jd;
      int gj = region3(wh0 + jd) * 3 + region3(ww0 + jm);
      bool cv = rv && (col < 49);
      int idx = cv ? (rd - jd + 6) * 13 + (rm - jm + 6) : 0;
      float s = acc[fn][r] + tab_l[idx] + (gr == gj ? 0.f : -100.f);
      sv[fn] = cv ? s : -1e30f;
    }
    float m = fmaxf(fmaxf(sv[0], sv[1]), fmaxf(sv[2], sv[3]));
#pragma unroll
    for (int o = 1; o < 16; o <<= 1) m = fmaxf(m, __shfl_xor(m, o));
    float sum = 0.f;
#pragma unroll
    for (int fn = 0; fn < 4; ++fn) {
      float e = __expf(sv[fn] - m);
      sum += e;
      int pc = ((fn >> 1) << 5) + 8 * (lr >> 2) + ((fn & 1) << 2) + (lr & 3);
      ps[row][pc] = f2bf(e);
    }
#pragma unroll
    for (int o = 1; o < 16; o <<= 1) sum += __shfl_xor(sum, o);
    rsum[r] = 1.f / sum;
  }
  __syncthreads();

  short8 ap0 = *(const short8*)&ps[w * 16 + lr][lg * 8];
  short8 ap1 = *(const short8*)&ps[w * 16 + lr][32 + lg * 8];
  f32x4 o2[2];
#pragma unroll
  for (int f = 0; f < 2; ++f) {
    o2[f] = (f32x4){0.f, 0.f, 0.f, 0.f};
    short8 bv0 = *(const short8*)&vsl[f * 16 + lr][lg * 8];
    short8 bv1 = *(const short8*)&vsl[f * 16 + lr][32 + lg * 8];
    o2[f] = __builtin_amdgcn_mfma_f32_16x16x32_bf16(ap0, bv0, o2[f], 0, 0, 0);
    o2[f] = __builtin_amdgcn_mfma_f32_16x16x32_bf16(ap1, bv1, o2[f], 0, 0, 0);
  }
#pragma unroll
  for (int f = 0; f < 2; ++f) {
#pragma unroll
    for (int r = 0; r < 4; ++r) {
      int row = w * 16 + lg * 4 + r;
      if (row < 49)
        attn_out[((size_t)win * 49 + row) * 192 + head * 32 + f * 16 + lr] =
            f2bf(o2[f][r] * rsum[r]);
    }
  }
}

// ---------------------------------------------------------------------------
extern "C" void kernel_launch(void* const* d_in, const int* in_sizes, int n_in,
                              void* d_out, int out_size, void* d_ws, size_t ws_size,
                              hipStream_t stream) {
  (void)in_sizes; (void)n_in; (void)out_size; (void)ws_size;
  const float* x    = (const float*)d_in[0];
  const float* qkvw = (const float*)d_in[1];
  const float* qb   = (const float*)d_in[2];
  const float* vb   = (const float*)d_in[3];
  const float* ls   = (const float*)d_in[4];
  const float* cw1  = (const float*)d_in[5];
  const float* cb1  = (const float*)d_in[6];
  const float* cw2  = (const float*)d_in[7];
  const float* pw   = (const float*)d_in[8];
  const float* pb   = (const float*)d_in[9];
  const float* n1g  = (const float*)d_in[10];
  const float* n1b  = (const float*)d_in[11];
  const float* n2g  = (const float*)d_in[12];
  const float* n2b  = (const float*)d_in[13];
  const float* f1w  = (const float*)d_in[14];
  const float* f1b  = (const float*)d_in[15];
  const float* f2w  = (const float*)d_in[16];
  const float* f2b  = (const float*)d_in[17];
  float* out = (float*)d_out;

  char* ws = (char*)d_ws;
  ushort_t* wq_bf = (ushort_t*)ws;                 // 110592
  ushort_t* wp_bf = wq_bf + 110592;                // 36864
  ushort_t* w1_bf = wp_bf + 36864;                 // 147456
  ushort_t* w2_bf = w1_bf + 147456;                // 147456
  float*    tab_s = (float*)(w2_bf + 147456);      // 6*169 floats
  const size_t OFF_BIG = 1 << 20;
  ushort_t* qkv_out = (ushort_t*)(ws + OFF_BIG);
  ushort_t* xw_bf   = (ushort_t*)(ws + OFF_BIG + 115605504);
  ushort_t* attn_o  = (ushort_t*)(ws + OFF_BIG + 115605504);
  ushort_t* x1_bf   = (ushort_t*)(ws + OFF_BIG + 154140672);
  ushort_t* hmid    = (ushort_t*)(ws + OFF_BIG);   // 100352*768 bf16 over R1+R2

  cvt_kernel<<<(110592 + 255) / 256, 256, 0, stream>>>(qkvw, wq_bf, 110592);
  cvt_kernel<<<(36864  + 255) / 256, 256, 0, stream>>>(pw,   wp_bf, 36864);
  cvt_kernel<<<(147456 + 255) / 256, 256, 0, stream>>>(f1w,  w1_bf, 147456);
  cvt_kernel<<<(147456 + 255) / 256, 256, 0, stream>>>(f2w,  w2_bf, 147456);
  cpb_kernel<<<169, 256, 0, stream>>>(cw1, cb1, cw2, tab_s);
  gather_cvt_kernel<<<9408, 256, 0, stream>>>(x, xw_bf);

  // qkv
  gemm_n192<192, 0><<<dim3(784, 3), 512, 0, stream>>>(xw_bf, wq_bf, qb, vb, qkv_out, 576);
  // attention
  attn_kernel<<<dim3(2048, 6), 256, 0, stream>>>(qkv_out, ls, tab_s, attn_o);
  // proj + LN1 + residual fused -> x1_bf (scatter img_pos)
  gemm_ln512<192, 0><<<784, 512, 0, stream>>>(attn_o, wp_bf, pb, n1g, n1b, x, nullptr, x1_bf, nullptr);
  // fc1 (silu)
  gemm_n192<192, 1><<<dim3(784, 4), 512, 0, stream>>>(x1_bf, w1_bf, f1b, nullptr, hmid, 768);
  // fc2 + LN2 + residual fused -> d_out fp32
  gemm_ln512<768, 1><<<784, 512, 0, stream>>>(hmid, w2_bf, f2b, n2g, n2b, nullptr, x1_bf, nullptr, out);
}

// Round 16
// 396.799 us; speedup vs baseline: 1.0411x; 1.0411x over previous
//
#include <hip/hip_runtime.h>

// ============================================================================
// Swin V2 block, round 16 = R13 split config for qkv/proj/fc1 (+ln_resid<0>)
// + fc2+LN2 fused ONLY (gemm_ln512<768>, 24 K-iters amortize the epilogue;
// R15 showed proj-fused = 110us vs 55 split -> K=192 can't amortize, reverted;
// fc2-fused <=109 vs 117 split -> kept). gemm_ln512 barrier structure fixed
// (single post-loop barrier, not per-iteration double).
// MFMA layout (HW-verified): A row=lane%16, k=4*(lane/16)+{0..3}(+16);
// C/D col=lane%16, row=4*(lane/16)+reg. LDS perm col=8*((k%16)/4)+4*(k/16)+k%4.
// ============================================================================

typedef unsigned short ushort_t;
using f32x4  = __attribute__((ext_vector_type(4))) float;
using short8 = __attribute__((ext_vector_type(8))) short;
union LD16 { short8 v; ushort4 h[2]; };

__device__ __forceinline__ ushort_t f2bf(float f) {
  union { float f; unsigned u; } v; v.f = f;
  unsigned r = v.u + 0x7fffu + ((v.u >> 16) & 1u);
  return (ushort_t)(r >> 16);
}
__device__ __forceinline__ float bf2f(ushort_t u) {
  union { unsigned u; float f; } v; v.u = ((unsigned)u) << 16;
  return v.f;
}

// windowed-token index m -> image row index (same map for gather and scatter)
__device__ __forceinline__ int img_pos(int m) {
  int win = m / 49, n = m - win * 49;
  int b = win >> 6, wi = win & 63;
  int nd = n / 7, nm = n - nd * 7;
  int hs = (wi >> 3) * 7 + nd;
  int ws = (wi & 7) * 7 + nm;
  int h = hs + 3; if (h >= 56) h -= 56;
  int w = ws + 3; if (w >= 56) w -= 56;
  return b * 3136 + h * 56 + w;
}

__device__ __forceinline__ int region3(int a) { return a < 49 ? 0 : (a < 53 ? 1 : 2); }

// ---------------------------------------------------------------------------
__global__ void cvt_kernel(const float* __restrict__ in, ushort_t* __restrict__ out, int n) {
  int i = blockIdx.x * 256 + threadIdx.x;
  if (i < n) out[i] = f2bf(in[i]);
}

// gather shifted-window rows + convert to bf16: xw[m][c] = bf16(x[img_pos(m)][c])
__global__ __launch_bounds__(256) void gather_cvt_kernel(
    const float* __restrict__ x, ushort_t* __restrict__ xw) {
  int i8 = blockIdx.x * 256 + threadIdx.x;      // 100352*24 tasks of 8 elems
  int m = i8 / 24, c8 = (i8 - m * 24) * 8;
  const float* p = x + (size_t)img_pos(m) * 192 + c8;
  float4 a = *(const float4*)p, b = *(const float4*)(p + 4);
  ushort_t* q = xw + (size_t)m * 192 + c8;
  *(ushort4*)q       = make_ushort4(f2bf(a.x), f2bf(a.y), f2bf(a.z), f2bf(a.w));
  *(ushort4*)(q + 4) = make_ushort4(f2bf(b.x), f2bf(b.y), f2bf(b.z), f2bf(b.w));
}

// ---------------------------------------------------------------------------
// CPB: tab_s[head][e] = 16*sigmoid( relu(REL_TABLE[e] @ w1.T + b1) @ w2.T )
__global__ __launch_bounds__(256) void cpb_kernel(
    const float* __restrict__ w1, const float* __restrict__ b1,
    const float* __restrict__ w2, float* __restrict__ tab_s) {
  int e = blockIdx.x;            // 0..168
  int t = threadIdx.x;           // 0..255
  int i = e / 13, j = e - 13 * (e / 13);
  auto cval = [](int a) -> float {
    float r = (a - 6) * (8.0f / 6.0f);
    float v = log2f(fabsf(r) + 1.f) * (1.f / 3.f);
    return r < 0.f ? -v : v;
  };
  float ci = cval(i), cj = cval(j);
  float h = fmaxf(ci * w1[2 * t] + cj * w1[2 * t + 1] + b1[t], 0.f);
  __shared__ float red[256];
  for (int head = 0; head < 6; ++head) {
    red[t] = h * w2[head * 256 + t];
    __syncthreads();
    for (int st = 128; st > 0; st >>= 1) {
      if (t < st) red[t] += red[t + st];
      __syncthreads();
    }
    if (t == 0) tab_s[head * 169 + e] = 16.f / (1.f + __expf(-red[0]));
    __syncthreads();
  }
}

// ---------------------------------------------------------------------------
// GEMM, tile 128(M) x 192(N), K-step 32, 512 threads = 8 waves (4x2 of
// 32x96), acc[2][6], T14 reg prefetch on t<256. (R13 proven template)
// MODE 0: qkv  MODE 1: fc1(silu)  MODE 2: proj (pre-LN, may alias A in-place)
template<int KTOT, int MODE>
__global__ __launch_bounds__(512, 4) void gemm_n192(
    const ushort_t* __restrict__ Ab, const ushort_t* __restrict__ W,
    const float* __restrict__ b0, const float* __restrict__ b1,
    ushort_t* out, int NTOT) {
  __shared__ ushort_t Al[128][40];
  __shared__ ushort_t Bl[192][40];
  int t = threadIdx.x;
  int m0 = blockIdx.x * 128, n0 = blockIdx.y * 192;
  int lane = t & 63, wid = t >> 6;
  int wm = wid >> 1, wn = wid & 1;
  int lr = lane & 15, lg = lane >> 4;

  bool stager = (t < 256);
  int arow = (t & 255) >> 1, akoff = (t & 1) << 4;
  const ushort_t* Arowp = Ab + (size_t)(m0 + arow) * KTOT + akoff;
  int colA = akoff ? 4 : 0;
  int bn = (t & 255) >> 2, cB = t & 3;
  const ushort_t* Browp  = W + (size_t)(n0 + bn) * KTOT + (cB << 3);
  const ushort_t* Browp2 = W + (size_t)(n0 + 64 + bn) * KTOT + (cB << 3);
  const ushort_t* Browp3 = W + (size_t)(n0 + 128 + bn) * KTOT + (cB << 3);
  int colB = ((cB & 1) << 4) | ((cB >> 1) << 2);   // {0,16,4,20}

  f32x4 acc[2][6];
#pragma unroll
  for (int a = 0; a < 2; ++a)
#pragma unroll
    for (int b = 0; b < 6; ++b) acc[a][b] = (f32x4){0.f, 0.f, 0.f, 0.f};

  LD16 A01, A23, B0, B1, B2;
  auto LOADREGS = [&](int kt) {
    A01.v = *(const short8*)(Arowp + kt);
    A23.v = *(const short8*)(Arowp + kt + 8);
    B0.v  = *(const short8*)(Browp + kt);
    B1.v  = *(const short8*)(Browp2 + kt);
    B2.v  = *(const short8*)(Browp3 + kt);
  };

  const int NT = KTOT / 32;
  if (stager) LOADREGS(0);
  for (int it = 0; it < NT; ++it) {
    if (stager) {
      ushort_t* Ar = &Al[arow][0];
      *(ushort4*)(Ar + colA +  0) = A01.h[0];
      *(ushort4*)(Ar + colA +  8) = A01.h[1];
      *(ushort4*)(Ar + colA + 16) = A23.h[0];
      *(ushort4*)(Ar + colA + 24) = A23.h[1];
      ushort_t* Br0 = &Bl[bn][0];
      *(ushort4*)(Br0 + colB + 0) = B0.h[0];
      *(ushort4*)(Br0 + colB + 8) = B0.h[1];
      ushort_t* Br1 = &Bl[64 + bn][0];
      *(ushort4*)(Br1 + colB + 0) = B1.h[0];
      *(ushort4*)(Br1 + colB + 8) = B1.h[1];
      ushort_t* Br2 = &Bl[128 + bn][0];
      *(ushort4*)(Br2 + colB + 0) = B2.h[0];
      *(ushort4*)(Br2 + colB + 8) = B2.h[1];
    }
    __syncthreads();
    if (stager && it + 1 < NT) LOADREGS((it + 1) * 32);   // in flight during MFMAs
    short8 af[2], bfv[6];
#pragma unroll
    for (int fm = 0; fm < 2; ++fm)
      af[fm] = *(const short8*)&Al[wm * 32 + fm * 16 + lr][lg * 8];
#pragma unroll
    for (int fn = 0; fn < 6; ++fn)
      bfv[fn] = *(const short8*)&Bl[wn * 96 + fn * 16 + lr][lg * 8];
#pragma unroll
    for (int fm = 0; fm < 2; ++fm)
#pragma unroll
      for (int fn = 0; fn < 6; ++fn)
        acc[fm][fn] = __builtin_amdgcn_mfma_f32_16x16x32_bf16(af[fm], bfv[fn], acc[fm][fn], 0, 0, 0);
    if (it + 1 < NT) __syncthreads();
  }
#pragma unroll
  for (int fm = 0; fm < 2; ++fm) {
#pragma unroll
    for (int fn = 0; fn < 6; ++fn) {
      int col = n0 + wn * 96 + fn * 16 + lr;
      float bias;
      if (MODE == 0) bias = (col < 192) ? b0[col] : ((col < 384) ? 0.f : b1[col - 384]);
      else           bias = b0[col];
#pragma unroll
      for (int r = 0; r < 4; ++r) {
        int row = m0 + wm * 32 + fm * 16 + lg * 4 + r;
        float v = acc[fm][fn][r] + bias;
        if (MODE == 1) v = v / (1.f + __expf(-v));   // silu
        out[(size_t)row * NTOT + col] = f2bf(v);
      }
    }
  }
}

// ---------------------------------------------------------------------------
// fc2 GEMM (K=768) + fused LN2 + residual. 512-thread R13 structure.
// natural row order, resid = x1_bf bf16, out = d_out fp32.
__global__ __launch_bounds__(512, 4) void gemm_ln_fc2(
    const ushort_t* __restrict__ Ab, const ushort_t* __restrict__ W,
    const float* __restrict__ bias, const float* __restrict__ gamma,
    const float* __restrict__ beta, const ushort_t* __restrict__ residb,
    float* __restrict__ outf) {
  const int KTOT = 768;
  __shared__ ushort_t Al[128][40];
  __shared__ ushort_t Bl[192][40];
  int t = threadIdx.x;
  int m0 = blockIdx.x * 128;
  int lane = t & 63, wid = t >> 6;
  int wm = wid >> 1, wn = wid & 1;
  int lr = lane & 15, lg = lane >> 4;

  bool stager = (t < 256);
  int arow = (t & 255) >> 1, akoff = (t & 1) << 4;
  const ushort_t* Arowp = Ab + (size_t)(m0 + arow) * KTOT + akoff;
  int colA = akoff ? 4 : 0;
  int bn = (t & 255) >> 2, cB = t & 3;
  const ushort_t* Browp  = W + (size_t)(bn) * KTOT + (cB << 3);
  const ushort_t* Browp2 = W + (size_t)(64 + bn) * KTOT + (cB << 3);
  const ushort_t* Browp3 = W + (size_t)(128 + bn) * KTOT + (cB << 3);
  int colB = ((cB & 1) << 4) | ((cB >> 1) << 2);

  f32x4 acc[2][6];
#pragma unroll
  for (int a = 0; a < 2; ++a)
#pragma unroll
    for (int b = 0; b < 6; ++b) acc[a][b] = (f32x4){0.f, 0.f, 0.f, 0.f};

  LD16 A01, A23, B0, B1, B2;
  auto LOADREGS = [&](int kt) {
    A01.v = *(const short8*)(Arowp + kt);
    A23.v = *(const short8*)(Arowp + kt + 8);
    B0.v  = *(const short8*)(Browp + kt);
    B1.v  = *(const short8*)(Browp2 + kt);
    B2.v  = *(const short8*)(Browp3 + kt);
  };

  const int NT = KTOT / 32;
  if (stager) LOADREGS(0);
  for (int it = 0; it < NT; ++it) {
    if (stager) {
      ushort_t* Ar = &Al[arow][0];
      *(ushort4*)(Ar + colA +  0) = A01.h[0];
      *(ushort4*)(Ar + colA +  8) = A01.h[1];
      *(ushort4*)(Ar + colA + 16) = A23.h[0];
      *(ushort4*)(Ar + colA + 24) = A23.h[1];
      ushort_t* Br0 = &Bl[bn][0];
      *(ushort4*)(Br0 + colB + 0) = B0.h[0];
      *(ushort4*)(Br0 + colB + 8) = B0.h[1];
      ushort_t* Br1 = &Bl[64 + bn][0];
      *(ushort4*)(Br1 + colB + 0) = B1.h[0];
      *(ushort4*)(Br1 + colB + 8) = B1.h[1];
      ushort_t* Br2 = &Bl[128 + bn][0];
      *(ushort4*)(Br2 + colB + 0) = B2.h[0];
      *(ushort4*)(Br2 + colB + 8) = B2.h[1];
    }
    __syncthreads();
    if (stager && it + 1 < NT) LOADREGS((it + 1) * 32);
    short8 af[2], bfv[6];
#pragma unroll
    for (int fm = 0; fm < 2; ++fm)
      af[fm] = *(const short8*)&Al[wm * 32 + fm * 16 + lr][lg * 8];
#pragma unroll
    for (int fn = 0; fn < 6; ++fn)
      bfv[fn] = *(const short8*)&Bl[wn * 96 + fn * 16 + lr][lg * 8];
#pragma unroll
    for (int fm = 0; fm < 2; ++fm)
#pragma unroll
      for (int fn = 0; fn < 6; ++fn)
        acc[fm][fn] = __builtin_amdgcn_mfma_f32_16x16x32_bf16(af[fm], bfv[fn], acc[fm][fn], 0, 0, 0);
    if (it + 1 < NT) __syncthreads();
  }
  __syncthreads();   // all waves done with Bl before part[] aliases it

  // LN epilogue. part aliases dead Bl: [2][128][2] floats = 2KB
  float* part = (float*)&Bl[0][0];
#pragma unroll
  for (int fm = 0; fm < 2; ++fm) {
#pragma unroll
    for (int r = 0; r < 4; ++r) {
      float s1 = 0.f, s2 = 0.f;
#pragma unroll
      for (int fn = 0; fn < 6; ++fn) {
        int col = wn * 96 + fn * 16 + lr;
        float v = acc[fm][fn][r] + bias[col];
        acc[fm][fn][r] = v;
        s1 += v; s2 += v * v;
      }
#pragma unroll
      for (int off = 1; off < 16; off <<= 1) {
        s1 += __shfl_xor(s1, off);
        s2 += __shfl_xor(s2, off);
      }
      if (lr == 0) {
        int lrow = wm * 32 + fm * 16 + lg * 4 + r;
        part[(wn * 128 + lrow) * 2 + 0] = s1;
        part[(wn * 128 + lrow) * 2 + 1] = s2;
      }
    }
  }
  __syncthreads();
#pragma unroll
  for (int fm = 0; fm < 2; ++fm) {
#pragma unroll
    for (int r = 0; r < 4; ++r) {
      int lrow = wm * 32 + fm * 16 + lg * 4 + r;
      float s1 = part[lrow * 2 + 0] + part[(128 + lrow) * 2 + 0];
      float s2 = part[lrow * 2 + 1] + part[(128 + lrow) * 2 + 1];
      float mean = s1 * (1.f / 192.f);
      float var  = s2 * (1.f / 192.f) - mean * mean;
      float rstd = rsqrtf(fmaxf(var, 0.f) + 1e-5f);
      size_t og = (size_t)(m0 + lrow) * 192;
#pragma unroll
      for (int fn = 0; fn < 6; ++fn) {
        int col = wn * 96 + fn * 16 + lr;
        float l = (acc[fm][fn][r] - mean) * rstd * gamma[col] + beta[col];
        outf[og + col] = bf2f(residb[og + col]) + l;
      }
    }
  }
}

// ---------------------------------------------------------------------------
// Streaming LayerNorm + residual for proj output (MODE 0 of old ln_resid).
// One wave per row; pre bf16 window order; out x1_bf[img_pos] =
// bf16(x_f32[img_pos] + LN(pre_row)).
__global__ __launch_bounds__(256) void ln_resid_kernel(
    const ushort_t* __restrict__ pre, const float* __restrict__ residf,
    const float* __restrict__ gamma, const float* __restrict__ beta,
    ushort_t* __restrict__ outb) {
  int m = (blockIdx.x * 256 + threadIdx.x) >> 6;   // row
  int lane = threadIdx.x & 63;
  const ushort_t* p = pre + (size_t)m * 192;
  float v0 = bf2f(p[lane]), v1 = bf2f(p[lane + 64]), v2 = bf2f(p[lane + 128]);
  float s1 = v0 + v1 + v2;
  float s2 = v0 * v0 + v1 * v1 + v2 * v2;
#pragma unroll
  for (int o = 1; o < 64; o <<= 1) {
    s1 += __shfl_xor(s1, o);
    s2 += __shfl_xor(s2, o);
  }
  float mean = s1 * (1.f / 192.f);
  float var  = s2 * (1.f / 192.f) - mean * mean;
  float rstd = rsqrtf(fmaxf(var, 0.f) + 1e-5f);
  float l0 = (v0 - mean) * rstd * gamma[lane]       + beta[lane];
  float l1 = (v1 - mean) * rstd * gamma[lane + 64]  + beta[lane + 64];
  float l2 = (v2 - mean) * rstd * gamma[lane + 128] + beta[lane + 128];
  size_t og = (size_t)img_pos(m) * 192;
  outb[og + lane]       = f2bf(residf[og + lane]       + l0);
  outb[og + lane + 64]  = f2bf(residf[og + lane + 64]  + l1);
  outb[og + lane + 128] = f2bf(residf[og + lane + 128] + l2);
}

// ---------------------------------------------------------------------------
// Attention (MFMA): block = (window, head), 256 threads = 4 waves. (R13 verbatim)
__global__ __launch_bounds__(256) void attn_kernel(
    const ushort_t* __restrict__ qkv, const float* __restrict__ logit_scale,
    const float* __restrict__ tab_s, ushort_t* __restrict__ attn_out) {
  __shared__ ushort_t qs[64][40];
  __shared__ ushort_t ksl[64][40];
  __shared__ ushort_t vsl[32][80];
  __shared__ ushort_t ps[64][80];
  __shared__ float tab_l[169];
  int win = blockIdx.x, head = blockIdx.y;
  int t = threadIdx.x;
  int wi = win & 63;
  int wh0 = (wi >> 3) * 7, ww0 = (wi & 7) * 7;
  size_t base = (size_t)win * 49 * 576 + head * 32;

  for (int u = t; u < 169; u += 256) tab_l[u] = tab_s[head * 169 + u];

  for (int u = t; u < 240; u += 256) {
    int arr = u / 120, v = u - arr * 120;
    int r = 49 + (v >> 3), c4 = (v & 7) << 2;
    ushort_t* p = arr ? &ksl[r][c4] : &qs[r][c4];
    *(ushort4*)p = make_ushort4(0, 0, 0, 0);
  }

  for (int u = t; u < 2048; u += 256) {
    int key = u >> 5, d = u & 31;
    ushort_t val = 0;
    if (key < 49) val = qkv[base + (size_t)key * 576 + 384 + d];
    int kk = key & 31;
    int pc = ((key >> 5) << 5) + 8 * ((kk >> 2) & 3) + 4 * (kk >> 4) + (kk & 3);
    vsl[d][pc] = val;
  }

  float scale = __expf(fminf(logit_scale[head], 4.605170186f));  // ln(100)

  if (t < 196) {
    int r = t >> 2, c = t & 3;
    const ushort_t* qp = qkv + base + (size_t)r * 576 + c * 8;
    ushort4 qa = *(const ushort4*)qp,         qb = *(const ushort4*)(qp + 4);
    ushort4 ka = *(const ushort4*)(qp + 192), kb = *(const ushort4*)(qp + 196);
    float qf[8] = {bf2f(qa.x), bf2f(qa.y), bf2f(qa.z), bf2f(qa.w),
                   bf2f(qb.x), bf2f(qb.y), bf2f(qb.z), bf2f(qb.w)};
    float kf[8] = {bf2f(ka.x), bf2f(ka.y), bf2f(ka.z), bf2f(ka.w),
                   bf2f(kb.x), bf2f(kb.y), bf2f(kb.z), bf2f(kb.w)};
    float sq = 0.f, sk = 0.f;
#pragma unroll
    for (int d = 0; d < 8; ++d) { sq += qf[d] * qf[d]; sk += kf[d] * kf[d]; }
    sq += __shfl_xor(sq, 1); sq += __shfl_xor(sq, 2);
    sk += __shfl_xor(sk, 1); sk += __shfl_xor(sk, 2);
    float rq = scale / fmaxf(sqrtf(sq), 1e-12f);
    float rk = 1.f   / fmaxf(sqrtf(sk), 1e-12f);
    int c0 = ((c & 1) << 4) | ((c >> 1) << 2);   // {0,16,4,20}
    ushort_t* qd = &qs[r][c0];
    *(ushort4*)(qd + 0) = make_ushort4(f2bf(qf[0]*rq), f2bf(qf[1]*rq), f2bf(qf[2]*rq), f2bf(qf[3]*rq));
    *(ushort4*)(qd + 8) = make_ushort4(f2bf(qf[4]*rq), f2bf(qf[5]*rq), f2bf(qf[6]*rq), f2bf(qf[7]*rq));
    ushort_t* kd = &ksl[r][c0];
    *(ushort4*)(kd + 0) = make_ushort4(f2bf(kf[0]*rk), f2bf(kf[1]*rk), f2bf(kf[2]*rk), f2bf(kf[3]*rk));
    *(ushort4*)(kd + 8) = make_ushort4(f2bf(kf[4]*rk), f2bf(kf[5]*rk), f2bf(kf[6]*rk), f2bf(kf[7]*rk));
  }
  __syncthreads();

  int lane = t & 63, w = t >> 6;
  int lr = lane & 15, lg = lane >> 4;

  short8 aq = *(const short8*)&qs[w * 16 + lr][lg * 8];
  f32x4 acc[4];
#pragma unroll
  for (int fn = 0; fn < 4; ++fn) {
    acc[fn] = (f32x4){0.f, 0.f, 0.f, 0.f};
    short8 bk = *(const short8*)&ksl[fn * 16 + lr][lg * 8];
    acc[fn] = __builtin_amdgcn_mfma_f32_16x16x32_bf16(aq, bk, acc[fn], 0, 0, 0);
  }

  float rsum[4];
#pragma unroll
  for (int r = 0; r < 4; ++r) {
    int row = w * 16 + lg * 4 + r;
    int rd = (row * 9363) >> 16, rm = row - 7 * rd;
    int gr = region3(wh0 + rd) * 3 + region3(ww0 + rm);
    bool rv = row < 49;
    float sv[4];
#pragma unroll
    for (int fn = 0; fn < 4; ++fn) {
      int col = fn * 16 + lr;
      int jd = (col * 9363) >> 16, jm = col - 7 * jd;
      int gj = region3(wh0 + jd) * 3 + region3(ww0 + jm);
      bool cv = rv && (col < 49);
      int idx = cv ? (rd - jd + 6) * 13 + (rm - jm + 6) : 0;
      float s = acc[fn][r] + tab_l[idx] + (gr == gj ? 0.f : -100.f);
      sv[fn] = cv ? s : -1e30f;
    }
    float m = fmaxf(fmaxf(sv[0], sv[1]), fmaxf(sv[2], sv[3]));
#pragma unroll
    for (int o = 1; o < 16; o <<= 1) m = fmaxf(m, __shfl_xor(m, o));
    float sum = 0.f;
#pragma unroll
    for (int fn = 0; fn < 4; ++fn) {
      float e = __expf(sv[fn] - m);
      sum += e;
      int pc = ((fn >> 1) << 5) + 8 * (lr >> 2) + ((fn & 1) << 2) + (lr & 3);
      ps[row][pc] = f2bf(e);
    }
#pragma unroll
    for (int o = 1; o < 16; o <<= 1) sum += __shfl_xor(sum, o);
    rsum[r] = 1.f / sum;
  }
  __syncthreads();

  short8 ap0 = *(const short8*)&ps[w * 16 + lr][lg * 8];
  short8 ap1 = *(const short8*)&ps[w * 16 + lr][32 + lg * 8];
  f32x4 o2[2];
#pragma unroll
  for (int f = 0; f < 2; ++f) {
    o2[f] = (f32x4){0.f, 0.f, 0.f, 0.f};
    short8 bv0 = *(const short8*)&vsl[f * 16 + lr][lg * 8];
    short8 bv1 = *(const short8*)&vsl[f * 16 + lr][32 + lg * 8];
    o2[f] = __builtin_amdgcn_mfma_f32_16x16x32_bf16(ap0, bv0, o2[f], 0, 0, 0);
    o2[f] = __builtin_amdgcn_mfma_f32_16x16x32_bf16(ap1, bv1, o2[f], 0, 0, 0);
  }
#pragma unroll
  for (int f = 0; f < 2; ++f) {
#pragma unroll
    for (int r = 0; r < 4; ++r) {
      int row = w * 16 + lg * 4 + r;
      if (row < 49)
        attn_out[((size_t)win * 49 + row) * 192 + head * 32 + f * 16 + lr] =
            f2bf(o2[f][r] * rsum[r]);
    }
  }
}

// ---------------------------------------------------------------------------
extern "C" void kernel_launch(void* const* d_in, const int* in_sizes, int n_in,
                              void* d_out, int out_size, void* d_ws, size_t ws_size,
                              hipStream_t stream) {
  (void)in_sizes; (void)n_in; (void)out_size; (void)ws_size;
  const float* x    = (const float*)d_in[0];
  const float* qkvw = (const float*)d_in[1];
  const float* qb   = (const float*)d_in[2];
  const float* vb   = (const float*)d_in[3];
  const float* ls   = (const float*)d_in[4];
  const float* cw1  = (const float*)d_in[5];
  const float* cb1  = (const float*)d_in[6];
  const float* cw2  = (const float*)d_in[7];
  const float* pw   = (const float*)d_in[8];
  const float* pb   = (const float*)d_in[9];
  const float* n1g  = (const float*)d_in[10];
  const float* n1b  = (const float*)d_in[11];
  const float* n2g  = (const float*)d_in[12];
  const float* n2b  = (const float*)d_in[13];
  const float* f1w  = (const float*)d_in[14];
  const float* f1b  = (const float*)d_in[15];
  const float* f2w  = (const float*)d_in[16];
  const float* f2b  = (const float*)d_in[17];
  float* out = (float*)d_out;

  char* ws = (char*)d_ws;
  ushort_t* wq_bf = (ushort_t*)ws;                 // 110592
  ushort_t* wp_bf = wq_bf + 110592;                // 36864
  ushort_t* w1_bf = wp_bf + 36864;                 // 147456
  ushort_t* w2_bf = w1_bf + 147456;                // 147456
  float*    tab_s = (float*)(w2_bf + 147456);      // 6*169 floats
  const size_t OFF_BIG = 1 << 20;
  ushort_t* qkv_out = (ushort_t*)(ws + OFF_BIG);
  ushort_t* xw_bf   = (ushort_t*)(ws + OFF_BIG + 115605504);
  ushort_t* attn_o  = (ushort_t*)(ws + OFF_BIG + 115605504);
  ushort_t* x1_bf   = (ushort_t*)(ws + OFF_BIG + 154140672);
  ushort_t* hmid    = (ushort_t*)(ws + OFF_BIG);   // 100352*768 bf16 over R1+R2

  cvt_kernel<<<(110592 + 255) / 256, 256, 0, stream>>>(qkvw, wq_bf, 110592);
  cvt_kernel<<<(36864  + 255) / 256, 256, 0, stream>>>(pw,   wp_bf, 36864);
  cvt_kernel<<<(147456 + 255) / 256, 256, 0, stream>>>(f1w,  w1_bf, 147456);
  cvt_kernel<<<(147456 + 255) / 256, 256, 0, stream>>>(f2w,  w2_bf, 147456);
  cpb_kernel<<<169, 256, 0, stream>>>(cw1, cb1, cw2, tab_s);
  gather_cvt_kernel<<<9408, 256, 0, stream>>>(x, xw_bf);

  // qkv
  gemm_n192<192, 0><<<dim3(784, 3), 512, 0, stream>>>(xw_bf, wq_bf, qb, vb, qkv_out, 576);
  // attention
  attn_kernel<<<dim3(2048, 6), 256, 0, stream>>>(qkv_out, ls, tab_s, attn_o);
  // proj (pre-LN, in-place over attn_o) + LN1/residual (split, R13 proven)
  gemm_n192<192, 2><<<dim3(784, 1), 512, 0, stream>>>(attn_o, wp_bf, pb, nullptr, attn_o, 192);
  ln_resid_kernel<<<25088, 256, 0, stream>>>(attn_o, x, n1g, n1b, x1_bf);
  // fc1 (silu)
  gemm_n192<192, 1><<<dim3(784, 4), 512, 0, stream>>>(x1_bf, w1_bf, f1b, nullptr, hmid, 768);
  // fc2 + LN2 + residual fused -> d_out fp32
  gemm_ln_fc2<<<784, 512, 0, stream>>>(hmid, w2_bf, f2b, n2g, n2b, x1_bf, out);
}

// Round 17
// 363.324 us; speedup vs baseline: 1.1370x; 1.0921x over previous
//
#include <hip/hip_runtime.h>

// ============================================================================
// Swin V2 block, round 17 = gload_lds 2-phase K-loop (R5/R8 machinery:
// k-permuted global storage + pre-swizzled sources, 1 barrier/iter)
// x 512-thread acc[2][6] occupancy structure (R13). By-subtraction evidence:
// R5/R8's 256-thread gload GEMMs ran ~50-60us vs today's 86 reg-staged.
// Stagers = t<256 (5 GLOADs), all 8 waves compute. fc2 keeps fused LN;
// proj split with perm-aware ln_resid.
// slot32(k) = 8*((k%16)/4) + 4*(k/16) + k%4 per 32-block (HW-verified R5/R8).
// MFMA C/D: col=lane%16, row=4*(lane/16)+reg.
// ============================================================================

typedef unsigned short ushort_t;
using f32x4  = __attribute__((ext_vector_type(4))) float;
using short8 = __attribute__((ext_vector_type(8))) short;

#define GLOAD(srcp, ldsp) __builtin_amdgcn_global_load_lds(                    \
    (const __attribute__((address_space(1))) void*)(srcp),                     \
    (__attribute__((address_space(3))) void*)(ldsp), 16, 0, 0)

__device__ __forceinline__ ushort_t f2bf(float f) {
  union { float f; unsigned u; } v; v.f = f;
  unsigned r = v.u + 0x7fffu + ((v.u >> 16) & 1u);
  return (ushort_t)(r >> 16);
}
__device__ __forceinline__ float bf2f(ushort_t u) {
  union { unsigned u; float f; } v; v.u = ((unsigned)u) << 16;
  return v.f;
}
__device__ __forceinline__ int slot32(int k) {
  return 8 * ((k & 15) >> 2) + ((k >> 4) << 2) + (k & 3);
}

// windowed-token index m -> image row index (same map for gather and scatter)
__device__ __forceinline__ int img_pos(int m) {
  int win = m / 49, n = m - win * 49;
  int b = win >> 6, wi = win & 63;
  int nd = n / 7, nm = n - nd * 7;
  int hs = (wi >> 3) * 7 + nd;
  int ws = (wi & 7) * 7 + nm;
  int h = hs + 3; if (h >= 56) h -= 56;
  int w = ws + 3; if (w >= 56) w -= 56;
  return b * 3136 + h * 56 + w;
}

__device__ __forceinline__ int region3(int a) { return a < 49 ? 0 : (a < 53 ? 1 : 2); }

// ---------------------------------------------------------------------------
// weight convert + k-permute within each 32-block of the K dim
__global__ void cvt_perm_kernel(const float* __restrict__ in, ushort_t* __restrict__ out,
                                int n, int K) {
  int i = blockIdx.x * 256 + threadIdx.x;
  if (i >= n) return;
  int row = i / K, j = i - row * K;
  int s = (j & ~31) + slot32(j & 31);
  out[row * K + s] = f2bf(in[i]);
}

// gather shifted windows + cvt + k-permute: xw[m][slot(c)] = bf16(x[img_pos(m)][c])
__global__ __launch_bounds__(256) void gather_cvt_kernel(
    const float* __restrict__ x, ushort_t* __restrict__ xw) {
  int i8 = blockIdx.x * 256 + threadIdx.x;      // 100352*24 tasks of 8 elems
  int m = i8 / 24, c8 = (i8 - m * 24) * 8;
  const float* p = x + (size_t)img_pos(m) * 192 + c8;
  float4 a = *(const float4*)p, b = *(const float4*)(p + 4);
  ushort_t* q = xw + (size_t)m * 192;
  int blk = c8 & ~31;
  int jj = (c8 & 31) >> 3;
  int b4 = ((jj & 1) << 4) | ((jj >> 1) << 2);
  *(ushort4*)(q + blk + b4)     = make_ushort4(f2bf(a.x), f2bf(a.y), f2bf(a.z), f2bf(a.w));
  *(ushort4*)(q + blk + b4 + 8) = make_ushort4(f2bf(b.x), f2bf(b.y), f2bf(b.z), f2bf(b.w));
}

// ---------------------------------------------------------------------------
// CPB: tab_s[head][e] = 16*sigmoid( relu(REL_TABLE[e] @ w1.T + b1) @ w2.T )
__global__ __launch_bounds__(256) void cpb_kernel(
    const float* __restrict__ w1, const float* __restrict__ b1,
    const float* __restrict__ w2, float* __restrict__ tab_s) {
  int e = blockIdx.x;            // 0..168
  int t = threadIdx.x;           // 0..255
  int i = e / 13, j = e - 13 * (e / 13);
  auto cval = [](int a) -> float {
    float r = (a - 6) * (8.0f / 6.0f);
    float v = log2f(fabsf(r) + 1.f) * (1.f / 3.f);
    return r < 0.f ? -v : v;
  };
  float ci = cval(i), cj = cval(j);
  float h = fmaxf(ci * w1[2 * t] + cj * w1[2 * t + 1] + b1[t], 0.f);
  __shared__ float red[256];
  for (int head = 0; head < 6; ++head) {
    red[t] = h * w2[head * 256 + t];
    __syncthreads();
    for (int st = 128; st > 0; st >>= 1) {
      if (t < st) red[t] += red[t + st];
      __syncthreads();
    }
    if (t == 0) tab_s[head * 169 + e] = 16.f / (1.f + __expf(-red[0]));
    __syncthreads();
  }
}

// ---------------------------------------------------------------------------
// gload_lds 2-phase GEMM, tile 128x192, BK=32, 512 threads = 8 waves
// (4x2 of 32x96), acc[2][6]. A,W k-permuted bf16; stagers t<256 issue 5
// GLOADs each; one barrier per K-iter. Output written k-permuted.
// MODE 0: qkv  MODE 1: fc1(silu)  MODE 2: proj (may alias A in-place)
template<int KTOT, int MODE>
__global__ __launch_bounds__(512, 4) void gemm_g512(
    const ushort_t* __restrict__ Ab, const ushort_t* __restrict__ W,
    const float* __restrict__ b0, const float* __restrict__ b1,
    ushort_t* out, int NTOT) {
  __shared__ ushort_t Al[2][4096];
  __shared__ ushort_t Bl[2][6144];
  int t = threadIdx.x;
  int m0 = blockIdx.x * 128, n0 = blockIdx.y * 192;
  int lane = t & 63, wid = t >> 6;
  int wm = wid >> 1, wn = wid & 1;
  int lr = lane & 15, lg = lane >> 4;

  bool stager = (t < 256);
  int sw = (t & 255) >> 6;        // staging wave 0..3
  int rloc = lane >> 2;
  int csrc = (lane & 3) ^ ((lane >> 3) & 3);
  int ca = sw * 2, cb = sw * 3;
  const ushort_t* sA0 = Ab + (size_t)(m0 + ca * 16      + rloc) * KTOT + csrc * 8;
  const ushort_t* sA1 = Ab + (size_t)(m0 + ca * 16 + 16 + rloc) * KTOT + csrc * 8;
  const ushort_t* sB0 = W  + (size_t)(n0 + cb * 16      + rloc) * KTOT + csrc * 8;
  const ushort_t* sB1 = W  + (size_t)(n0 + cb * 16 + 16 + rloc) * KTOT + csrc * 8;
  const ushort_t* sB2 = W  + (size_t)(n0 + cb * 16 + 32 + rloc) * KTOT + csrc * 8;

  auto STAGE = [&](int buf, int kt) {
    GLOAD(sA0 + kt, &Al[buf][(ca + 0) * 512]);
    GLOAD(sA1 + kt, &Al[buf][(ca + 1) * 512]);
    GLOAD(sB0 + kt, &Bl[buf][(cb + 0) * 512]);
    GLOAD(sB1 + kt, &Bl[buf][(cb + 1) * 512]);
    GLOAD(sB2 + kt, &Bl[buf][(cb + 2) * 512]);
  };

  int coff = (lg ^ ((lr >> 1) & 3)) * 8;

  f32x4 acc[2][6];
#pragma unroll
  for (int a = 0; a < 2; ++a)
#pragma unroll
    for (int b = 0; b < 6; ++b) acc[a][b] = (f32x4){0.f, 0.f, 0.f, 0.f};

  const int NT = KTOT / 32;
  if (stager) STAGE(0, 0);
  __syncthreads();
  int cur = 0;
  for (int it = 0; it < NT; ++it) {
    if (stager && it + 1 < NT) STAGE(cur ^ 1, (it + 1) * 32);
    short8 af[2], bfv[6];
#pragma unroll
    for (int fm = 0; fm < 2; ++fm)
      af[fm] = *(const short8*)&Al[cur][(wm * 32 + fm * 16 + lr) * 32 + coff];
#pragma unroll
    for (int fn = 0; fn < 6; ++fn)
      bfv[fn] = *(const short8*)&Bl[cur][(wn * 96 + fn * 16 + lr) * 32 + coff];
#pragma unroll
    for (int fm = 0; fm < 2; ++fm)
#pragma unroll
      for (int fn = 0; fn < 6; ++fn)
        acc[fm][fn] = __builtin_amdgcn_mfma_f32_16x16x32_bf16(af[fm], bfv[fn], acc[fm][fn], 0, 0, 0);
    __syncthreads();
    cur ^= 1;
  }

#pragma unroll
  for (int fm = 0; fm < 2; ++fm) {
#pragma unroll
    for (int fn = 0; fn < 6; ++fn) {
      int col = n0 + wn * 96 + fn * 16 + lr;               // true col (bias)
      int colp = n0 + wn * 96 + ((fn >> 1) << 5) +         // permuted col (store)
                 ((lr >> 2) << 3) + ((fn & 1) << 2) + (lr & 3);
      float bias;
      if (MODE == 0) bias = (col < 192) ? b0[col] : ((col < 384) ? 0.f : b1[col - 384]);
      else           bias = b0[col];
#pragma unroll
      for (int r = 0; r < 4; ++r) {
        int row = m0 + wm * 32 + fm * 16 + lg * 4 + r;
        float v = acc[fm][fn][r] + bias;
        if (MODE == 1) v = v / (1.f + __expf(-v));   // silu
        out[(size_t)row * NTOT + colp] = f2bf(v);
      }
    }
  }
}

// ---------------------------------------------------------------------------
// fc2 (K=768) gload 2-phase + fused LN2 + residual. resid = x1_bf (permuted),
// out = d_out fp32 true cols.
__global__ __launch_bounds__(512, 4) void gemm_g512_lnfc2(
    const ushort_t* __restrict__ Ab, const ushort_t* __restrict__ W,
    const float* __restrict__ bias, const float* __restrict__ gamma,
    const float* __restrict__ beta, const ushort_t* __restrict__ residb,
    float* __restrict__ outf) {
  const int KTOT = 768;
  __shared__ ushort_t Al[2][4096];
  __shared__ ushort_t Bl[2][6144];
  int t = threadIdx.x;
  int m0 = blockIdx.x * 128;
  int lane = t & 63, wid = t >> 6;
  int wm = wid >> 1, wn = wid & 1;
  int lr = lane & 15, lg = lane >> 4;

  bool stager = (t < 256);
  int sw = (t & 255) >> 6;
  int rloc = lane >> 2;
  int csrc = (lane & 3) ^ ((lane >> 3) & 3);
  int ca = sw * 2, cb = sw * 3;
  const ushort_t* sA0 = Ab + (size_t)(m0 + ca * 16      + rloc) * KTOT + csrc * 8;
  const ushort_t* sA1 = Ab + (size_t)(m0 + ca * 16 + 16 + rloc) * KTOT + csrc * 8;
  const ushort_t* sB0 = W  + (size_t)(cb * 16      + rloc) * KTOT + csrc * 8;
  const ushort_t* sB1 = W  + (size_t)(cb * 16 + 16 + rloc) * KTOT + csrc * 8;
  const ushort_t* sB2 = W  + (size_t)(cb * 16 + 32 + rloc) * KTOT + csrc * 8;

  auto STAGE = [&](int buf, int kt) {
    GLOAD(sA0 + kt, &Al[buf][(ca + 0) * 512]);
    GLOAD(sA1 + kt, &Al[buf][(ca + 1) * 512]);
    GLOAD(sB0 + kt, &Bl[buf][(cb + 0) * 512]);
    GLOAD(sB1 + kt, &Bl[buf][(cb + 1) * 512]);
    GLOAD(sB2 + kt, &Bl[buf][(cb + 2) * 512]);
  };

  int coff = (lg ^ ((lr >> 1) & 3)) * 8;

  f32x4 acc[2][6];
#pragma unroll
  for (int a = 0; a < 2; ++a)
#pragma unroll
    for (int b = 0; b < 6; ++b) acc[a][b] = (f32x4){0.f, 0.f, 0.f, 0.f};

  const int NT = KTOT / 32;
  if (stager) STAGE(0, 0);
  __syncthreads();
  int cur = 0;
  for (int it = 0; it < NT; ++it) {
    if (stager && it + 1 < NT) STAGE(cur ^ 1, (it + 1) * 32);
    short8 af[2], bfv[6];
#pragma unroll
    for (int fm = 0; fm < 2; ++fm)
      af[fm] = *(const short8*)&Al[cur][(wm * 32 + fm * 16 + lr) * 32 + coff];
#pragma unroll
    for (int fn = 0; fn < 6; ++fn)
      bfv[fn] = *(const short8*)&Bl[cur][(wn * 96 + fn * 16 + lr) * 32 + coff];
#pragma unroll
    for (int fm = 0; fm < 2; ++fm)
#pragma unroll
      for (int fn = 0; fn < 6; ++fn)
        acc[fm][fn] = __builtin_amdgcn_mfma_f32_16x16x32_bf16(af[fm], bfv[fn], acc[fm][fn], 0, 0, 0);
    __syncthreads();
    cur ^= 1;
  }

  // LN epilogue. part aliases dead Bl[0]: [2][128][2] floats = 2KB
  float* part = (float*)&Bl[0][0];
#pragma unroll
  for (int fm = 0; fm < 2; ++fm) {
#pragma unroll
    for (int r = 0; r < 4; ++r) {
      float s1 = 0.f, s2 = 0.f;
#pragma unroll
      for (int fn = 0; fn < 6; ++fn) {
        int col = wn * 96 + fn * 16 + lr;
        float v = acc[fm][fn][r] + bias[col];
        acc[fm][fn][r] = v;
        s1 += v; s2 += v * v;
      }
#pragma unroll
      for (int off = 1; off < 16; off <<= 1) {
        s1 += __shfl_xor(s1, off);
        s2 += __shfl_xor(s2, off);
      }
      if (lr == 0) {
        int lrow = wm * 32 + fm * 16 + lg * 4 + r;
        part[(wn * 128 + lrow) * 2 + 0] = s1;
        part[(wn * 128 + lrow) * 2 + 1] = s2;
      }
    }
  }
  __syncthreads();
#pragma unroll
  for (int fm = 0; fm < 2; ++fm) {
#pragma unroll
    for (int r = 0; r < 4; ++r) {
      int lrow = wm * 32 + fm * 16 + lg * 4 + r;
      float s1 = part[lrow * 2 + 0] + part[(128 + lrow) * 2 + 0];
      float s2 = part[lrow * 2 + 1] + part[(128 + lrow) * 2 + 1];
      float mean = s1 * (1.f / 192.f);
      float var  = s2 * (1.f / 192.f) - mean * mean;
      float rstd = rsqrtf(fmaxf(var, 0.f) + 1e-5f);
      size_t og = (size_t)(m0 + lrow) * 192;
#pragma unroll
      for (int fn = 0; fn < 6; ++fn) {
        int col = wn * 96 + fn * 16 + lr;
        int colp = (col & ~31) + slot32(col & 31);
        float l = (acc[fm][fn][r] - mean) * rstd * gamma[col] + beta[col];
        outf[og + col] = bf2f(residb[og + colp]) + l;
      }
    }
  }
}

// ---------------------------------------------------------------------------
// Streaming LayerNorm + residual for proj output. pre is PERMUTED bf16 in
// window order; out x1_bf[img_pos] permuted = bf16(x[img_pos] + LN(pre)).
__global__ __launch_bounds__(256) void ln_resid_kernel(
    const ushort_t* __restrict__ pre, const float* __restrict__ residf,
    const float* __restrict__ gamma, const float* __restrict__ beta,
    ushort_t* __restrict__ outb) {
  int m = (blockIdx.x * 256 + threadIdx.x) >> 6;   // row
  int lane = threadIdx.x & 63;
  int c0 = lane, c1 = lane + 64, c2 = lane + 128;
  int s0 = (c0 & ~31) + slot32(c0 & 31);
  int s1c = (c1 & ~31) + slot32(c1 & 31);
  int s2c = (c2 & ~31) + slot32(c2 & 31);
  const ushort_t* p = pre + (size_t)m * 192;
  float v0 = bf2f(p[s0]), v1 = bf2f(p[s1c]), v2 = bf2f(p[s2c]);
  float s1 = v0 + v1 + v2;
  float s2 = v0 * v0 + v1 * v1 + v2 * v2;
#pragma unroll
  for (int o = 1; o < 64; o <<= 1) {
    s1 += __shfl_xor(s1, o);
    s2 += __shfl_xor(s2, o);
  }
  float mean = s1 * (1.f / 192.f);
  float var  = s2 * (1.f / 192.f) - mean * mean;
  float rstd = rsqrtf(fmaxf(var, 0.f) + 1e-5f);
  float l0 = (v0 - mean) * rstd * gamma[c0] + beta[c0];
  float l1 = (v1 - mean) * rstd * gamma[c1] + beta[c1];
  float l2 = (v2 - mean) * rstd * gamma[c2] + beta[c2];
  size_t og = (size_t)img_pos(m) * 192;
  outb[og + s0]  = f2bf(residf[og + c0] + l0);
  outb[og + s1c] = f2bf(residf[og + c1] + l1);
  outb[og + s2c] = f2bf(residf[og + c2] + l2);
}

// ---------------------------------------------------------------------------
// Attention (MFMA): block = (window, head), 256 threads = 4 waves.
// qkv k-permuted storage -> staging straight copy; V slot-perm propagates
// into attn_o (permuted, as proj expects). (R8 verbatim)
__global__ __launch_bounds__(256) void attn_kernel(
    const ushort_t* __restrict__ qkv, const float* __restrict__ logit_scale,
    const float* __restrict__ tab_s, ushort_t* __restrict__ attn_out) {
  __shared__ ushort_t qs[64][40];
  __shared__ ushort_t ksl[64][40];
  __shared__ ushort_t vsl[32][80];
  __shared__ ushort_t ps[64][80];
  __shared__ float tab_l[169];
  int win = blockIdx.x, head = blockIdx.y;
  int t = threadIdx.x;
  int wi = win & 63;
  int wh0 = (wi >> 3) * 7, ww0 = (wi & 7) * 7;
  size_t base = (size_t)win * 49 * 576 + head * 32;

  for (int u = t; u < 169; u += 256) tab_l[u] = tab_s[head * 169 + u];

  for (int u = t; u < 240; u += 256) {
    int arr = u / 120, v = u - arr * 120;
    int r = 49 + (v >> 3), c4 = (v & 7) << 2;
    ushort_t* p = arr ? &ksl[r][c4] : &qs[r][c4];
    *(ushort4*)p = make_ushort4(0, 0, 0, 0);
  }

  for (int u = t; u < 2048; u += 256) {
    int key = u >> 5, d = u & 31;
    ushort_t val = 0;
    if (key < 49) val = qkv[base + (size_t)key * 576 + 384 + d];
    int kk = key & 31;
    int pc = ((key >> 5) << 5) + 8 * ((kk >> 2) & 3) + 4 * (kk >> 4) + (kk & 3);
    vsl[d][pc] = val;
  }

  float scale = __expf(fminf(logit_scale[head], 4.605170186f));  // ln(100)

  if (t < 196) {
    int r = t >> 2, c = t & 3;
    const ushort_t* qp = qkv + base + (size_t)r * 576 + c * 8;
    ushort4 qa = *(const ushort4*)qp,         qb = *(const ushort4*)(qp + 4);
    ushort4 ka = *(const ushort4*)(qp + 192), kb = *(const ushort4*)(qp + 196);
    float qf[8] = {bf2f(qa.x), bf2f(qa.y), bf2f(qa.z), bf2f(qa.w),
                   bf2f(qb.x), bf2f(qb.y), bf2f(qb.z), bf2f(qb.w)};
    float kf[8] = {bf2f(ka.x), bf2f(ka.y), bf2f(ka.z), bf2f(ka.w),
                   bf2f(kb.x), bf2f(kb.y), bf2f(kb.z), bf2f(kb.w)};
    float sq = 0.f, sk = 0.f;
#pragma unroll
    for (int d = 0; d < 8; ++d) { sq += qf[d] * qf[d]; sk += kf[d] * kf[d]; }
    sq += __shfl_xor(sq, 1); sq += __shfl_xor(sq, 2);
    sk += __shfl_xor(sk, 1); sk += __shfl_xor(sk, 2);
    float rq = scale / fmaxf(sqrtf(sq), 1e-12f);
    float rk = 1.f   / fmaxf(sqrtf(sk), 1e-12f);
    ushort_t* qd = &qs[r][c * 8];
    *(ushort4*)(qd + 0) = make_ushort4(f2bf(qf[0]*rq), f2bf(qf[1]*rq), f2bf(qf[2]*rq), f2bf(qf[3]*rq));
    *(ushort4*)(qd + 4) = make_ushort4(f2bf(qf[4]*rq), f2bf(qf[5]*rq), f2bf(qf[6]*rq), f2bf(qf[7]*rq));
    ushort_t* kd = &ksl[r][c * 8];
    *(ushort4*)(kd + 0) = make_ushort4(f2bf(kf[0]*rk), f2bf(kf[1]*rk), f2bf(kf[2]*rk), f2bf(kf[3]*rk));
    *(ushort4*)(kd + 4) = make_ushort4(f2bf(kf[4]*rk), f2bf(kf[5]*rk), f2bf(kf[6]*rk), f2bf(kf[7]*rk));
  }
  __syncthreads();

  int lane = t & 63, w = t >> 6;
  int lr = lane & 15, lg = lane >> 4;

  short8 aq = *(const short8*)&qs[w * 16 + lr][lg * 8];
  f32x4 acc[4];
#pragma unroll
  for (int fn = 0; fn < 4; ++fn) {
    acc[fn] = (f32x4){0.f, 0.f, 0.f, 0.f};
    short8 bk = *(const short8*)&ksl[fn * 16 + lr][lg * 8];
    acc[fn] = __builtin_amdgcn_mfma_f32_16x16x32_bf16(aq, bk, acc[fn], 0, 0, 0);
  }

  float rsum[4];
#pragma unroll
  for (int r = 0; r < 4; ++r) {
    int row = w * 16 + lg * 4 + r;
    int rd = (row * 9363) >> 16, rm = row - 7 * rd;
    int gr = region3(wh0 + rd) * 3 + region3(ww0 + rm);
    bool rv = row < 49;
    float sv[4];
#pragma unroll
    for (int fn = 0; fn < 4; ++fn) {
      int col = fn * 16 + lr;
      int jd = (col * 9363) >> 16, jm = col - 7 * jd;
      int gj = region3(wh0 + jd) * 3 + region3(ww0 + jm);
      bool cv = rv && (col < 49);
      int idx = cv ? (rd - jd + 6) * 13 + (rm - jm + 6) : 0;
      float s = acc[fn][r] + tab_l[idx] + (gr == gj ? 0.f : -100.f);
      sv[fn] = cv ? s : -1e30f;
    }
    float m = fmaxf(fmaxf(sv[0], sv[1]), fmaxf(sv[2], sv[3]));
#pragma unroll
    for (int o = 1; o < 16; o <<= 1) m = fmaxf(m, __shfl_xor(m, o));
    float sum = 0.f;
#pragma unroll
    for (int fn = 0; fn < 4; ++fn) {
      float e = __expf(sv[fn] - m);
      sum += e;
      int pc = ((fn >> 1) << 5) + 8 * (lr >> 2) + ((fn & 1) << 2) + (lr & 3);
      ps[row][pc] = f2bf(e);
    }
#pragma unroll
    for (int o = 1; o < 16; o <<= 1) sum += __shfl_xor(sum, o);
    rsum[r] = 1.f / sum;
  }
  __syncthreads();

  short8 ap0 = *(const short8*)&ps[w * 16 + lr][lg * 8];
  short8 ap1 = *(const short8*)&ps[w * 16 + lr][32 + lg * 8];
  f32x4 o2[2];
#pragma unroll
  for (int f = 0; f < 2; ++f) {
    o2[f] = (f32x4){0.f, 0.f, 0.f, 0.f};
    short8 bv0 = *(const short8*)&vsl[f * 16 + lr][lg * 8];
    short8 bv1 = *(const short8*)&vsl[f * 16 + lr][32 + lg * 8];
    o2[f] = __builtin_amdgcn_mfma_f32_16x16x32_bf16(ap0, bv0, o2[f], 0, 0, 0);
    o2[f] = __builtin_amdgcn_mfma_f32_16x16x32_bf16(ap1, bv1, o2[f], 0, 0, 0);
  }
#pragma unroll
  for (int f = 0; f < 2; ++f) {
#pragma unroll
    for (int r = 0; r < 4; ++r) {
      int row = w * 16 + lg * 4 + r;
      if (row < 49)
        attn_out[((size_t)win * 49 + row) * 192 + head * 32 + f * 16 + lr] =
            f2bf(o2[f][r] * rsum[r]);
    }
  }
}

// ---------------------------------------------------------------------------
extern "C" void kernel_launch(void* const* d_in, const int* in_sizes, int n_in,
                              void* d_out, int out_size, void* d_ws, size_t ws_size,
                              hipStream_t stream) {
  (void)in_sizes; (void)n_in; (void)out_size; (void)ws_size;
  const float* x    = (const float*)d_in[0];
  const float* qkvw = (const float*)d_in[1];
  const float* qb   = (const float*)d_in[2];
  const float* vb   = (const float*)d_in[3];
  const float* ls   = (const float*)d_in[4];
  const float* cw1  = (const float*)d_in[5];
  const float* cb1  = (const float*)d_in[6];
  const float* cw2  = (const float*)d_in[7];
  const float* pw   = (const float*)d_in[8];
  const float* pb   = (const float*)d_in[9];
  const float* n1g  = (const float*)d_in[10];
  const float* n1b  = (const float*)d_in[11];
  const float* n2g  = (const float*)d_in[12];
  const float* n2b  = (const float*)d_in[13];
  const float* f1w  = (const float*)d_in[14];
  const float* f1b  = (const float*)d_in[15];
  const float* f2w  = (const float*)d_in[16];
  const float* f2b  = (const float*)d_in[17];
  float* out = (float*)d_out;

  char* ws = (char*)d_ws;
  ushort_t* wq_bf = (ushort_t*)ws;                 // 110592 (perm K=192)
  ushort_t* wp_bf = wq_bf + 110592;                // 36864  (perm K=192)
  ushort_t* w1_bf = wp_bf + 36864;                 // 147456 (perm K=192)
  ushort_t* w2_bf = w1_bf + 147456;                // 147456 (perm K=768)
  float*    tab_s = (float*)(w2_bf + 147456);      // 6*169 floats
  const size_t OFF_BIG = 1 << 20;
  ushort_t* qkv_out = (ushort_t*)(ws + OFF_BIG);
  ushort_t* xw_bf   = (ushort_t*)(ws + OFF_BIG + 115605504);
  ushort_t* attn_o  = (ushort_t*)(ws + OFF_BIG + 115605504);
  ushort_t* x1_bf   = (ushort_t*)(ws + OFF_BIG + 154140672);
  ushort_t* hmid    = (ushort_t*)(ws + OFF_BIG);   // 100352*768 bf16 over R1+R2

  cvt_perm_kernel<<<(110592 + 255) / 256, 256, 0, stream>>>(qkvw, wq_bf, 110592, 192);
  cvt_perm_kernel<<<(36864  + 255) / 256, 256, 0, stream>>>(pw,   wp_bf, 36864, 192);
  cvt_perm_kernel<<<(147456 + 255) / 256, 256, 0, stream>>>(f1w,  w1_bf, 147456, 192);
  cvt_perm_kernel<<<(147456 + 255) / 256, 256, 0, stream>>>(f2w,  w2_bf, 147456, 768);
  cpb_kernel<<<169, 256, 0, stream>>>(cw1, cb1, cw2, tab_s);
  gather_cvt_kernel<<<9408, 256, 0, stream>>>(x, xw_bf);

  // qkv (gload 2-phase, 512 threads)
  gemm_g512<192, 0><<<dim3(784, 3), 512, 0, stream>>>(xw_bf, wq_bf, qb, vb, qkv_out, 576);
  // attention
  attn_kernel<<<dim3(2048, 6), 256, 0, stream>>>(qkv_out, ls, tab_s, attn_o);
  // proj (pre-LN, in-place over attn_o) + perm-aware LN1/residual
  gemm_g512<192, 2><<<dim3(784, 1), 512, 0, stream>>>(attn_o, wp_bf, pb, nullptr, attn_o, 192);
  ln_resid_kernel<<<25088, 256, 0, stream>>>(attn_o, x, n1g, n1b, x1_bf);
  // fc1 (silu)
  gemm_g512<192, 1><<<dim3(784, 4), 512, 0, stream>>>(x1_bf, w1_bf, f1b, nullptr, hmid, 768);
  // fc2 + LN2 + residual fused -> d_out fp32
  gemm_g512_lnfc2<<<784, 512, 0, stream>>>(hmid, w2_bf, f2b, n2g, n2b, x1_bf, out);
}

// Round 18
// 359.138 us; speedup vs baseline: 1.1503x; 1.0117x over previous
//
#include <hip/hip_runtime.h>

// ============================================================================
// Swin V2 block, round 18 = R17 base (363us best) + 3-buffer counted-vmcnt
// pipeline (T3/T4) for qkv/fc1 ONLY. Theory: 108 unified regs -> 16 waves/CU
// cap; 2-buffer loop forces vmcnt drain of the single in-flight stage each
// iter -> iter = max(compute ~200cy, load ~400-900cy). 3 bufs + vmcnt(10)
// keeps 2 stages in flight across raw barriers. proj/fc2 keep R17 loop.
// vmcnt derivation: 5 gloads/stage; wait "outstanding<=10" <=> stage(it)
// complete (in-order completion). Tail: 5 then 0.
// slot32(k) = 8*((k%16)/4) + 4*(k/16) + k%4 (HW-verified). C/D: col=lane%16,
// row=4*(lane/16)+reg.
// ============================================================================

typedef unsigned short ushort_t;
using f32x4  = __attribute__((ext_vector_type(4))) float;
using short8 = __attribute__((ext_vector_type(8))) short;

#define GLOAD(srcp, ldsp) __builtin_amdgcn_global_load_lds(                    \
    (const __attribute__((address_space(1))) void*)(srcp),                     \
    (__attribute__((address_space(3))) void*)(ldsp), 16, 0, 0)

__device__ __forceinline__ ushort_t f2bf(float f) {
  union { float f; unsigned u; } v; v.f = f;
  unsigned r = v.u + 0x7fffu + ((v.u >> 16) & 1u);
  return (ushort_t)(r >> 16);
}
__device__ __forceinline__ float bf2f(ushort_t u) {
  union { unsigned u; float f; } v; v.u = ((unsigned)u) << 16;
  return v.f;
}
__device__ __forceinline__ int slot32(int k) {
  return 8 * ((k & 15) >> 2) + ((k >> 4) << 2) + (k & 3);
}

// windowed-token index m -> image row index (same map for gather and scatter)
__device__ __forceinline__ int img_pos(int m) {
  int win = m / 49, n = m - win * 49;
  int b = win >> 6, wi = win & 63;
  int nd = n / 7, nm = n - nd * 7;
  int hs = (wi >> 3) * 7 + nd;
  int ws = (wi & 7) * 7 + nm;
  int h = hs + 3; if (h >= 56) h -= 56;
  int w = ws + 3; if (w >= 56) w -= 56;
  return b * 3136 + h * 56 + w;
}

__device__ __forceinline__ int region3(int a) { return a < 49 ? 0 : (a < 53 ? 1 : 2); }

// ---------------------------------------------------------------------------
// All four weight tensors converted + k-permuted in ONE launch.
__global__ __launch_bounds__(256) void cvt_perm_all(
    const float* __restrict__ qkvw, const float* __restrict__ pw,
    const float* __restrict__ f1w, const float* __restrict__ f2w,
    ushort_t* __restrict__ wq, ushort_t* __restrict__ wp,
    ushort_t* __restrict__ w1, ushort_t* __restrict__ w2) {
  int i = blockIdx.x * 256 + threadIdx.x;   // 0..442367
  if (i >= 442368) return;
  const float* in; ushort_t* out; int K, j;
  if (i < 110592)      { j = i;          in = qkvw; out = wq; K = 192; }
  else if (i < 147456) { j = i - 110592; in = pw;   out = wp; K = 192; }
  else if (i < 294912) { j = i - 147456; in = f1w;  out = w1; K = 192; }
  else                 { j = i - 294912; in = f2w;  out = w2; K = 768; }
  int row = j / K, c = j - row * K;
  out[row * K + (c & ~31) + slot32(c & 31)] = f2bf(in[j]);
}

// gather shifted windows + cvt + k-permute: xw[m][slot(c)] = bf16(x[img_pos(m)][c])
__global__ __launch_bounds__(256) void gather_cvt_kernel(
    const float* __restrict__ x, ushort_t* __restrict__ xw) {
  int i8 = blockIdx.x * 256 + threadIdx.x;      // 100352*24 tasks of 8 elems
  int m = i8 / 24, c8 = (i8 - m * 24) * 8;
  const float* p = x + (size_t)img_pos(m) * 192 + c8;
  float4 a = *(const float4*)p, b = *(const float4*)(p + 4);
  ushort_t* q = xw + (size_t)m * 192;
  int blk = c8 & ~31;
  int jj = (c8 & 31) >> 3;
  int b4 = ((jj & 1) << 4) | ((jj >> 1) << 2);
  *(ushort4*)(q + blk + b4)     = make_ushort4(f2bf(a.x), f2bf(a.y), f2bf(a.z), f2bf(a.w));
  *(ushort4*)(q + blk + b4 + 8) = make_ushort4(f2bf(b.x), f2bf(b.y), f2bf(b.z), f2bf(b.w));
}

// ---------------------------------------------------------------------------
// CPB: tab_s[head][e] = 16*sigmoid( relu(REL_TABLE[e] @ w1.T + b1) @ w2.T )
__global__ __launch_bounds__(256) void cpb_kernel(
    const float* __restrict__ w1, const float* __restrict__ b1,
    const float* __restrict__ w2, float* __restrict__ tab_s) {
  int e = blockIdx.x;            // 0..168
  int t = threadIdx.x;           // 0..255
  int i = e / 13, j = e - 13 * (e / 13);
  auto cval = [](int a) -> float {
    float r = (a - 6) * (8.0f / 6.0f);
    float v = log2f(fabsf(r) + 1.f) * (1.f / 3.f);
    return r < 0.f ? -v : v;
  };
  float ci = cval(i), cj = cval(j);
  float h = fmaxf(ci * w1[2 * t] + cj * w1[2 * t + 1] + b1[t], 0.f);
  __shared__ float red[256];
  for (int head = 0; head < 6; ++head) {
    red[t] = h * w2[head * 256 + t];
    __syncthreads();
    for (int st = 128; st > 0; st >>= 1) {
      if (t < st) red[t] += red[t + st];
      __syncthreads();
    }
    if (t == 0) tab_s[head * 169 + e] = 16.f / (1.f + __expf(-red[0]));
    __syncthreads();
  }
}

// ---------------------------------------------------------------------------
// 3-buffer counted-vmcnt gload GEMM (T3/T4), tile 128x192, BK=32, 512 thr
// = 8 waves (4x2 of 32x96), acc[2][6]. Stagers t<256: 5 GLOADs/stage; 2
// stages in flight across raw barriers via vmcnt(10). Output k-permuted.
// MODE 0: qkv  MODE 1: fc1(silu)
template<int KTOT, int MODE>
__global__ __launch_bounds__(512, 4) void gemm_p3(
    const ushort_t* __restrict__ Ab, const ushort_t* __restrict__ W,
    const float* __restrict__ b0, const float* __restrict__ b1,
    ushort_t* __restrict__ out, int NTOT) {
  __shared__ ushort_t Al[3][4096];
  __shared__ ushort_t Bl[3][6144];
  int t = threadIdx.x;
  int m0 = blockIdx.x * 128, n0 = blockIdx.y * 192;
  int lane = t & 63, wid = t >> 6;
  int wm = wid >> 1, wn = wid & 1;
  int lr = lane & 15, lg = lane >> 4;

  bool stager = (t < 256);
  int sw = (t & 255) >> 6;
  int rloc = lane >> 2;
  int csrc = (lane & 3) ^ ((lane >> 3) & 3);
  int ca = sw * 2, cb = sw * 3;
  const ushort_t* sA0 = Ab + (size_t)(m0 + ca * 16      + rloc) * KTOT + csrc * 8;
  const ushort_t* sA1 = Ab + (size_t)(m0 + ca * 16 + 16 + rloc) * KTOT + csrc * 8;
  const ushort_t* sB0 = W  + (size_t)(n0 + cb * 16      + rloc) * KTOT + csrc * 8;
  const ushort_t* sB1 = W  + (size_t)(n0 + cb * 16 + 16 + rloc) * KTOT + csrc * 8;
  const ushort_t* sB2 = W  + (size_t)(n0 + cb * 16 + 32 + rloc) * KTOT + csrc * 8;

  auto STAGE = [&](int buf, int kt) {
    GLOAD(sA0 + kt, &Al[buf][(ca + 0) * 512]);
    GLOAD(sA1 + kt, &Al[buf][(ca + 1) * 512]);
    GLOAD(sB0 + kt, &Bl[buf][(cb + 0) * 512]);
    GLOAD(sB1 + kt, &Bl[buf][(cb + 1) * 512]);
    GLOAD(sB2 + kt, &Bl[buf][(cb + 2) * 512]);
  };

  int coff = (lg ^ ((lr >> 1) & 3)) * 8;

  f32x4 acc[2][6];
#pragma unroll
  for (int a = 0; a < 2; ++a)
#pragma unroll
    for (int b = 0; b < 6; ++b) acc[a][b] = (f32x4){0.f, 0.f, 0.f, 0.f};

  const int NT = KTOT / 32;
  if (stager) { STAGE(0, 0); STAGE(1, 32); }
  for (int it = 0; it < NT; ++it) {
    int cur = it % 3;
    if (stager) {
      if (it + 2 < NT) {
        STAGE((it + 2) % 3, (it + 2) * 32);     // overwrites buf read in it-1
        asm volatile("s_waitcnt vmcnt(10)" ::: "memory");   // stage(it) done
      } else if (it + 1 < NT) {
        asm volatile("s_waitcnt vmcnt(5)" ::: "memory");
      } else {
        asm volatile("s_waitcnt vmcnt(0)" ::: "memory");
      }
    }
    __builtin_amdgcn_sched_barrier(0);
    __builtin_amdgcn_s_barrier();               // buf[cur] visible to all
    __builtin_amdgcn_sched_barrier(0);
    short8 af[2], bfv[6];
#pragma unroll
    for (int fm = 0; fm < 2; ++fm)
      af[fm] = *(const short8*)&Al[cur][(wm * 32 + fm * 16 + lr) * 32 + coff];
#pragma unroll
    for (int fn = 0; fn < 6; ++fn)
      bfv[fn] = *(const short8*)&Bl[cur][(wn * 96 + fn * 16 + lr) * 32 + coff];
#pragma unroll
    for (int fm = 0; fm < 2; ++fm)
#pragma unroll
      for (int fn = 0; fn < 6; ++fn)
        acc[fm][fn] = __builtin_amdgcn_mfma_f32_16x16x32_bf16(af[fm], bfv[fn], acc[fm][fn], 0, 0, 0);
    __builtin_amdgcn_sched_barrier(0);
    __builtin_amdgcn_s_barrier();               // reads of buf[cur] retired
    __builtin_amdgcn_sched_barrier(0);
  }

#pragma unroll
  for (int fm = 0; fm < 2; ++fm) {
#pragma unroll
    for (int fn = 0; fn < 6; ++fn) {
      int col = n0 + wn * 96 + fn * 16 + lr;               // true col (bias)
      int colp = n0 + wn * 96 + ((fn >> 1) << 5) +         // permuted col (store)
                 ((lr >> 2) << 3) + ((fn & 1) << 2) + (lr & 3);
      float bias;
      if (MODE == 0) bias = (col < 192) ? b0[col] : ((col < 384) ? 0.f : b1[col - 384]);
      else           bias = b0[col];
#pragma unroll
      for (int r = 0; r < 4; ++r) {
        int row = m0 + wm * 32 + fm * 16 + lg * 4 + r;
        float v = acc[fm][fn][r] + bias;
        if (MODE == 1) v = v / (1.f + __expf(-v));   // silu
        out[(size_t)row * NTOT + colp] = f2bf(v);
      }
    }
  }
}

// ---------------------------------------------------------------------------
// gload_lds 2-phase GEMM (R17 verbatim). MODE 2: proj (may alias A in-place)
template<int KTOT, int MODE>
__global__ __launch_bounds__(512, 4) void gemm_g512(
    const ushort_t* __restrict__ Ab, const ushort_t* __restrict__ W,
    const float* __restrict__ b0, const float* __restrict__ b1,
    ushort_t* out, int NTOT) {
  __shared__ ushort_t Al[2][4096];
  __shared__ ushort_t Bl[2][6144];
  int t = threadIdx.x;
  int m0 = blockIdx.x * 128, n0 = blockIdx.y * 192;
  int lane = t & 63, wid = t >> 6;
  int wm = wid >> 1, wn = wid & 1;
  int lr = lane & 15, lg = lane >> 4;

  bool stager = (t < 256);
  int sw = (t & 255) >> 6;
  int rloc = lane >> 2;
  int csrc = (lane & 3) ^ ((lane >> 3) & 3);
  int ca = sw * 2, cb = sw * 3;
  const ushort_t* sA0 = Ab + (size_t)(m0 + ca * 16      + rloc) * KTOT + csrc * 8;
  const ushort_t* sA1 = Ab + (size_t)(m0 + ca * 16 + 16 + rloc) * KTOT + csrc * 8;
  const ushort_t* sB0 = W  + (size_t)(n0 + cb * 16      + rloc) * KTOT + csrc * 8;
  const ushort_t* sB1 = W  + (size_t)(n0 + cb * 16 + 16 + rloc) * KTOT + csrc * 8;
  const ushort_t* sB2 = W  + (size_t)(n0 + cb * 16 + 32 + rloc) * KTOT + csrc * 8;

  auto STAGE = [&](int buf, int kt) {
    GLOAD(sA0 + kt, &Al[buf][(ca + 0) * 512]);
    GLOAD(sA1 + kt, &Al[buf][(ca + 1) * 512]);
    GLOAD(sB0 + kt, &Bl[buf][(cb + 0) * 512]);
    GLOAD(sB1 + kt, &Bl[buf][(cb + 1) * 512]);
    GLOAD(sB2 + kt, &Bl[buf][(cb + 2) * 512]);
  };

  int coff = (lg ^ ((lr >> 1) & 3)) * 8;

  f32x4 acc[2][6];
#pragma unroll
  for (int a = 0; a < 2; ++a)
#pragma unroll
    for (int b = 0; b < 6; ++b) acc[a][b] = (f32x4){0.f, 0.f, 0.f, 0.f};

  const int NT = KTOT / 32;
  if (stager) STAGE(0, 0);
  __syncthreads();
  int cur = 0;
  for (int it = 0; it < NT; ++it) {
    if (stager && it + 1 < NT) STAGE(cur ^ 1, (it + 1) * 32);
    short8 af[2], bfv[6];
#pragma unroll
    for (int fm = 0; fm < 2; ++fm)
      af[fm] = *(const short8*)&Al[cur][(wm * 32 + fm * 16 + lr) * 32 + coff];
#pragma unroll
    for (int fn = 0; fn < 6; ++fn)
      bfv[fn] = *(const short8*)&Bl[cur][(wn * 96 + fn * 16 + lr) * 32 + coff];
#pragma unroll
    for (int fm = 0; fm < 2; ++fm)
#pragma unroll
      for (int fn = 0; fn < 6; ++fn)
        acc[fm][fn] = __builtin_amdgcn_mfma_f32_16x16x32_bf16(af[fm], bfv[fn], acc[fm][fn], 0, 0, 0);
    __syncthreads();
    cur ^= 1;
  }

#pragma unroll
  for (int fm = 0; fm < 2; ++fm) {
#pragma unroll
    for (int fn = 0; fn < 6; ++fn) {
      int col = n0 + wn * 96 + fn * 16 + lr;
      int colp = n0 + wn * 96 + ((fn >> 1) << 5) +
                 ((lr >> 2) << 3) + ((fn & 1) << 2) + (lr & 3);
      float bias;
      if (MODE == 0) bias = (col < 192) ? b0[col] : ((col < 384) ? 0.f : b1[col - 384]);
      else           bias = b0[col];
#pragma unroll
      for (int r = 0; r < 4; ++r) {
        int row = m0 + wm * 32 + fm * 16 + lg * 4 + r;
        float v = acc[fm][fn][r] + bias;
        if (MODE == 1) v = v / (1.f + __expf(-v));
        out[(size_t)row * NTOT + colp] = f2bf(v);
      }
    }
  }
}

// ---------------------------------------------------------------------------
// fc2 (K=768) gload 2-phase + fused LN2 + residual (R17 verbatim).
__global__ __launch_bounds__(512, 4) void gemm_g512_lnfc2(
    const ushort_t* __restrict__ Ab, const ushort_t* __restrict__ W,
    const float* __restrict__ bias, const float* __restrict__ gamma,
    const float* __restrict__ beta, const ushort_t* __restrict__ residb,
    float* __restrict__ outf) {
  const int KTOT = 768;
  __shared__ ushort_t Al[2][4096];
  __shared__ ushort_t Bl[2][6144];
  int t = threadIdx.x;
  int m0 = blockIdx.x * 128;
  int lane = t & 63, wid = t >> 6;
  int wm = wid >> 1, wn = wid & 1;
  int lr = lane & 15, lg = lane >> 4;

  bool stager = (t < 256);
  int sw = (t & 255) >> 6;
  int rloc = lane >> 2;
  int csrc = (lane & 3) ^ ((lane >> 3) & 3);
  int ca = sw * 2, cb = sw * 3;
  const ushort_t* sA0 = Ab + (size_t)(m0 + ca * 16      + rloc) * KTOT + csrc * 8;
  const ushort_t* sA1 = Ab + (size_t)(m0 + ca * 16 + 16 + rloc) * KTOT + csrc * 8;
  const ushort_t* sB0 = W  + (size_t)(cb * 16      + rloc) * KTOT + csrc * 8;
  const ushort_t* sB1 = W  + (size_t)(cb * 16 + 16 + rloc) * KTOT + csrc * 8;
  const ushort_t* sB2 = W  + (size_t)(cb * 16 + 32 + rloc) * KTOT + csrc * 8;

  auto STAGE = [&](int buf, int kt) {
    GLOAD(sA0 + kt, &Al[buf][(ca + 0) * 512]);
    GLOAD(sA1 + kt, &Al[buf][(ca + 1) * 512]);
    GLOAD(sB0 + kt, &Bl[buf][(cb + 0) * 512]);
    GLOAD(sB1 + kt, &Bl[buf][(cb + 1) * 512]);
    GLOAD(sB2 + kt, &Bl[buf][(cb + 2) * 512]);
  };

  int coff = (lg ^ ((lr >> 1) & 3)) * 8;

  f32x4 acc[2][6];
#pragma unroll
  for (int a = 0; a < 2; ++a)
#pragma unroll
    for (int b = 0; b < 6; ++b) acc[a][b] = (f32x4){0.f, 0.f, 0.f, 0.f};

  const int NT = KTOT / 32;
  if (stager) STAGE(0, 0);
  __syncthreads();
  int cur = 0;
  for (int it = 0; it < NT; ++it) {
    if (stager && it + 1 < NT) STAGE(cur ^ 1, (it + 1) * 32);
    short8 af[2], bfv[6];
#pragma unroll
    for (int fm = 0; fm < 2; ++fm)
      af[fm] = *(const short8*)&Al[cur][(wm * 32 + fm * 16 + lr) * 32 + coff];
#pragma unroll
    for (int fn = 0; fn < 6; ++fn)
      bfv[fn] = *(const short8*)&Bl[cur][(wn * 96 + fn * 16 + lr) * 32 + coff];
#pragma unroll
    for (int fm = 0; fm < 2; ++fm)
#pragma unroll
      for (int fn = 0; fn < 6; ++fn)
        acc[fm][fn] = __builtin_amdgcn_mfma_f32_16x16x32_bf16(af[fm], bfv[fn], acc[fm][fn], 0, 0, 0);
    __syncthreads();
    cur ^= 1;
  }

  float* part = (float*)&Bl[0][0];
#pragma unroll
  for (int fm = 0; fm < 2; ++fm) {
#pragma unroll
    for (int r = 0; r < 4; ++r) {
      float s1 = 0.f, s2 = 0.f;
#pragma unroll
      for (int fn = 0; fn < 6; ++fn) {
        int col = wn * 96 + fn * 16 + lr;
        float v = acc[fm][fn][r] + bias[col];
        acc[fm][fn][r] = v;
        s1 += v; s2 += v * v;
      }
#pragma unroll
      for (int off = 1; off < 16; off <<= 1) {
        s1 += __shfl_xor(s1, off);
        s2 += __shfl_xor(s2, off);
      }
      if (lr == 0) {
        int lrow = wm * 32 + fm * 16 + lg * 4 + r;
        part[(wn * 128 + lrow) * 2 + 0] = s1;
        part[(wn * 128 + lrow) * 2 + 1] = s2;
      }
    }
  }
  __syncthreads();
#pragma unroll
  for (int fm = 0; fm < 2; ++fm) {
#pragma unroll
    for (int r = 0; r < 4; ++r) {
      int lrow = wm * 32 + fm * 16 + lg * 4 + r;
      float s1 = part[lrow * 2 + 0] + part[(128 + lrow) * 2 + 0];
      float s2 = part[lrow * 2 + 1] + part[(128 + lrow) * 2 + 1];
      float mean = s1 * (1.f / 192.f);
      float var  = s2 * (1.f / 192.f) - mean * mean;
      float rstd = rsqrtf(fmaxf(var, 0.f) + 1e-5f);
      size_t og = (size_t)(m0 + lrow) * 192;
#pragma unroll
      for (int fn = 0; fn < 6; ++fn) {
        int col = wn * 96 + fn * 16 + lr;
        int colp = (col & ~31) + slot32(col & 31);
        float l = (acc[fm][fn][r] - mean) * rstd * gamma[col] + beta[col];
        outf[og + col] = bf2f(residb[og + colp]) + l;
      }
    }
  }
}

// ---------------------------------------------------------------------------
// Streaming LayerNorm + residual for proj output (perm-aware). (R17 verbatim)
__global__ __launch_bounds__(256) void ln_resid_kernel(
    const ushort_t* __restrict__ pre, const float* __restrict__ residf,
    const float* __restrict__ gamma, const float* __restrict__ beta,
    ushort_t* __restrict__ outb) {
  int m = (blockIdx.x * 256 + threadIdx.x) >> 6;   // row
  int lane = threadIdx.x & 63;
  int c0 = lane, c1 = lane + 64, c2 = lane + 128;
  int s0 = (c0 & ~31) + slot32(c0 & 31);
  int s1c = (c1 & ~31) + slot32(c1 & 31);
  int s2c = (c2 & ~31) + slot32(c2 & 31);
  const ushort_t* p = pre + (size_t)m * 192;
  float v0 = bf2f(p[s0]), v1 = bf2f(p[s1c]), v2 = bf2f(p[s2c]);
  float s1 = v0 + v1 + v2;
  float s2 = v0 * v0 + v1 * v1 + v2 * v2;
#pragma unroll
  for (int o = 1; o < 64; o <<= 1) {
    s1 += __shfl_xor(s1, o);
    s2 += __shfl_xor(s2, o);
  }
  float mean = s1 * (1.f / 192.f);
  float var  = s2 * (1.f / 192.f) - mean * mean;
  float rstd = rsqrtf(fmaxf(var, 0.f) + 1e-5f);
  float l0 = (v0 - mean) * rstd * gamma[c0] + beta[c0];
  float l1 = (v1 - mean) * rstd * gamma[c1] + beta[c1];
  float l2 = (v2 - mean) * rstd * gamma[c2] + beta[c2];
  size_t og = (size_t)img_pos(m) * 192;
  outb[og + s0]  = f2bf(residf[og + c0] + l0);
  outb[og + s1c] = f2bf(residf[og + c1] + l1);
  outb[og + s2c] = f2bf(residf[og + c2] + l2);
}

// ---------------------------------------------------------------------------
// Attention (MFMA): block = (window, head), 256 threads = 4 waves. (R17 verbatim)
__global__ __launch_bounds__(256) void attn_kernel(
    const ushort_t* __restrict__ qkv, const float* __restrict__ logit_scale,
    const float* __restrict__ tab_s, ushort_t* __restrict__ attn_out) {
  __shared__ ushort_t qs[64][40];
  __shared__ ushort_t ksl[64][40];
  __shared__ ushort_t vsl[32][80];
  __shared__ ushort_t ps[64][80];
  __shared__ float tab_l[169];
  int win = blockIdx.x, head = blockIdx.y;
  int t = threadIdx.x;
  int wi = win & 63;
  int wh0 = (wi >> 3) * 7, ww0 = (wi & 7) * 7;
  size_t base = (size_t)win * 49 * 576 + head * 32;

  for (int u = t; u < 169; u += 256) tab_l[u] = tab_s[head * 169 + u];

  for (int u = t; u < 240; u += 256) {
    int arr = u / 120, v = u - arr * 120;
    int r = 49 + (v >> 3), c4 = (v & 7) << 2;
    ushort_t* p = arr ? &ksl[r][c4] : &qs[r][c4];
    *(ushort4*)p = make_ushort4(0, 0, 0, 0);
  }

  for (int u = t; u < 2048; u += 256) {
    int key = u >> 5, d = u & 31;
    ushort_t val = 0;
    if (key < 49) val = qkv[base + (size_t)key * 576 + 384 + d];
    int kk = key & 31;
    int pc = ((key >> 5) << 5) + 8 * ((kk >> 2) & 3) + 4 * (kk >> 4) + (kk & 3);
    vsl[d][pc] = val;
  }

  float scale = __expf(fminf(logit_scale[head], 4.605170186f));  // ln(100)

  if (t < 196) {
    int r = t >> 2, c = t & 3;
    const ushort_t* qp = qkv + base + (size_t)r * 576 + c * 8;
    ushort4 qa = *(const ushort4*)qp,         qb = *(const ushort4*)(qp + 4);
    ushort4 ka = *(const ushort4*)(qp + 192), kb = *(const ushort4*)(qp + 196);
    float qf[8] = {bf2f(qa.x), bf2f(qa.y), bf2f(qa.z), bf2f(qa.w),
                   bf2f(qb.x), bf2f(qb.y), bf2f(qb.z), bf2f(qb.w)};
    float kf[8] = {bf2f(ka.x), bf2f(ka.y), bf2f(ka.z), bf2f(ka.w),
                   bf2f(kb.x), bf2f(kb.y), bf2f(kb.z), bf2f(kb.w)};
    float sq = 0.f, sk = 0.f;
#pragma unroll
    for (int d = 0; d < 8; ++d) { sq += qf[d] * qf[d]; sk += kf[d] * kf[d]; }
    sq += __shfl_xor(sq, 1); sq += __shfl_xor(sq, 2);
    sk += __shfl_xor(sk, 1); sk += __shfl_xor(sk, 2);
    float rq = scale / fmaxf(sqrtf(sq), 1e-12f);
    float rk = 1.f   / fmaxf(sqrtf(sk), 1e-12f);
    ushort_t* qd = &qs[r][c * 8];
    *(ushort4*)(qd + 0) = make_ushort4(f2bf(qf[0]*rq), f2bf(qf[1]*rq), f2bf(qf[2]*rq), f2bf(qf[3]*rq));
    *(ushort4*)(qd + 4) = make_ushort4(f2bf(qf[4]*rq), f2bf(qf[5]*rq), f2bf(qf[6]*rq), f2bf(qf[7]*rq));
    ushort_t* kd = &ksl[r][c * 8];
    *(ushort4*)(kd + 0) = make_ushort4(f2bf(kf[0]*rk), f2bf(kf[1]*rk), f2bf(kf[2]*rk), f2bf(kf[3]*rk));
    *(ushort4*)(kd + 4) = make_ushort4(f2bf(kf[4]*rk), f2bf(kf[5]*rk), f2bf(kf[6]*rk), f2bf(kf[7]*rk));
  }
  __syncthreads();

  int lane = t & 63, w = t >> 6;
  int lr = lane & 15, lg = lane >> 4;

  short8 aq = *(const short8*)&qs[w * 16 + lr][lg * 8];
  f32x4 acc[4];
#pragma unroll
  for (int fn = 0; fn < 4; ++fn) {
    acc[fn] = (f32x4){0.f, 0.f, 0.f, 0.f};
    short8 bk = *(const short8*)&ksl[fn * 16 + lr][lg * 8];
    acc[fn] = __builtin_amdgcn_mfma_f32_16x16x32_bf16(aq, bk, acc[fn], 0, 0, 0);
  }

  float rsum[4];
#pragma unroll
  for (int r = 0; r < 4; ++r) {
    int row = w * 16 + lg * 4 + r;
    int rd = (row * 9363) >> 16, rm = row - 7 * rd;
    int gr = region3(wh0 + rd) * 3 + region3(ww0 + rm);
    bool rv = row < 49;
    float sv[4];
#pragma unroll
    for (int fn = 0; fn < 4; ++fn) {
      int col = fn * 16 + lr;
      int jd = (col * 9363) >> 16, jm = col - 7 * jd;
      int gj = region3(wh0 + jd) * 3 + region3(ww0 + jm);
      bool cv = rv && (col < 49);
      int idx = cv ? (rd - jd + 6) * 13 + (rm - jm + 6) : 0;
      float s = acc[fn][r] + tab_l[idx] + (gr == gj ? 0.f : -100.f);
      sv[fn] = cv ? s : -1e30f;
    }
    float m = fmaxf(fmaxf(sv[0], sv[1]), fmaxf(sv[2], sv[3]));
#pragma unroll
    for (int o = 1; o < 16; o <<= 1) m = fmaxf(m, __shfl_xor(m, o));
    float sum = 0.f;
#pragma unroll
    for (int fn = 0; fn < 4; ++fn) {
      float e = __expf(sv[fn] - m);
      sum += e;
      int pc = ((fn >> 1) << 5) + 8 * (lr >> 2) + ((fn & 1) << 2) + (lr & 3);
      ps[row][pc] = f2bf(e);
    }
#pragma unroll
    for (int o = 1; o < 16; o <<= 1) sum += __shfl_xor(sum, o);
    rsum[r] = 1.f / sum;
  }
  __syncthreads();

  short8 ap0 = *(const short8*)&ps[w * 16 + lr][lg * 8];
  short8 ap1 = *(const short8*)&ps[w * 16 + lr][32 + lg * 8];
  f32x4 o2[2];
#pragma unroll
  for (int f = 0; f < 2; ++f) {
    o2[f] = (f32x4){0.f, 0.f, 0.f, 0.f};
    short8 bv0 = *(const short8*)&vsl[f * 16 + lr][lg * 8];
    short8 bv1 = *(const short8*)&vsl[f * 16 + lr][32 + lg * 8];
    o2[f] = __builtin_amdgcn_mfma_f32_16x16x32_bf16(ap0, bv0, o2[f], 0, 0, 0);
    o2[f] = __builtin_amdgcn_mfma_f32_16x16x32_bf16(ap1, bv1, o2[f], 0, 0, 0);
  }
#pragma unroll
  for (int f = 0; f < 2; ++f) {
#pragma unroll
    for (int r = 0; r < 4; ++r) {
      int row = w * 16 + lg * 4 + r;
      if (row < 49)
        attn_out[((size_t)win * 49 + row) * 192 + head * 32 + f * 16 + lr] =
            f2bf(o2[f][r] * rsum[r]);
    }
  }
}

// ---------------------------------------------------------------------------
extern "C" void kernel_launch(void* const* d_in, const int* in_sizes, int n_in,
                              void* d_out, int out_size, void* d_ws, size_t ws_size,
                              hipStream_t stream) {
  (void)in_sizes; (void)n_in; (void)out_size; (void)ws_size;
  const float* x    = (const float*)d_in[0];
  const float* qkvw = (const float*)d_in[1];
  const float* qb   = (const float*)d_in[2];
  const float* vb   = (const float*)d_in[3];
  const float* ls   = (const float*)d_in[4];
  const float* cw1  = (const float*)d_in[5];
  const float* cb1  = (const float*)d_in[6];
  const float* cw2  = (const float*)d_in[7];
  const float* pw   = (const float*)d_in[8];
  const float* pb   = (const float*)d_in[9];
  const float* n1g  = (const float*)d_in[10];
  const float* n1b  = (const float*)d_in[11];
  const float* n2g  = (const float*)d_in[12];
  const float* n2b  = (const float*)d_in[13];
  const float* f1w  = (const float*)d_in[14];
  const float* f1b  = (const float*)d_in[15];
  const float* f2w  = (const float*)d_in[16];
  const float* f2b  = (const float*)d_in[17];
  float* out = (float*)d_out;

  char* ws = (char*)d_ws;
  ushort_t* wq_bf = (ushort_t*)ws;                 // 110592 (perm K=192)
  ushort_t* wp_bf = wq_bf + 110592;                // 36864  (perm K=192)
  ushort_t* w1_bf = wp_bf + 36864;                 // 147456 (perm K=192)
  ushort_t* w2_bf = w1_bf + 147456;                // 147456 (perm K=768)
  float*    tab_s = (float*)(w2_bf + 147456);      // 6*169 floats
  const size_t OFF_BIG = 1 << 20;
  ushort_t* qkv_out = (ushort_t*)(ws + OFF_BIG);
  ushort_t* xw_bf   = (ushort_t*)(ws + OFF_BIG + 115605504);
  ushort_t* attn_o  = (ushort_t*)(ws + OFF_BIG + 115605504);
  ushort_t* x1_bf   = (ushort_t*)(ws + OFF_BIG + 154140672);
  ushort_t* hmid    = (ushort_t*)(ws + OFF_BIG);   // 100352*768 bf16 over R1+R2

  cvt_perm_all<<<1728, 256, 0, stream>>>(qkvw, pw, f1w, f2w, wq_bf, wp_bf, w1_bf, w2_bf);
  cpb_kernel<<<169, 256, 0, stream>>>(cw1, cb1, cw2, tab_s);
  gather_cvt_kernel<<<9408, 256, 0, stream>>>(x, xw_bf);

  // qkv (3-buffer counted-vmcnt pipeline)
  gemm_p3<192, 0><<<dim3(784, 3), 512, 0, stream>>>(xw_bf, wq_bf, qb, vb, qkv_out, 576);
  // attention
  attn_kernel<<<dim3(2048, 6), 256, 0, stream>>>(qkv_out, ls, tab_s, attn_o);
  // proj (pre-LN, in-place over attn_o) + perm-aware LN1/residual
  gemm_g512<192, 2><<<dim3(784, 1), 512, 0, stream>>>(attn_o, wp_bf, pb, nullptr, attn_o, 192);
  ln_resid_kernel<<<25088, 256, 0, stream>>>(attn_o, x, n1g, n1b, x1_bf);
  // fc1 (silu, 3-buffer counted-vmcnt pipeline)
  gemm_p3<192, 1><<<dim3(784, 4), 512, 0, stream>>>(x1_bf, w1_bf, f1b, nullptr, hmid, 768);
  // fc2 + LN2 + residual fused -> d_out fp32
  gemm_g512_lnfc2<<<784, 512, 0, stream>>>(hmid, w2_bf, f2b, n2g, n2b, x1_bf, out);
}

// Round 19
// 355.427 us; speedup vs baseline: 1.1623x; 1.0104x over previous
//
#include <hip/hip_runtime.h>

// ============================================================================
// Swin V2 block, round 19 = R18 base (359us best) + T5 s_setprio around MFMA
// clusters in gemm_p3 / gemm_g512 / gemm_g512_lnfc2 / attn.
// Rationale: 5 K-loop structures all land 84-95us on qkv/fc1 (VALU 56,
// Mfma 14, occ 34, BW 43%) -> mixed-issue regime, no single pipe saturated.
// 512-thread kernels have wave role-split (stagers t<256 vs pure-compute
// t>=256) = T5's prerequisite (m218b +21-25% role-split; m190 0% lockstep;
// m191 +4-7% attn). Single variable; disjoint dispatches.
// slot32(k) = 8*((k%16)/4) + 4*(k/16) + k%4 (HW-verified). C/D: col=lane%16,
// row=4*(lane/16)+reg.
// ============================================================================

typedef unsigned short ushort_t;
using f32x4  = __attribute__((ext_vector_type(4))) float;
using short8 = __attribute__((ext_vector_type(8))) short;

#define GLOAD(srcp, ldsp) __builtin_amdgcn_global_load_lds(                    \
    (const __attribute__((address_space(1))) void*)(srcp),                     \
    (__attribute__((address_space(3))) void*)(ldsp), 16, 0, 0)

__device__ __forceinline__ ushort_t f2bf(float f) {
  union { float f; unsigned u; } v; v.f = f;
  unsigned r = v.u + 0x7fffu + ((v.u >> 16) & 1u);
  return (ushort_t)(r >> 16);
}
__device__ __forceinline__ float bf2f(ushort_t u) {
  union { unsigned u; float f; } v; v.u = ((unsigned)u) << 16;
  return v.f;
}
__device__ __forceinline__ int slot32(int k) {
  return 8 * ((k & 15) >> 2) + ((k >> 4) << 2) + (k & 3);
}

// windowed-token index m -> image row index (same map for gather and scatter)
__device__ __forceinline__ int img_pos(int m) {
  int win = m / 49, n = m - win * 49;
  int b = win >> 6, wi = win & 63;
  int nd = n / 7, nm = n - nd * 7;
  int hs = (wi >> 3) * 7 + nd;
  int ws = (wi & 7) * 7 + nm;
  int h = hs + 3; if (h >= 56) h -= 56;
  int w = ws + 3; if (w >= 56) w -= 56;
  return b * 3136 + h * 56 + w;
}

__device__ __forceinline__ int region3(int a) { return a < 49 ? 0 : (a < 53 ? 1 : 2); }

// ---------------------------------------------------------------------------
// All four weight tensors converted + k-permuted in ONE launch.
__global__ __launch_bounds__(256) void cvt_perm_all(
    const float* __restrict__ qkvw, const float* __restrict__ pw,
    const float* __restrict__ f1w, const float* __restrict__ f2w,
    ushort_t* __restrict__ wq, ushort_t* __restrict__ wp,
    ushort_t* __restrict__ w1, ushort_t* __restrict__ w2) {
  int i = blockIdx.x * 256 + threadIdx.x;   // 0..442367
  if (i >= 442368) return;
  const float* in; ushort_t* out; int K, j;
  if (i < 110592)      { j = i;          in = qkvw; out = wq; K = 192; }
  else if (i < 147456) { j = i - 110592; in = pw;   out = wp; K = 192; }
  else if (i < 294912) { j = i - 147456; in = f1w;  out = w1; K = 192; }
  else                 { j = i - 294912; in = f2w;  out = w2; K = 768; }
  int row = j / K, c = j - row * K;
  out[row * K + (c & ~31) + slot32(c & 31)] = f2bf(in[j]);
}

// gather shifted windows + cvt + k-permute: xw[m][slot(c)] = bf16(x[img_pos(m)][c])
__global__ __launch_bounds__(256) void gather_cvt_kernel(
    const float* __restrict__ x, ushort_t* __restrict__ xw) {
  int i8 = blockIdx.x * 256 + threadIdx.x;      // 100352*24 tasks of 8 elems
  int m = i8 / 24, c8 = (i8 - m * 24) * 8;
  const float* p = x + (size_t)img_pos(m) * 192 + c8;
  float4 a = *(const float4*)p, b = *(const float4*)(p + 4);
  ushort_t* q = xw + (size_t)m * 192;
  int blk = c8 & ~31;
  int jj = (c8 & 31) >> 3;
  int b4 = ((jj & 1) << 4) | ((jj >> 1) << 2);
  *(ushort4*)(q + blk + b4)     = make_ushort4(f2bf(a.x), f2bf(a.y), f2bf(a.z), f2bf(a.w));
  *(ushort4*)(q + blk + b4 + 8) = make_ushort4(f2bf(b.x), f2bf(b.y), f2bf(b.z), f2bf(b.w));
}

// ---------------------------------------------------------------------------
// CPB: tab_s[head][e] = 16*sigmoid( relu(REL_TABLE[e] @ w1.T + b1) @ w2.T )
__global__ __launch_bounds__(256) void cpb_kernel(
    const float* __restrict__ w1, const float* __restrict__ b1,
    const float* __restrict__ w2, float* __restrict__ tab_s) {
  int e = blockIdx.x;            // 0..168
  int t = threadIdx.x;           // 0..255
  int i = e / 13, j = e - 13 * (e / 13);
  auto cval = [](int a) -> float {
    float r = (a - 6) * (8.0f / 6.0f);
    float v = log2f(fabsf(r) + 1.f) * (1.f / 3.f);
    return r < 0.f ? -v : v;
  };
  float ci = cval(i), cj = cval(j);
  float h = fmaxf(ci * w1[2 * t] + cj * w1[2 * t + 1] + b1[t], 0.f);
  __shared__ float red[256];
  for (int head = 0; head < 6; ++head) {
    red[t] = h * w2[head * 256 + t];
    __syncthreads();
    for (int st = 128; st > 0; st >>= 1) {
      if (t < st) red[t] += red[t + st];
      __syncthreads();
    }
    if (t == 0) tab_s[head * 169 + e] = 16.f / (1.f + __expf(-red[0]));
    __syncthreads();
  }
}

// ---------------------------------------------------------------------------
// 3-buffer counted-vmcnt gload GEMM (T3/T4) + T5 setprio. tile 128x192,
// BK=32, 512 thr = 8 waves (4x2 of 32x96), acc[2][6]. Output k-permuted.
// MODE 0: qkv  MODE 1: fc1(silu)
template<int KTOT, int MODE>
__global__ __launch_bounds__(512, 4) void gemm_p3(
    const ushort_t* __restrict__ Ab, const ushort_t* __restrict__ W,
    const float* __restrict__ b0, const float* __restrict__ b1,
    ushort_t* __restrict__ out, int NTOT) {
  __shared__ ushort_t Al[3][4096];
  __shared__ ushort_t Bl[3][6144];
  int t = threadIdx.x;
  int m0 = blockIdx.x * 128, n0 = blockIdx.y * 192;
  int lane = t & 63, wid = t >> 6;
  int wm = wid >> 1, wn = wid & 1;
  int lr = lane & 15, lg = lane >> 4;

  bool stager = (t < 256);
  int sw = (t & 255) >> 6;
  int rloc = lane >> 2;
  int csrc = (lane & 3) ^ ((lane >> 3) & 3);
  int ca = sw * 2, cb = sw * 3;
  const ushort_t* sA0 = Ab + (size_t)(m0 + ca * 16      + rloc) * KTOT + csrc * 8;
  const ushort_t* sA1 = Ab + (size_t)(m0 + ca * 16 + 16 + rloc) * KTOT + csrc * 8;
  const ushort_t* sB0 = W  + (size_t)(n0 + cb * 16      + rloc) * KTOT + csrc * 8;
  const ushort_t* sB1 = W  + (size_t)(n0 + cb * 16 + 16 + rloc) * KTOT + csrc * 8;
  const ushort_t* sB2 = W  + (size_t)(n0 + cb * 16 + 32 + rloc) * KTOT + csrc * 8;

  auto STAGE = [&](int buf, int kt) {
    GLOAD(sA0 + kt, &Al[buf][(ca + 0) * 512]);
    GLOAD(sA1 + kt, &Al[buf][(ca + 1) * 512]);
    GLOAD(sB0 + kt, &Bl[buf][(cb + 0) * 512]);
    GLOAD(sB1 + kt, &Bl[buf][(cb + 1) * 512]);
    GLOAD(sB2 + kt, &Bl[buf][(cb + 2) * 512]);
  };

  int coff = (lg ^ ((lr >> 1) & 3)) * 8;

  f32x4 acc[2][6];
#pragma unroll
  for (int a = 0; a < 2; ++a)
#pragma unroll
    for (int b = 0; b < 6; ++b) acc[a][b] = (f32x4){0.f, 0.f, 0.f, 0.f};

  const int NT = KTOT / 32;
  if (stager) { STAGE(0, 0); STAGE(1, 32); }
  for (int it = 0; it < NT; ++it) {
    int cur = it % 3;
    if (stager) {
      if (it + 2 < NT) {
        STAGE((it + 2) % 3, (it + 2) * 32);
        asm volatile("s_waitcnt vmcnt(10)" ::: "memory");
      } else if (it + 1 < NT) {
        asm volatile("s_waitcnt vmcnt(5)" ::: "memory");
      } else {
        asm volatile("s_waitcnt vmcnt(0)" ::: "memory");
      }
    }
    __builtin_amdgcn_sched_barrier(0);
    __builtin_amdgcn_s_barrier();
    __builtin_amdgcn_sched_barrier(0);
    short8 af[2], bfv[6];
#pragma unroll
    for (int fm = 0; fm < 2; ++fm)
      af[fm] = *(const short8*)&Al[cur][(wm * 32 + fm * 16 + lr) * 32 + coff];
#pragma unroll
    for (int fn = 0; fn < 6; ++fn)
      bfv[fn] = *(const short8*)&Bl[cur][(wn * 96 + fn * 16 + lr) * 32 + coff];
    __builtin_amdgcn_s_setprio(1);
#pragma unroll
    for (int fm = 0; fm < 2; ++fm)
#pragma unroll
      for (int fn = 0; fn < 6; ++fn)
        acc[fm][fn] = __builtin_amdgcn_mfma_f32_16x16x32_bf16(af[fm], bfv[fn], acc[fm][fn], 0, 0, 0);
    __builtin_amdgcn_s_setprio(0);
    __builtin_amdgcn_sched_barrier(0);
    __builtin_amdgcn_s_barrier();
    __builtin_amdgcn_sched_barrier(0);
  }

#pragma unroll
  for (int fm = 0; fm < 2; ++fm) {
#pragma unroll
    for (int fn = 0; fn < 6; ++fn) {
      int col = n0 + wn * 96 + fn * 16 + lr;
      int colp = n0 + wn * 96 + ((fn >> 1) << 5) +
                 ((lr >> 2) << 3) + ((fn & 1) << 2) + (lr & 3);
      float bias;
      if (MODE == 0) bias = (col < 192) ? b0[col] : ((col < 384) ? 0.f : b1[col - 384]);
      else           bias = b0[col];
#pragma unroll
      for (int r = 0; r < 4; ++r) {
        int row = m0 + wm * 32 + fm * 16 + lg * 4 + r;
        float v = acc[fm][fn][r] + bias;
        if (MODE == 1) v = v / (1.f + __expf(-v));   // silu
        out[(size_t)row * NTOT + colp] = f2bf(v);
      }
    }
  }
}

// ---------------------------------------------------------------------------
// gload_lds 2-phase GEMM + T5 setprio. MODE 2: proj (may alias A in-place)
template<int KTOT, int MODE>
__global__ __launch_bounds__(512, 4) void gemm_g512(
    const ushort_t* __restrict__ Ab, const ushort_t* __restrict__ W,
    const float* __restrict__ b0, const float* __restrict__ b1,
    ushort_t* out, int NTOT) {
  __shared__ ushort_t Al[2][4096];
  __shared__ ushort_t Bl[2][6144];
  int t = threadIdx.x;
  int m0 = blockIdx.x * 128, n0 = blockIdx.y * 192;
  int lane = t & 63, wid = t >> 6;
  int wm = wid >> 1, wn = wid & 1;
  int lr = lane & 15, lg = lane >> 4;

  bool stager = (t < 256);
  int sw = (t & 255) >> 6;
  int rloc = lane >> 2;
  int csrc = (lane & 3) ^ ((lane >> 3) & 3);
  int ca = sw * 2, cb = sw * 3;
  const ushort_t* sA0 = Ab + (size_t)(m0 + ca * 16      + rloc) * KTOT + csrc * 8;
  const ushort_t* sA1 = Ab + (size_t)(m0 + ca * 16 + 16 + rloc) * KTOT + csrc * 8;
  const ushort_t* sB0 = W  + (size_t)(n0 + cb * 16      + rloc) * KTOT + csrc * 8;
  const ushort_t* sB1 = W  + (size_t)(n0 + cb * 16 + 16 + rloc) * KTOT + csrc * 8;
  const ushort_t* sB2 = W  + (size_t)(n0 + cb * 16 + 32 + rloc) * KTOT + csrc * 8;

  auto STAGE = [&](int buf, int kt) {
    GLOAD(sA0 + kt, &Al[buf][(ca + 0) * 512]);
    GLOAD(sA1 + kt, &Al[buf][(ca + 1) * 512]);
    GLOAD(sB0 + kt, &Bl[buf][(cb + 0) * 512]);
    GLOAD(sB1 + kt, &Bl[buf][(cb + 1) * 512]);
    GLOAD(sB2 + kt, &Bl[buf][(cb + 2) * 512]);
  };

  int coff = (lg ^ ((lr >> 1) & 3)) * 8;

  f32x4 acc[2][6];
#pragma unroll
  for (int a = 0; a < 2; ++a)
#pragma unroll
    for (int b = 0; b < 6; ++b) acc[a][b] = (f32x4){0.f, 0.f, 0.f, 0.f};

  const int NT = KTOT / 32;
  if (stager) STAGE(0, 0);
  __syncthreads();
  int cur = 0;
  for (int it = 0; it < NT; ++it) {
    if (stager && it + 1 < NT) STAGE(cur ^ 1, (it + 1) * 32);
    short8 af[2], bfv[6];
#pragma unroll
    for (int fm = 0; fm < 2; ++fm)
      af[fm] = *(const short8*)&Al[cur][(wm * 32 + fm * 16 + lr) * 32 + coff];
#pragma unroll
    for (int fn = 0; fn < 6; ++fn)
      bfv[fn] = *(const short8*)&Bl[cur][(wn * 96 + fn * 16 + lr) * 32 + coff];
    __builtin_amdgcn_s_setprio(1);
#pragma unroll
    for (int fm = 0; fm < 2; ++fm)
#pragma unroll
      for (int fn = 0; fn < 6; ++fn)
        acc[fm][fn] = __builtin_amdgcn_mfma_f32_16x16x32_bf16(af[fm], bfv[fn], acc[fm][fn], 0, 0, 0);
    __builtin_amdgcn_s_setprio(0);
    __syncthreads();
    cur ^= 1;
  }

#pragma unroll
  for (int fm = 0; fm < 2; ++fm) {
#pragma unroll
    for (int fn = 0; fn < 6; ++fn) {
      int col = n0 + wn * 96 + fn * 16 + lr;
      int colp = n0 + wn * 96 + ((fn >> 1) << 5) +
                 ((lr >> 2) << 3) + ((fn & 1) << 2) + (lr & 3);
      float bias;
      if (MODE == 0) bias = (col < 192) ? b0[col] : ((col < 384) ? 0.f : b1[col - 384]);
      else           bias = b0[col];
#pragma unroll
      for (int r = 0; r < 4; ++r) {
        int row = m0 + wm * 32 + fm * 16 + lg * 4 + r;
        float v = acc[fm][fn][r] + bias;
        if (MODE == 1) v = v / (1.f + __expf(-v));
        out[(size_t)row * NTOT + colp] = f2bf(v);
      }
    }
  }
}

// ---------------------------------------------------------------------------
// fc2 (K=768) gload 2-phase + fused LN2 + residual + T5 setprio.
__global__ __launch_bounds__(512, 4) void gemm_g512_lnfc2(
    const ushort_t* __restrict__ Ab, const ushort_t* __restrict__ W,
    const float* __restrict__ bias, const float* __restrict__ gamma,
    const float* __restrict__ beta, const ushort_t* __restrict__ residb,
    float* __restrict__ outf) {
  const int KTOT = 768;
  __shared__ ushort_t Al[2][4096];
  __shared__ ushort_t Bl[2][6144];
  int t = threadIdx.x;
  int m0 = blockIdx.x * 128;
  int lane = t & 63, wid = t >> 6;
  int wm = wid >> 1, wn = wid & 1;
  int lr = lane & 15, lg = lane >> 4;

  bool stager = (t < 256);
  int sw = (t & 255) >> 6;
  int rloc = lane >> 2;
  int csrc = (lane & 3) ^ ((lane >> 3) & 3);
  int ca = sw * 2, cb = sw * 3;
  const ushort_t* sA0 = Ab + (size_t)(m0 + ca * 16      + rloc) * KTOT + csrc * 8;
  const ushort_t* sA1 = Ab + (size_t)(m0 + ca * 16 + 16 + rloc) * KTOT + csrc * 8;
  const ushort_t* sB0 = W  + (size_t)(cb * 16      + rloc) * KTOT + csrc * 8;
  const ushort_t* sB1 = W  + (size_t)(cb * 16 + 16 + rloc) * KTOT + csrc * 8;
  const ushort_t* sB2 = W  + (size_t)(cb * 16 + 32 + rloc) * KTOT + csrc * 8;

  auto STAGE = [&](int buf, int kt) {
    GLOAD(sA0 + kt, &Al[buf][(ca + 0) * 512]);
    GLOAD(sA1 + kt, &Al[buf][(ca + 1) * 512]);
    GLOAD(sB0 + kt, &Bl[buf][(cb + 0) * 512]);
    GLOAD(sB1 + kt, &Bl[buf][(cb + 1) * 512]);
    GLOAD(sB2 + kt, &Bl[buf][(cb + 2) * 512]);
  };

  int coff = (lg ^ ((lr >> 1) & 3)) * 8;

  f32x4 acc[2][6];
#pragma unroll
  for (int a = 0; a < 2; ++a)
#pragma unroll
    for (int b = 0; b < 6; ++b) acc[a][b] = (f32x4){0.f, 0.f, 0.f, 0.f};

  const int NT = KTOT / 32;
  if (stager) STAGE(0, 0);
  __syncthreads();
  int cur = 0;
  for (int it = 0; it < NT; ++it) {
    if (stager && it + 1 < NT) STAGE(cur ^ 1, (it + 1) * 32);
    short8 af[2], bfv[6];
#pragma unroll
    for (int fm = 0; fm < 2; ++fm)
      af[fm] = *(const short8*)&Al[cur][(wm * 32 + fm * 16 + lr) * 32 + coff];
#pragma unroll
    for (int fn = 0; fn < 6; ++fn)
      bfv[fn] = *(const short8*)&Bl[cur][(wn * 96 + fn * 16 + lr) * 32 + coff];
    __builtin_amdgcn_s_setprio(1);
#pragma unroll
    for (int fm = 0; fm < 2; ++fm)
#pragma unroll
      for (int fn = 0; fn < 6; ++fn)
        acc[fm][fn] = __builtin_amdgcn_mfma_f32_16x16x32_bf16(af[fm], bfv[fn], acc[fm][fn], 0, 0, 0);
    __builtin_amdgcn_s_setprio(0);
    __syncthreads();
    cur ^= 1;
  }

  float* part = (float*)&Bl[0][0];
#pragma unroll
  for (int fm = 0; fm < 2; ++fm) {
#pragma unroll
    for (int r = 0; r < 4; ++r) {
      float s1 = 0.f, s2 = 0.f;
#pragma unroll
      for (int fn = 0; fn < 6; ++fn) {
        int col = wn * 96 + fn * 16 + lr;
        float v = acc[fm][fn][r] + bias[col];
        acc[fm][fn][r] = v;
        s1 += v; s2 += v * v;
      }
#pragma unroll
      for (int off = 1; off < 16; off <<= 1) {
        s1 += __shfl_xor(s1, off);
        s2 += __shfl_xor(s2, off);
      }
      if (lr == 0) {
        int lrow = wm * 32 + fm * 16 + lg * 4 + r;
        part[(wn * 128 + lrow) * 2 + 0] = s1;
        part[(wn * 128 + lrow) * 2 + 1] = s2;
      }
    }
  }
  __syncthreads();
#pragma unroll
  for (int fm = 0; fm < 2; ++fm) {
#pragma unroll
    for (int r = 0; r < 4; ++r) {
      int lrow = wm * 32 + fm * 16 + lg * 4 + r;
      float s1 = part[lrow * 2 + 0] + part[(128 + lrow) * 2 + 0];
      float s2 = part[lrow * 2 + 1] + part[(128 + lrow) * 2 + 1];
      float mean = s1 * (1.f / 192.f);
      float var  = s2 * (1.f / 192.f) - mean * mean;
      float rstd = rsqrtf(fmaxf(var, 0.f) + 1e-5f);
      size_t og = (size_t)(m0 + lrow) * 192;
#pragma unroll
      for (int fn = 0; fn < 6; ++fn) {
        int col = wn * 96 + fn * 16 + lr;
        int colp = (col & ~31) + slot32(col & 31);
        float l = (acc[fm][fn][r] - mean) * rstd * gamma[col] + beta[col];
        outf[og + col] = bf2f(residb[og + colp]) + l;
      }
    }
  }
}

// ---------------------------------------------------------------------------
// Streaming LayerNorm + residual for proj output (perm-aware). (R18 verbatim)
__global__ __launch_bounds__(256) void ln_resid_kernel(
    const ushort_t* __restrict__ pre, const float* __restrict__ residf,
    const float* __restrict__ gamma, const float* __restrict__ beta,
    ushort_t* __restrict__ outb) {
  int m = (blockIdx.x * 256 + threadIdx.x) >> 6;   // row
  int lane = threadIdx.x & 63;
  int c0 = lane, c1 = lane + 64, c2 = lane + 128;
  int s0 = (c0 & ~31) + slot32(c0 & 31);
  int s1c = (c1 & ~31) + slot32(c1 & 31);
  int s2c = (c2 & ~31) + slot32(c2 & 31);
  const ushort_t* p = pre + (size_t)m * 192;
  float v0 = bf2f(p[s0]), v1 = bf2f(p[s1c]), v2 = bf2f(p[s2c]);
  float s1 = v0 + v1 + v2;
  float s2 = v0 * v0 + v1 * v1 + v2 * v2;
#pragma unroll
  for (int o = 1; o < 64; o <<= 1) {
    s1 += __shfl_xor(s1, o);
    s2 += __shfl_xor(s2, o);
  }
  float mean = s1 * (1.f / 192.f);
  float var  = s2 * (1.f / 192.f) - mean * mean;
  float rstd = rsqrtf(fmaxf(var, 0.f) + 1e-5f);
  float l0 = (v0 - mean) * rstd * gamma[c0] + beta[c0];
  float l1 = (v1 - mean) * rstd * gamma[c1] + beta[c1];
  float l2 = (v2 - mean) * rstd * gamma[c2] + beta[c2];
  size_t og = (size_t)img_pos(m) * 192;
  outb[og + s0]  = f2bf(residf[og + c0] + l0);
  outb[og + s1c] = f2bf(residf[og + c1] + l1);
  outb[og + s2c] = f2bf(residf[og + c2] + l2);
}

// ---------------------------------------------------------------------------
// Attention (MFMA) + T5 setprio: block = (window, head), 256 threads = 4 waves.
__global__ __launch_bounds__(256) void attn_kernel(
    const ushort_t* __restrict__ qkv, const float* __restrict__ logit_scale,
    const float* __restrict__ tab_s, ushort_t* __restrict__ attn_out) {
  __shared__ ushort_t qs[64][40];
  __shared__ ushort_t ksl[64][40];
  __shared__ ushort_t vsl[32][80];
  __shared__ ushort_t ps[64][80];
  __shared__ float tab_l[169];
  int win = blockIdx.x, head = blockIdx.y;
  int t = threadIdx.x;
  int wi = win & 63;
  int wh0 = (wi >> 3) * 7, ww0 = (wi & 7) * 7;
  size_t base = (size_t)win * 49 * 576 + head * 32;

  for (int u = t; u < 169; u += 256) tab_l[u] = tab_s[head * 169 + u];

  for (int u = t; u < 240; u += 256) {
    int arr = u / 120, v = u - arr * 120;
    int r = 49 + (v >> 3), c4 = (v & 7) << 2;
    ushort_t* p = arr ? &ksl[r][c4] : &qs[r][c4];
    *(ushort4*)p = make_ushort4(0, 0, 0, 0);
  }

  for (int u = t; u < 2048; u += 256) {
    int key = u >> 5, d = u & 31;
    ushort_t val = 0;
    if (key < 49) val = qkv[base + (size_t)key * 576 + 384 + d];
    int kk = key & 31;
    int pc = ((key >> 5) << 5) + 8 * ((kk >> 2) & 3) + 4 * (kk >> 4) + (kk & 3);
    vsl[d][pc] = val;
  }

  float scale = __expf(fminf(logit_scale[head], 4.605170186f));  // ln(100)

  if (t < 196) {
    int r = t >> 2, c = t & 3;
    const ushort_t* qp = qkv + base + (size_t)r * 576 + c * 8;
    ushort4 qa = *(const ushort4*)qp,         qb = *(const ushort4*)(qp + 4);
    ushort4 ka = *(const ushort4*)(qp + 192), kb = *(const ushort4*)(qp + 196);
    float qf[8] = {bf2f(qa.x), bf2f(qa.y), bf2f(qa.z), bf2f(qa.w),
                   bf2f(qb.x), bf2f(qb.y), bf2f(qb.z), bf2f(qb.w)};
    float kf[8] = {bf2f(ka.x), bf2f(ka.y), bf2f(ka.z), bf2f(ka.w),
                   bf2f(kb.x), bf2f(kb.y), bf2f(kb.z), bf2f(kb.w)};
    float sq = 0.f, sk = 0.f;
#pragma unroll
    for (int d = 0; d < 8; ++d) { sq += qf[d] * qf[d]; sk += kf[d] * kf[d]; }
    sq += __shfl_xor(sq, 1); sq += __shfl_xor(sq, 2);
    sk += __shfl_xor(sk, 1); sk += __shfl_xor(sk, 2);
    float rq = scale / fmaxf(sqrtf(sq), 1e-12f);
    float rk = 1.f   / fmaxf(sqrtf(sk), 1e-12f);
    ushort_t* qd = &qs[r][c * 8];
    *(ushort4*)(qd + 0) = make_ushort4(f2bf(qf[0]*rq), f2bf(qf[1]*rq), f2bf(qf[2]*rq), f2bf(qf[3]*rq));
    *(ushort4*)(qd + 4) = make_ushort4(f2bf(qf[4]*rq), f2bf(qf[5]*rq), f2bf(qf[6]*rq), f2bf(qf[7]*rq));
    ushort_t* kd = &ksl[r][c * 8];
    *(ushort4*)(kd + 0) = make_ushort4(f2bf(kf[0]*rk), f2bf(kf[1]*rk), f2bf(kf[2]*rk), f2bf(kf[3]*rk));
    *(ushort4*)(kd + 4) = make_ushort4(f2bf(kf[4]*rk), f2bf(kf[5]*rk), f2bf(kf[6]*rk), f2bf(kf[7]*rk));
  }
  __syncthreads();

  int lane = t & 63, w = t >> 6;
  int lr = lane & 15, lg = lane >> 4;

  short8 aq = *(const short8*)&qs[w * 16 + lr][lg * 8];
  f32x4 acc[4];
  __builtin_amdgcn_s_setprio(1);
#pragma unroll
  for (int fn = 0; fn < 4; ++fn) {
    acc[fn] = (f32x4){0.f, 0.f, 0.f, 0.f};
    short8 bk = *(const short8*)&ksl[fn * 16 + lr][lg * 8];
    acc[fn] = __builtin_amdgcn_mfma_f32_16x16x32_bf16(aq, bk, acc[fn], 0, 0, 0);
  }
  __builtin_amdgcn_s_setprio(0);

  float rsum[4];
#pragma unroll
  for (int r = 0; r < 4; ++r) {
    int row = w * 16 + lg * 4 + r;
    int rd = (row * 9363) >> 16, rm = row - 7 * rd;
    int gr = region3(wh0 + rd) * 3 + region3(ww0 + rm);
    bool rv = row < 49;
    float sv[4];
#pragma unroll
    for (int fn = 0; fn < 4; ++fn) {
      int col = fn * 16 + lr;
      int jd = (col * 9363) >> 16, jm = col - 7 * jd;
      int gj = region3(wh0 + jd) * 3 + region3(ww0 + jm);
      bool cv = rv && (col < 49);
      int idx = cv ? (rd - jd + 6) * 13 + (rm - jm + 6) : 0;
      float s = acc[fn][r] + tab_l[idx] + (gr == gj ? 0.f : -100.f);
      sv[fn] = cv ? s : -1e30f;
    }
    float m = fmaxf(fmaxf(sv[0], sv[1]), fmaxf(sv[2], sv[3]));
#pragma unroll
    for (int o = 1; o < 16; o <<= 1) m = fmaxf(m, __shfl_xor(m, o));
    float sum = 0.f;
#pragma unroll
    for (int fn = 0; fn < 4; ++fn) {
      float e = __expf(sv[fn] - m);
      sum += e;
      int pc = ((fn >> 1) << 5) + 8 * (lr >> 2) + ((fn & 1) << 2) + (lr & 3);
      ps[row][pc] = f2bf(e);
    }
#pragma unroll
    for (int o = 1; o < 16; o <<= 1) sum += __shfl_xor(sum, o);
    rsum[r] = 1.f / sum;
  }
  __syncthreads();

  short8 ap0 = *(const short8*)&ps[w * 16 + lr][lg * 8];
  short8 ap1 = *(const short8*)&ps[w * 16 + lr][32 + lg * 8];
  f32x4 o2[2];
  __builtin_amdgcn_s_setprio(1);
#pragma unroll
  for (int f = 0; f < 2; ++f) {
    o2[f] = (f32x4){0.f, 0.f, 0.f, 0.f};
    short8 bv0 = *(const short8*)&vsl[f * 16 + lr][lg * 8];
    short8 bv1 = *(const short8*)&vsl[f * 16 + lr][32 + lg * 8];
    o2[f] = __builtin_amdgcn_mfma_f32_16x16x32_bf16(ap0, bv0, o2[f], 0, 0, 0);
    o2[f] = __builtin_amdgcn_mfma_f32_16x16x32_bf16(ap1, bv1, o2[f], 0, 0, 0);
  }
  __builtin_amdgcn_s_setprio(0);
#pragma unroll
  for (int f = 0; f < 2; ++f) {
#pragma unroll
    for (int r = 0; r < 4; ++r) {
      int row = w * 16 + lg * 4 + r;
      if (row < 49)
        attn_out[((size_t)win * 49 + row) * 192 + head * 32 + f * 16 + lr] =
            f2bf(o2[f][r] * rsum[r]);
    }
  }
}

// ---------------------------------------------------------------------------
extern "C" void kernel_launch(void* const* d_in, const int* in_sizes, int n_in,
                              void* d_out, int out_size, void* d_ws, size_t ws_size,
                              hipStream_t stream) {
  (void)in_sizes; (void)n_in; (void)out_size; (void)ws_size;
  const float* x    = (const float*)d_in[0];
  const float* qkvw = (const float*)d_in[1];
  const float* qb   = (const float*)d_in[2];
  const float* vb   = (const float*)d_in[3];
  const float* ls   = (const float*)d_in[4];
  const float* cw1  = (const float*)d_in[5];
  const float* cb1  = (const float*)d_in[6];
  const float* cw2  = (const float*)d_in[7];
  const float* pw   = (const float*)d_in[8];
  const float* pb   = (const float*)d_in[9];
  const float* n1g  = (const float*)d_in[10];
  const float* n1b  = (const float*)d_in[11];
  const float* n2g  = (const float*)d_in[12];
  const float* n2b  = (const float*)d_in[13];
  const float* f1w  = (const float*)d_in[14];
  const float* f1b  = (const float*)d_in[15];
  const float* f2w  = (const float*)d_in[16];
  const float* f2b  = (const float*)d_in[17];
  float* out = (float*)d_out;

  char* ws = (char*)d_ws;
  ushort_t* wq_bf = (ushort_t*)ws;                 // 110592 (perm K=192)
  ushort_t* wp_bf = wq_bf + 110592;                // 36864  (perm K=192)
  ushort_t* w1_bf = wp_bf + 36864;                 // 147456 (perm K=192)
  ushort_t* w2_bf = w1_bf + 147456;                // 147456 (perm K=768)
  float*    tab_s = (float*)(w2_bf + 147456);      // 6*169 floats
  const size_t OFF_BIG = 1 << 20;
  ushort_t* qkv_out = (ushort_t*)(ws + OFF_BIG);
  ushort_t* xw_bf   = (ushort_t*)(ws + OFF_BIG + 115605504);
  ushort_t* attn_o  = (ushort_t*)(ws + OFF_BIG + 115605504);
  ushort_t* x1_bf   = (ushort_t*)(ws + OFF_BIG + 154140672);
  ushort_t* hmid    = (ushort_t*)(ws + OFF_BIG);   // 100352*768 bf16 over R1+R2

  cvt_perm_all<<<1728, 256, 0, stream>>>(qkvw, pw, f1w, f2w, wq_bf, wp_bf, w1_bf, w2_bf);
  cpb_kernel<<<169, 256, 0, stream>>>(cw1, cb1, cw2, tab_s);
  gather_cvt_kernel<<<9408, 256, 0, stream>>>(x, xw_bf);

  // qkv (3-buffer counted-vmcnt pipeline + setprio)
  gemm_p3<192, 0><<<dim3(784, 3), 512, 0, stream>>>(xw_bf, wq_bf, qb, vb, qkv_out, 576);
  // attention (+ setprio)
  attn_kernel<<<dim3(2048, 6), 256, 0, stream>>>(qkv_out, ls, tab_s, attn_o);
  // proj (pre-LN, in-place over attn_o) + perm-aware LN1/residual
  gemm_g512<192, 2><<<dim3(784, 1), 512, 0, stream>>>(attn_o, wp_bf, pb, nullptr, attn_o, 192);
  ln_resid_kernel<<<25088, 256, 0, stream>>>(attn_o, x, n1g, n1b, x1_bf);
  // fc1 (silu, 3-buffer counted-vmcnt pipeline + setprio)
  gemm_p3<192, 1><<<dim3(784, 4), 512, 0, stream>>>(x1_bf, w1_bf, f1b, nullptr, hmid, 768);
  // fc2 + LN2 + residual fused -> d_out fp32 (+ setprio)
  gemm_g512_lnfc2<<<784, 512, 0, stream>>>(hmid, w2_bf, f2b, n2g, n2b, x1_bf, out);
}

// Round 20
// 340.252 us; speedup vs baseline: 1.2141x; 1.0446x over previous
//
#include <hip/hip_runtime.h>

// ============================================================================
// Swin V2 block, round 20 = R19 base (355us best) + T1 XCD-chunked swizzle
// with y-fastest decomposition on qkv/fc1 grids.
// Theory: qkv/fc1 FETCH = 2x A-size (y-slabs re-read A on different XCDs).
// Remap lin -> xcd=lin%8, wg=xcd*(NB/8)+lin/8; y=wg%NY (fastest), x=wg/NY:
// each XCD gets contiguous x-range with ALL y -> A panel reused in XCD L2.
// NB 2352/3136 both %8==0 -> bijective (ERRATA #11 ok). Zero structural risk.
// slot32(k) = 8*((k%16)/4) + 4*(k/16) + k%4 (HW-verified). C/D: col=lane%16,
// row=4*(lane/16)+reg.
// ============================================================================

typedef unsigned short ushort_t;
using f32x4  = __attribute__((ext_vector_type(4))) float;
using short8 = __attribute__((ext_vector_type(8))) short;

#define GLOAD(srcp, ldsp) __builtin_amdgcn_global_load_lds(                    \
    (const __attribute__((address_space(1))) void*)(srcp),                     \
    (__attribute__((address_space(3))) void*)(ldsp), 16, 0, 0)

__device__ __forceinline__ ushort_t f2bf(float f) {
  union { float f; unsigned u; } v; v.f = f;
  unsigned r = v.u + 0x7fffu + ((v.u >> 16) & 1u);
  return (ushort_t)(r >> 16);
}
__device__ __forceinline__ float bf2f(ushort_t u) {
  union { unsigned u; float f; } v; v.u = ((unsigned)u) << 16;
  return v.f;
}
__device__ __forceinline__ int slot32(int k) {
  return 8 * ((k & 15) >> 2) + ((k >> 4) << 2) + (k & 3);
}

// windowed-token index m -> image row index (same map for gather and scatter)
__device__ __forceinline__ int img_pos(int m) {
  int win = m / 49, n = m - win * 49;
  int b = win >> 6, wi = win & 63;
  int nd = n / 7, nm = n - nd * 7;
  int hs = (wi >> 3) * 7 + nd;
  int ws = (wi & 7) * 7 + nm;
  int h = hs + 3; if (h >= 56) h -= 56;
  int w = ws + 3; if (w >= 56) w -= 56;
  return b * 3136 + h * 56 + w;
}

__device__ __forceinline__ int region3(int a) { return a < 49 ? 0 : (a < 53 ? 1 : 2); }

// ---------------------------------------------------------------------------
// All four weight tensors converted + k-permuted in ONE launch.
__global__ __launch_bounds__(256) void cvt_perm_all(
    const float* __restrict__ qkvw, const float* __restrict__ pw,
    const float* __restrict__ f1w, const float* __restrict__ f2w,
    ushort_t* __restrict__ wq, ushort_t* __restrict__ wp,
    ushort_t* __restrict__ w1, ushort_t* __restrict__ w2) {
  int i = blockIdx.x * 256 + threadIdx.x;   // 0..442367
  if (i >= 442368) return;
  const float* in; ushort_t* out; int K, j;
  if (i < 110592)      { j = i;          in = qkvw; out = wq; K = 192; }
  else if (i < 147456) { j = i - 110592; in = pw;   out = wp; K = 192; }
  else if (i < 294912) { j = i - 147456; in = f1w;  out = w1; K = 192; }
  else                 { j = i - 294912; in = f2w;  out = w2; K = 768; }
  int row = j / K, c = j - row * K;
  out[row * K + (c & ~31) + slot32(c & 31)] = f2bf(in[j]);
}

// gather shifted windows + cvt + k-permute: xw[m][slot(c)] = bf16(x[img_pos(m)][c])
__global__ __launch_bounds__(256) void gather_cvt_kernel(
    const float* __restrict__ x, ushort_t* __restrict__ xw) {
  int i8 = blockIdx.x * 256 + threadIdx.x;      // 100352*24 tasks of 8 elems
  int m = i8 / 24, c8 = (i8 - m * 24) * 8;
  const float* p = x + (size_t)img_pos(m) * 192 + c8;
  float4 a = *(const float4*)p, b = *(const float4*)(p + 4);
  ushort_t* q = xw + (size_t)m * 192;
  int blk = c8 & ~31;
  int jj = (c8 & 31) >> 3;
  int b4 = ((jj & 1) << 4) | ((jj >> 1) << 2);
  *(ushort4*)(q + blk + b4)     = make_ushort4(f2bf(a.x), f2bf(a.y), f2bf(a.z), f2bf(a.w));
  *(ushort4*)(q + blk + b4 + 8) = make_ushort4(f2bf(b.x), f2bf(b.y), f2bf(b.z), f2bf(b.w));
}

// ---------------------------------------------------------------------------
// CPB: tab_s[head][e] = 16*sigmoid( relu(REL_TABLE[e] @ w1.T + b1) @ w2.T )
__global__ __launch_bounds__(256) void cpb_kernel(
    const float* __restrict__ w1, const float* __restrict__ b1,
    const float* __restrict__ w2, float* __restrict__ tab_s) {
  int e = blockIdx.x;            // 0..168
  int t = threadIdx.x;           // 0..255
  int i = e / 13, j = e - 13 * (e / 13);
  auto cval = [](int a) -> float {
    float r = (a - 6) * (8.0f / 6.0f);
    float v = log2f(fabsf(r) + 1.f) * (1.f / 3.f);
    return r < 0.f ? -v : v;
  };
  float ci = cval(i), cj = cval(j);
  float h = fmaxf(ci * w1[2 * t] + cj * w1[2 * t + 1] + b1[t], 0.f);
  __shared__ float red[256];
  for (int head = 0; head < 6; ++head) {
    red[t] = h * w2[head * 256 + t];
    __syncthreads();
    for (int st = 128; st > 0; st >>= 1) {
      if (t < st) red[t] += red[t + st];
      __syncthreads();
    }
    if (t == 0) tab_s[head * 169 + e] = 16.f / (1.f + __expf(-red[0]));
    __syncthreads();
  }
}

// ---------------------------------------------------------------------------
// 3-buffer counted-vmcnt gload GEMM (T3/T4) + T5 setprio + T1 XCD swizzle.
// tile 128x192, BK=32, 512 thr = 8 waves (4x2 of 32x96), acc[2][6].
// 1-D grid NB = 784*NY; xcd-chunked, y-fastest. Output k-permuted.
// MODE 0: qkv  MODE 1: fc1(silu)
template<int KTOT, int MODE, int NY>
__global__ __launch_bounds__(512, 4) void gemm_p3(
    const ushort_t* __restrict__ Ab, const ushort_t* __restrict__ W,
    const float* __restrict__ b0, const float* __restrict__ b1,
    ushort_t* __restrict__ out, int NTOT) {
  __shared__ ushort_t Al[3][4096];
  __shared__ ushort_t Bl[3][6144];
  // T1: xcd-chunked swizzle (NB%8==0), y-fastest for A reuse within XCD L2
  const int NB = 784 * NY;
  int lin = blockIdx.x;
  int wg = (lin & 7) * (NB >> 3) + (lin >> 3);
  int m0 = (wg / NY) * 128, n0 = (wg % NY) * 192;
  int t = threadIdx.x;
  int lane = t & 63, wid = t >> 6;
  int wm = wid >> 1, wn = wid & 1;
  int lr = lane & 15, lg = lane >> 4;

  bool stager = (t < 256);
  int sw = (t & 255) >> 6;
  int rloc = lane >> 2;
  int csrc = (lane & 3) ^ ((lane >> 3) & 3);
  int ca = sw * 2, cb = sw * 3;
  const ushort_t* sA0 = Ab + (size_t)(m0 + ca * 16      + rloc) * KTOT + csrc * 8;
  const ushort_t* sA1 = Ab + (size_t)(m0 + ca * 16 + 16 + rloc) * KTOT + csrc * 8;
  const ushort_t* sB0 = W  + (size_t)(n0 + cb * 16      + rloc) * KTOT + csrc * 8;
  const ushort_t* sB1 = W  + (size_t)(n0 + cb * 16 + 16 + rloc) * KTOT + csrc * 8;
  const ushort_t* sB2 = W  + (size_t)(n0 + cb * 16 + 32 + rloc) * KTOT + csrc * 8;

  auto STAGE = [&](int buf, int kt) {
    GLOAD(sA0 + kt, &Al[buf][(ca + 0) * 512]);
    GLOAD(sA1 + kt, &Al[buf][(ca + 1) * 512]);
    GLOAD(sB0 + kt, &Bl[buf][(cb + 0) * 512]);
    GLOAD(sB1 + kt, &Bl[buf][(cb + 1) * 512]);
    GLOAD(sB2 + kt, &Bl[buf][(cb + 2) * 512]);
  };

  int coff = (lg ^ ((lr >> 1) & 3)) * 8;

  f32x4 acc[2][6];
#pragma unroll
  for (int a = 0; a < 2; ++a)
#pragma unroll
    for (int b = 0; b < 6; ++b) acc[a][b] = (f32x4){0.f, 0.f, 0.f, 0.f};

  const int NT = KTOT / 32;
  if (stager) { STAGE(0, 0); STAGE(1, 32); }
  for (int it = 0; it < NT; ++it) {
    int cur = it % 3;
    if (stager) {
      if (it + 2 < NT) {
        STAGE((it + 2) % 3, (it + 2) * 32);
        asm volatile("s_waitcnt vmcnt(10)" ::: "memory");
      } else if (it + 1 < NT) {
        asm volatile("s_waitcnt vmcnt(5)" ::: "memory");
      } else {
        asm volatile("s_waitcnt vmcnt(0)" ::: "memory");
      }
    }
    __builtin_amdgcn_sched_barrier(0);
    __builtin_amdgcn_s_barrier();
    __builtin_amdgcn_sched_barrier(0);
    short8 af[2], bfv[6];
#pragma unroll
    for (int fm = 0; fm < 2; ++fm)
      af[fm] = *(const short8*)&Al[cur][(wm * 32 + fm * 16 + lr) * 32 + coff];
#pragma unroll
    for (int fn = 0; fn < 6; ++fn)
      bfv[fn] = *(const short8*)&Bl[cur][(wn * 96 + fn * 16 + lr) * 32 + coff];
    __builtin_amdgcn_s_setprio(1);
#pragma unroll
    for (int fm = 0; fm < 2; ++fm)
#pragma unroll
      for (int fn = 0; fn < 6; ++fn)
        acc[fm][fn] = __builtin_amdgcn_mfma_f32_16x16x32_bf16(af[fm], bfv[fn], acc[fm][fn], 0, 0, 0);
    __builtin_amdgcn_s_setprio(0);
    __builtin_amdgcn_sched_barrier(0);
    __builtin_amdgcn_s_barrier();
    __builtin_amdgcn_sched_barrier(0);
  }

#pragma unroll
  for (int fm = 0; fm < 2; ++fm) {
#pragma unroll
    for (int fn = 0; fn < 6; ++fn) {
      int col = n0 + wn * 96 + fn * 16 + lr;
      int colp = n0 + wn * 96 + ((fn >> 1) << 5) +
                 ((lr >> 2) << 3) + ((fn & 1) << 2) + (lr & 3);
      float bias;
      if (MODE == 0) bias = (col < 192) ? b0[col] : ((col < 384) ? 0.f : b1[col - 384]);
      else           bias = b0[col];
#pragma unroll
      for (int r = 0; r < 4; ++r) {
        int row = m0 + wm * 32 + fm * 16 + lg * 4 + r;
        float v = acc[fm][fn][r] + bias;
        if (MODE == 1) v = v / (1.f + __expf(-v));   // silu
        out[(size_t)row * NTOT + colp] = f2bf(v);
      }
    }
  }
}

// ---------------------------------------------------------------------------
// gload_lds 2-phase GEMM + T5 setprio. MODE 2: proj (may alias A in-place)
template<int KTOT, int MODE>
__global__ __launch_bounds__(512, 4) void gemm_g512(
    const ushort_t* __restrict__ Ab, const ushort_t* __restrict__ W,
    const float* __restrict__ b0, const float* __restrict__ b1,
    ushort_t* out, int NTOT) {
  __shared__ ushort_t Al[2][4096];
  __shared__ ushort_t Bl[2][6144];
  int t = threadIdx.x;
  int m0 = blockIdx.x * 128, n0 = blockIdx.y * 192;
  int lane = t & 63, wid = t >> 6;
  int wm = wid >> 1, wn = wid & 1;
  int lr = lane & 15, lg = lane >> 4;

  bool stager = (t < 256);
  int sw = (t & 255) >> 6;
  int rloc = lane >> 2;
  int csrc = (lane & 3) ^ ((lane >> 3) & 3);
  int ca = sw * 2, cb = sw * 3;
  const ushort_t* sA0 = Ab + (size_t)(m0 + ca * 16      + rloc) * KTOT + csrc * 8;
  const ushort_t* sA1 = Ab + (size_t)(m0 + ca * 16 + 16 + rloc) * KTOT + csrc * 8;
  const ushort_t* sB0 = W  + (size_t)(n0 + cb * 16      + rloc) * KTOT + csrc * 8;
  const ushort_t* sB1 = W  + (size_t)(n0 + cb * 16 + 16 + rloc) * KTOT + csrc * 8;
  const ushort_t* sB2 = W  + (size_t)(n0 + cb * 16 + 32 + rloc) * KTOT + csrc * 8;

  auto STAGE = [&](int buf, int kt) {
    GLOAD(sA0 + kt, &Al[buf][(ca + 0) * 512]);
    GLOAD(sA1 + kt, &Al[buf][(ca + 1) * 512]);
    GLOAD(sB0 + kt, &Bl[buf][(cb + 0) * 512]);
    GLOAD(sB1 + kt, &Bl[buf][(cb + 1) * 512]);
    GLOAD(sB2 + kt, &Bl[buf][(cb + 2) * 512]);
  };

  int coff = (lg ^ ((lr >> 1) & 3)) * 8;

  f32x4 acc[2][6];
#pragma unroll
  for (int a = 0; a < 2; ++a)
#pragma unroll
    for (int b = 0; b < 6; ++b) acc[a][b] = (f32x4){0.f, 0.f, 0.f, 0.f};

  const int NT = KTOT / 32;
  if (stager) STAGE(0, 0);
  __syncthreads();
  int cur = 0;
  for (int it = 0; it < NT; ++it) {
    if (stager && it + 1 < NT) STAGE(cur ^ 1, (it + 1) * 32);
    short8 af[2], bfv[6];
#pragma unroll
    for (int fm = 0; fm < 2; ++fm)
      af[fm] = *(const short8*)&Al[cur][(wm * 32 + fm * 16 + lr) * 32 + coff];
#pragma unroll
    for (int fn = 0; fn < 6; ++fn)
      bfv[fn] = *(const short8*)&Bl[cur][(wn * 96 + fn * 16 + lr) * 32 + coff];
    __builtin_amdgcn_s_setprio(1);
#pragma unroll
    for (int fm = 0; fm < 2; ++fm)
#pragma unroll
      for (int fn = 0; fn < 6; ++fn)
        acc[fm][fn] = __builtin_amdgcn_mfma_f32_16x16x32_bf16(af[fm], bfv[fn], acc[fm][fn], 0, 0, 0);
    __builtin_amdgcn_s_setprio(0);
    __syncthreads();
    cur ^= 1;
  }

#pragma unroll
  for (int fm = 0; fm < 2; ++fm) {
#pragma unroll
    for (int fn = 0; fn < 6; ++fn) {
      int col = n0 + wn * 96 + fn * 16 + lr;
      int colp = n0 + wn * 96 + ((fn >> 1) << 5) +
                 ((lr >> 2) << 3) + ((fn & 1) << 2) + (lr & 3);
      float bias;
      if (MODE == 0) bias = (col < 192) ? b0[col] : ((col < 384) ? 0.f : b1[col - 384]);
      else           bias = b0[col];
#pragma unroll
      for (int r = 0; r < 4; ++r) {
        int row = m0 + wm * 32 + fm * 16 + lg * 4 + r;
        float v = acc[fm][fn][r] + bias;
        if (MODE == 1) v = v / (1.f + __expf(-v));
        out[(size_t)row * NTOT + colp] = f2bf(v);
      }
    }
  }
}

// ---------------------------------------------------------------------------
// fc2 (K=768) gload 2-phase + fused LN2 + residual + T5 setprio.
__global__ __launch_bounds__(512, 4) void gemm_g512_lnfc2(
    const ushort_t* __restrict__ Ab, const ushort_t* __restrict__ W,
    const float* __restrict__ bias, const float* __restrict__ gamma,
    const float* __restrict__ beta, const ushort_t* __restrict__ residb,
    float* __restrict__ outf) {
  const int KTOT = 768;
  __shared__ ushort_t Al[2][4096];
  __shared__ ushort_t Bl[2][6144];
  int t = threadIdx.x;
  int m0 = blockIdx.x * 128;
  int lane = t & 63, wid = t >> 6;
  int wm = wid >> 1, wn = wid & 1;
  int lr = lane & 15, lg = lane >> 4;

  bool stager = (t < 256);
  int sw = (t & 255) >> 6;
  int rloc = lane >> 2;
  int csrc = (lane & 3) ^ ((lane >> 3) & 3);
  int ca = sw * 2, cb = sw * 3;
  const ushort_t* sA0 = Ab + (size_t)(m0 + ca * 16      + rloc) * KTOT + csrc * 8;
  const ushort_t* sA1 = Ab + (size_t)(m0 + ca * 16 + 16 + rloc) * KTOT + csrc * 8;
  const ushort_t* sB0 = W  + (size_t)(cb * 16      + rloc) * KTOT + csrc * 8;
  const ushort_t* sB1 = W  + (size_t)(cb * 16 + 16 + rloc) * KTOT + csrc * 8;
  const ushort_t* sB2 = W  + (size_t)(cb * 16 + 32 + rloc) * KTOT + csrc * 8;

  auto STAGE = [&](int buf, int kt) {
    GLOAD(sA0 + kt, &Al[buf][(ca + 0) * 512]);
    GLOAD(sA1 + kt, &Al[buf][(ca + 1) * 512]);
    GLOAD(sB0 + kt, &Bl[buf][(cb + 0) * 512]);
    GLOAD(sB1 + kt, &Bl[buf][(cb + 1) * 512]);
    GLOAD(sB2 + kt, &Bl[buf][(cb + 2) * 512]);
  };

  int coff = (lg ^ ((lr >> 1) & 3)) * 8;

  f32x4 acc[2][6];
#pragma unroll
  for (int a = 0; a < 2; ++a)
#pragma unroll
    for (int b = 0; b < 6; ++b) acc[a][b] = (f32x4){0.f, 0.f, 0.f, 0.f};

  const int NT = KTOT / 32;
  if (stager) STAGE(0, 0);
  __syncthreads();
  int cur = 0;
  for (int it = 0; it < NT; ++it) {
    if (stager && it + 1 < NT) STAGE(cur ^ 1, (it + 1) * 32);
    short8 af[2], bfv[6];
#pragma unroll
    for (int fm = 0; fm < 2; ++fm)
      af[fm] = *(const short8*)&Al[cur][(wm * 32 + fm * 16 + lr) * 32 + coff];
#pragma unroll
    for (int fn = 0; fn < 6; ++fn)
      bfv[fn] = *(const short8*)&Bl[cur][(wn * 96 + fn * 16 + lr) * 32 + coff];
    __builtin_amdgcn_s_setprio(1);
#pragma unroll
    for (int fm = 0; fm < 2; ++fm)
#pragma unroll
      for (int fn = 0; fn < 6; ++fn)
        acc[fm][fn] = __builtin_amdgcn_mfma_f32_16x16x32_bf16(af[fm], bfv[fn], acc[fm][fn], 0, 0, 0);
    __builtin_amdgcn_s_setprio(0);
    __syncthreads();
    cur ^= 1;
  }

  float* part = (float*)&Bl[0][0];
#pragma unroll
  for (int fm = 0; fm < 2; ++fm) {
#pragma unroll
    for (int r = 0; r < 4; ++r) {
      float s1 = 0.f, s2 = 0.f;
#pragma unroll
      for (int fn = 0; fn < 6; ++fn) {
        int col = wn * 96 + fn * 16 + lr;
        float v = acc[fm][fn][r] + bias[col];
        acc[fm][fn][r] = v;
        s1 += v; s2 += v * v;
      }
#pragma unroll
      for (int off = 1; off < 16; off <<= 1) {
        s1 += __shfl_xor(s1, off);
        s2 += __shfl_xor(s2, off);
      }
      if (lr == 0) {
        int lrow = wm * 32 + fm * 16 + lg * 4 + r;
        part[(wn * 128 + lrow) * 2 + 0] = s1;
        part[(wn * 128 + lrow) * 2 + 1] = s2;
      }
    }
  }
  __syncthreads();
#pragma unroll
  for (int fm = 0; fm < 2; ++fm) {
#pragma unroll
    for (int r = 0; r < 4; ++r) {
      int lrow = wm * 32 + fm * 16 + lg * 4 + r;
      float s1 = part[lrow * 2 + 0] + part[(128 + lrow) * 2 + 0];
      float s2 = part[lrow * 2 + 1] + part[(128 + lrow) * 2 + 1];
      float mean = s1 * (1.f / 192.f);
      float var  = s2 * (1.f / 192.f) - mean * mean;
      float rstd = rsqrtf(fmaxf(var, 0.f) + 1e-5f);
      size_t og = (size_t)(m0 + lrow) * 192;
#pragma unroll
      for (int fn = 0; fn < 6; ++fn) {
        int col = wn * 96 + fn * 16 + lr;
        int colp = (col & ~31) + slot32(col & 31);
        float l = (acc[fm][fn][r] - mean) * rstd * gamma[col] + beta[col];
        outf[og + col] = bf2f(residb[og + colp]) + l;
      }
    }
  }
}

// ---------------------------------------------------------------------------
// Streaming LayerNorm + residual for proj output (perm-aware). (R19 verbatim)
__global__ __launch_bounds__(256) void ln_resid_kernel(
    const ushort_t* __restrict__ pre, const float* __restrict__ residf,
    const float* __restrict__ gamma, const float* __restrict__ beta,
    ushort_t* __restrict__ outb) {
  int m = (blockIdx.x * 256 + threadIdx.x) >> 6;   // row
  int lane = threadIdx.x & 63;
  int c0 = lane, c1 = lane + 64, c2 = lane + 128;
  int s0 = (c0 & ~31) + slot32(c0 & 31);
  int s1c = (c1 & ~31) + slot32(c1 & 31);
  int s2c = (c2 & ~31) + slot32(c2 & 31);
  const ushort_t* p = pre + (size_t)m * 192;
  float v0 = bf2f(p[s0]), v1 = bf2f(p[s1c]), v2 = bf2f(p[s2c]);
  float s1 = v0 + v1 + v2;
  float s2 = v0 * v0 + v1 * v1 + v2 * v2;
#pragma unroll
  for (int o = 1; o < 64; o <<= 1) {
    s1 += __shfl_xor(s1, o);
    s2 += __shfl_xor(s2, o);
  }
  float mean = s1 * (1.f / 192.f);
  float var  = s2 * (1.f / 192.f) - mean * mean;
  float rstd = rsqrtf(fmaxf(var, 0.f) + 1e-5f);
  float l0 = (v0 - mean) * rstd * gamma[c0] + beta[c0];
  float l1 = (v1 - mean) * rstd * gamma[c1] + beta[c1];
  float l2 = (v2 - mean) * rstd * gamma[c2] + beta[c2];
  size_t og = (size_t)img_pos(m) * 192;
  outb[og + s0]  = f2bf(residf[og + c0] + l0);
  outb[og + s1c] = f2bf(residf[og + c1] + l1);
  outb[og + s2c] = f2bf(residf[og + c2] + l2);
}

// ---------------------------------------------------------------------------
// Attention (MFMA) + T5 setprio: block = (window, head), 256 threads = 4 waves.
__global__ __launch_bounds__(256) void attn_kernel(
    const ushort_t* __restrict__ qkv, const float* __restrict__ logit_scale,
    const float* __restrict__ tab_s, ushort_t* __restrict__ attn_out) {
  __shared__ ushort_t qs[64][40];
  __shared__ ushort_t ksl[64][40];
  __shared__ ushort_t vsl[32][80];
  __shared__ ushort_t ps[64][80];
  __shared__ float tab_l[169];
  int win = blockIdx.x, head = blockIdx.y;
  int t = threadIdx.x;
  int wi = win & 63;
  int wh0 = (wi >> 3) * 7, ww0 = (wi & 7) * 7;
  size_t base = (size_t)win * 49 * 576 + head * 32;

  for (int u = t; u < 169; u += 256) tab_l[u] = tab_s[head * 169 + u];

  for (int u = t; u < 240; u += 256) {
    int arr = u / 120, v = u - arr * 120;
    int r = 49 + (v >> 3), c4 = (v & 7) << 2;
    ushort_t* p = arr ? &ksl[r][c4] : &qs[r][c4];
    *(ushort4*)p = make_ushort4(0, 0, 0, 0);
  }

  for (int u = t; u < 2048; u += 256) {
    int key = u >> 5, d = u & 31;
    ushort_t val = 0;
    if (key < 49) val = qkv[base + (size_t)key * 576 + 384 + d];
    int kk = key & 31;
    int pc = ((key >> 5) << 5) + 8 * ((kk >> 2) & 3) + 4 * (kk >> 4) + (kk & 3);
    vsl[d][pc] = val;
  }

  float scale = __expf(fminf(logit_scale[head], 4.605170186f));  // ln(100)

  if (t < 196) {
    int r = t >> 2, c = t & 3;
    const ushort_t* qp = qkv + base + (size_t)r * 576 + c * 8;
    ushort4 qa = *(const ushort4*)qp,         qb = *(const ushort4*)(qp + 4);
    ushort4 ka = *(const ushort4*)(qp + 192), kb = *(const ushort4*)(qp + 196);
    float qf[8] = {bf2f(qa.x), bf2f(qa.y), bf2f(qa.z), bf2f(qa.w),
                   bf2f(qb.x), bf2f(qb.y), bf2f(qb.z), bf2f(qb.w)};
    float kf[8] = {bf2f(ka.x), bf2f(ka.y), bf2f(ka.z), bf2f(ka.w),
                   bf2f(kb.x), bf2f(kb.y), bf2f(kb.z), bf2f(kb.w)};
    float sq = 0.f, sk = 0.f;
#pragma unroll
    for (int d = 0; d < 8; ++d) { sq += qf[d] * qf[d]; sk += kf[d] * kf[d]; }
    sq += __shfl_xor(sq, 1); sq += __shfl_xor(sq, 2);
    sk += __shfl_xor(sk, 1); sk += __shfl_xor(sk, 2);
    float rq = scale / fmaxf(sqrtf(sq), 1e-12f);
    float rk = 1.f   / fmaxf(sqrtf(sk), 1e-12f);
    ushort_t* qd = &qs[r][c * 8];
    *(ushort4*)(qd + 0) = make_ushort4(f2bf(qf[0]*rq), f2bf(qf[1]*rq), f2bf(qf[2]*rq), f2bf(qf[3]*rq));
    *(ushort4*)(qd + 4) = make_ushort4(f2bf(qf[4]*rq), f2bf(qf[5]*rq), f2bf(qf[6]*rq), f2bf(qf[7]*rq));
    ushort_t* kd = &ksl[r][c * 8];
    *(ushort4*)(kd + 0) = make_ushort4(f2bf(kf[0]*rk), f2bf(kf[1]*rk), f2bf(kf[2]*rk), f2bf(kf[3]*rk));
    *(ushort4*)(kd + 4) = make_ushort4(f2bf(kf[4]*rk), f2bf(kf[5]*rk), f2bf(kf[6]*rk), f2bf(kf[7]*rk));
  }
  __syncthreads();

  int lane = t & 63, w = t >> 6;
  int lr = lane & 15, lg = lane >> 4;

  short8 aq = *(const short8*)&qs[w * 16 + lr][lg * 8];
  f32x4 acc[4];
  __builtin_amdgcn_s_setprio(1);
#pragma unroll
  for (int fn = 0; fn < 4; ++fn) {
    acc[fn] = (f32x4){0.f, 0.f, 0.f, 0.f};
    short8 bk = *(const short8*)&ksl[fn * 16 + lr][lg * 8];
    acc[fn] = __builtin_amdgcn_mfma_f32_16x16x32_bf16(aq, bk, acc[fn], 0, 0, 0);
  }
  __builtin_amdgcn_s_setprio(0);

  float rsum[4];
#pragma unroll
  for (int r = 0; r < 4; ++r) {
    int row = w * 16 + lg * 4 + r;
    int rd = (row * 9363) >> 16, rm = row - 7 * rd;
    int gr = region3(wh0 + rd) * 3 + region3(ww0 + rm);
    bool rv = row < 49;
    float sv[4];
#pragma unroll
    for (int fn = 0; fn < 4; ++fn) {
      int col = fn * 16 + lr;
      int jd = (col * 9363) >> 16, jm = col - 7 * jd;
      int gj = region3(wh0 + jd) * 3 + region3(ww0 + jm);
      bool cv = rv && (col < 49);
      int idx = cv ? (rd - jd + 6) * 13 + (rm - jm + 6) : 0;
      float s = acc[fn][r] + tab_l[idx] + (gr == gj ? 0.f : -100.f);
      sv[fn] = cv ? s : -1e30f;
    }
    float m = fmaxf(fmaxf(sv[0], sv[1]), fmaxf(sv[2], sv[3]));
#pragma unroll
    for (int o = 1; o < 16; o <<= 1) m = fmaxf(m, __shfl_xor(m, o));
    float sum = 0.f;
#pragma unroll
    for (int fn = 0; fn < 4; ++fn) {
      float e = __expf(sv[fn] - m);
      sum += e;
      int pc = ((fn >> 1) << 5) + 8 * (lr >> 2) + ((fn & 1) << 2) + (lr & 3);
      ps[row][pc] = f2bf(e);
    }
#pragma unroll
    for (int o = 1; o < 16; o <<= 1) sum += __shfl_xor(sum, o);
    rsum[r] = 1.f / sum;
  }
  __syncthreads();

  short8 ap0 = *(const short8*)&ps[w * 16 + lr][lg * 8];
  short8 ap1 = *(const short8*)&ps[w * 16 + lr][32 + lg * 8];
  f32x4 o2[2];
  __builtin_amdgcn_s_setprio(1);
#pragma unroll
  for (int f = 0; f < 2; ++f) {
    o2[f] = (f32x4){0.f, 0.f, 0.f, 0.f};
    short8 bv0 = *(const short8*)&vsl[f * 16 + lr][lg * 8];
    short8 bv1 = *(const short8*)&vsl[f * 16 + lr][32 + lg * 8];
    o2[f] = __builtin_amdgcn_mfma_f32_16x16x32_bf16(ap0, bv0, o2[f], 0, 0, 0);
    o2[f] = __builtin_amdgcn_mfma_f32_16x16x32_bf16(ap1, bv1, o2[f], 0, 0, 0);
  }
  __builtin_amdgcn_s_setprio(0);
#pragma unroll
  for (int f = 0; f < 2; ++f) {
#pragma unroll
    for (int r = 0; r < 4; ++r) {
      int row = w * 16 + lg * 4 + r;
      if (row < 49)
        attn_out[((size_t)win * 49 + row) * 192 + head * 32 + f * 16 + lr] =
            f2bf(o2[f][r] * rsum[r]);
    }
  }
}

// ---------------------------------------------------------------------------
extern "C" void kernel_launch(void* const* d_in, const int* in_sizes, int n_in,
                              void* d_out, int out_size, void* d_ws, size_t ws_size,
                              hipStream_t stream) {
  (void)in_sizes; (void)n_in; (void)out_size; (void)ws_size;
  const float* x    = (const float*)d_in[0];
  const float* qkvw = (const float*)d_in[1];
  const float* qb   = (const float*)d_in[2];
  const float* vb   = (const float*)d_in[3];
  const float* ls   = (const float*)d_in[4];
  const float* cw1  = (const float*)d_in[5];
  const float* cb1  = (const float*)d_in[6];
  const float* cw2  = (const float*)d_in[7];
  const float* pw   = (const float*)d_in[8];
  const float* pb   = (const float*)d_in[9];
  const float* n1g  = (const float*)d_in[10];
  const float* n1b  = (const float*)d_in[11];
  const float* n2g  = (const float*)d_in[12];
  const float* n2b  = (const float*)d_in[13];
  const float* f1w  = (const float*)d_in[14];
  const float* f1b  = (const float*)d_in[15];
  const float* f2w  = (const float*)d_in[16];
  const float* f2b  = (const float*)d_in[17];
  float* out = (float*)d_out;

  char* ws = (char*)d_ws;
  ushort_t* wq_bf = (ushort_t*)ws;                 // 110592 (perm K=192)
  ushort_t* wp_bf = wq_bf + 110592;                // 36864  (perm K=192)
  ushort_t* w1_bf = wp_bf + 36864;                 // 147456 (perm K=192)
  ushort_t* w2_bf = w1_bf + 147456;                // 147456 (perm K=768)
  float*    tab_s = (float*)(w2_bf + 147456);      // 6*169 floats
  const size_t OFF_BIG = 1 << 20;
  ushort_t* qkv_out = (ushort_t*)(ws + OFF_BIG);
  ushort_t* xw_bf   = (ushort_t*)(ws + OFF_BIG + 115605504);
  ushort_t* attn_o  = (ushort_t*)(ws + OFF_BIG + 115605504);
  ushort_t* x1_bf   = (ushort_t*)(ws + OFF_BIG + 154140672);
  ushort_t* hmid    = (ushort_t*)(ws + OFF_BIG);   // 100352*768 bf16 over R1+R2

  cvt_perm_all<<<1728, 256, 0, stream>>>(qkvw, pw, f1w, f2w, wq_bf, wp_bf, w1_bf, w2_bf);
  cpb_kernel<<<169, 256, 0, stream>>>(cw1, cb1, cw2, tab_s);
  gather_cvt_kernel<<<9408, 256, 0, stream>>>(x, xw_bf);

  // qkv (p3 pipeline + setprio + XCD swizzle, y-fastest)
  gemm_p3<192, 0, 3><<<2352, 512, 0, stream>>>(xw_bf, wq_bf, qb, vb, qkv_out, 576);
  // attention (+ setprio)
  attn_kernel<<<dim3(2048, 6), 256, 0, stream>>>(qkv_out, ls, tab_s, attn_o);
  // proj (pre-LN, in-place over attn_o) + perm-aware LN1/residual
  gemm_g512<192, 2><<<dim3(784, 1), 512, 0, stream>>>(attn_o, wp_bf, pb, nullptr, attn_o, 192);
  ln_resid_kernel<<<25088, 256, 0, stream>>>(attn_o, x, n1g, n1b, x1_bf);
  // fc1 (silu, p3 pipeline + setprio + XCD swizzle, y-fastest)
  gemm_p3<192, 1, 4><<<3136, 512, 0, stream>>>(x1_bf, w1_bf, f1b, nullptr, hmid, 768);
  // fc2 + LN2 + residual fused -> d_out fp32 (+ setprio)
  gemm_g512_lnfc2<<<784, 512, 0, stream>>>(hmid, w2_bf, f2b, n2g, n2b, x1_bf, out);
}

// Round 21
// 339.260 us; speedup vs baseline: 1.2177x; 1.0029x over previous
//
#include <hip/hip_runtime.h>

// ============================================================================
// Swin V2 block, round 21 = R20 base (340us best) + T1 XCD-chunked swizzle on
// the ATTENTION grid: 1-D 12288 blocks, idx=(lin&7)*1536+lin/8, win=idx/6,
// head=idx%6 -> all 6 heads of a window temporally+XCD adjacent; head pairs
// share 128B qkv cache lines -> attn FETCH ~halves.
// R20 post-mortem: qkv/fc1 FETCH 76.6->20MB (T1 works); GEMMs plateaued
// across 7 structures (~85-95us each) - done tuning them.
// slot32(k) = 8*((k%16)/4) + 4*(k/16) + k%4 (HW-verified). C/D: col=lane%16,
// row=4*(lane/16)+reg.
// ============================================================================

typedef unsigned short ushort_t;
using f32x4  = __attribute__((ext_vector_type(4))) float;
using short8 = __attribute__((ext_vector_type(8))) short;

#define GLOAD(srcp, ldsp) __builtin_amdgcn_global_load_lds(                    \
    (const __attribute__((address_space(1))) void*)(srcp),                     \
    (__attribute__((address_space(3))) void*)(ldsp), 16, 0, 0)

__device__ __forceinline__ ushort_t f2bf(float f) {
  union { float f; unsigned u; } v; v.f = f;
  unsigned r = v.u + 0x7fffu + ((v.u >> 16) & 1u);
  return (ushort_t)(r >> 16);
}
__device__ __forceinline__ float bf2f(ushort_t u) {
  union { unsigned u; float f; } v; v.u = ((unsigned)u) << 16;
  return v.f;
}
__device__ __forceinline__ int slot32(int k) {
  return 8 * ((k & 15) >> 2) + ((k >> 4) << 2) + (k & 3);
}

// windowed-token index m -> image row index (same map for gather and scatter)
__device__ __forceinline__ int img_pos(int m) {
  int win = m / 49, n = m - win * 49;
  int b = win >> 6, wi = win & 63;
  int nd = n / 7, nm = n - nd * 7;
  int hs = (wi >> 3) * 7 + nd;
  int ws = (wi & 7) * 7 + nm;
  int h = hs + 3; if (h >= 56) h -= 56;
  int w = ws + 3; if (w >= 56) w -= 56;
  return b * 3136 + h * 56 + w;
}

__device__ __forceinline__ int region3(int a) { return a < 49 ? 0 : (a < 53 ? 1 : 2); }

// ---------------------------------------------------------------------------
// All four weight tensors converted + k-permuted in ONE launch.
__global__ __launch_bounds__(256) void cvt_perm_all(
    const float* __restrict__ qkvw, const float* __restrict__ pw,
    const float* __restrict__ f1w, const float* __restrict__ f2w,
    ushort_t* __restrict__ wq, ushort_t* __restrict__ wp,
    ushort_t* __restrict__ w1, ushort_t* __restrict__ w2) {
  int i = blockIdx.x * 256 + threadIdx.x;   // 0..442367
  if (i >= 442368) return;
  const float* in; ushort_t* out; int K, j;
  if (i < 110592)      { j = i;          in = qkvw; out = wq; K = 192; }
  else if (i < 147456) { j = i - 110592; in = pw;   out = wp; K = 192; }
  else if (i < 294912) { j = i - 147456; in = f1w;  out = w1; K = 192; }
  else                 { j = i - 294912; in = f2w;  out = w2; K = 768; }
  int row = j / K, c = j - row * K;
  out[row * K + (c & ~31) + slot32(c & 31)] = f2bf(in[j]);
}

// gather shifted windows + cvt + k-permute: xw[m][slot(c)] = bf16(x[img_pos(m)][c])
__global__ __launch_bounds__(256) void gather_cvt_kernel(
    const float* __restrict__ x, ushort_t* __restrict__ xw) {
  int i8 = blockIdx.x * 256 + threadIdx.x;      // 100352*24 tasks of 8 elems
  int m = i8 / 24, c8 = (i8 - m * 24) * 8;
  const float* p = x + (size_t)img_pos(m) * 192 + c8;
  float4 a = *(const float4*)p, b = *(const float4*)(p + 4);
  ushort_t* q = xw + (size_t)m * 192;
  int blk = c8 & ~31;
  int jj = (c8 & 31) >> 3;
  int b4 = ((jj & 1) << 4) | ((jj >> 1) << 2);
  *(ushort4*)(q + blk + b4)     = make_ushort4(f2bf(a.x), f2bf(a.y), f2bf(a.z), f2bf(a.w));
  *(ushort4*)(q + blk + b4 + 8) = make_ushort4(f2bf(b.x), f2bf(b.y), f2bf(b.z), f2bf(b.w));
}

// ---------------------------------------------------------------------------
// CPB: tab_s[head][e] = 16*sigmoid( relu(REL_TABLE[e] @ w1.T + b1) @ w2.T )
__global__ __launch_bounds__(256) void cpb_kernel(
    const float* __restrict__ w1, const float* __restrict__ b1,
    const float* __restrict__ w2, float* __restrict__ tab_s) {
  int e = blockIdx.x;            // 0..168
  int t = threadIdx.x;           // 0..255
  int i = e / 13, j = e - 13 * (e / 13);
  auto cval = [](int a) -> float {
    float r = (a - 6) * (8.0f / 6.0f);
    float v = log2f(fabsf(r) + 1.f) * (1.f / 3.f);
    return r < 0.f ? -v : v;
  };
  float ci = cval(i), cj = cval(j);
  float h = fmaxf(ci * w1[2 * t] + cj * w1[2 * t + 1] + b1[t], 0.f);
  __shared__ float red[256];
  for (int head = 0; head < 6; ++head) {
    red[t] = h * w2[head * 256 + t];
    __syncthreads();
    for (int st = 128; st > 0; st >>= 1) {
      if (t < st) red[t] += red[t + st];
      __syncthreads();
    }
    if (t == 0) tab_s[head * 169 + e] = 16.f / (1.f + __expf(-red[0]));
    __syncthreads();
  }
}

// ---------------------------------------------------------------------------
// 3-buffer counted-vmcnt gload GEMM (T3/T4) + T5 setprio + T1 XCD swizzle.
// tile 128x192, BK=32, 512 thr = 8 waves (4x2 of 32x96), acc[2][6].
// 1-D grid NB = 784*NY; xcd-chunked, y-fastest. Output k-permuted.
// MODE 0: qkv  MODE 1: fc1(silu)
template<int KTOT, int MODE, int NY>
__global__ __launch_bounds__(512, 4) void gemm_p3(
    const ushort_t* __restrict__ Ab, const ushort_t* __restrict__ W,
    const float* __restrict__ b0, const float* __restrict__ b1,
    ushort_t* __restrict__ out, int NTOT) {
  __shared__ ushort_t Al[3][4096];
  __shared__ ushort_t Bl[3][6144];
  const int NB = 784 * NY;
  int lin = blockIdx.x;
  int wg = (lin & 7) * (NB >> 3) + (lin >> 3);
  int m0 = (wg / NY) * 128, n0 = (wg % NY) * 192;
  int t = threadIdx.x;
  int lane = t & 63, wid = t >> 6;
  int wm = wid >> 1, wn = wid & 1;
  int lr = lane & 15, lg = lane >> 4;

  bool stager = (t < 256);
  int sw = (t & 255) >> 6;
  int rloc = lane >> 2;
  int csrc = (lane & 3) ^ ((lane >> 3) & 3);
  int ca = sw * 2, cb = sw * 3;
  const ushort_t* sA0 = Ab + (size_t)(m0 + ca * 16      + rloc) * KTOT + csrc * 8;
  const ushort_t* sA1 = Ab + (size_t)(m0 + ca * 16 + 16 + rloc) * KTOT + csrc * 8;
  const ushort_t* sB0 = W  + (size_t)(n0 + cb * 16      + rloc) * KTOT + csrc * 8;
  const ushort_t* sB1 = W  + (size_t)(n0 + cb * 16 + 16 + rloc) * KTOT + csrc * 8;
  const ushort_t* sB2 = W  + (size_t)(n0 + cb * 16 + 32 + rloc) * KTOT + csrc * 8;

  auto STAGE = [&](int buf, int kt) {
    GLOAD(sA0 + kt, &Al[buf][(ca + 0) * 512]);
    GLOAD(sA1 + kt, &Al[buf][(ca + 1) * 512]);
    GLOAD(sB0 + kt, &Bl[buf][(cb + 0) * 512]);
    GLOAD(sB1 + kt, &Bl[buf][(cb + 1) * 512]);
    GLOAD(sB2 + kt, &Bl[buf][(cb + 2) * 512]);
  };

  int coff = (lg ^ ((lr >> 1) & 3)) * 8;

  f32x4 acc[2][6];
#pragma unroll
  for (int a = 0; a < 2; ++a)
#pragma unroll
    for (int b = 0; b < 6; ++b) acc[a][b] = (f32x4){0.f, 0.f, 0.f, 0.f};

  const int NT = KTOT / 32;
  if (stager) { STAGE(0, 0); STAGE(1, 32); }
  for (int it = 0; it < NT; ++it) {
    int cur = it % 3;
    if (stager) {
      if (it + 2 < NT) {
        STAGE((it + 2) % 3, (it + 2) * 32);
        asm volatile("s_waitcnt vmcnt(10)" ::: "memory");
      } else if (it + 1 < NT) {
        asm volatile("s_waitcnt vmcnt(5)" ::: "memory");
      } else {
        asm volatile("s_waitcnt vmcnt(0)" ::: "memory");
      }
    }
    __builtin_amdgcn_sched_barrier(0);
    __builtin_amdgcn_s_barrier();
    __builtin_amdgcn_sched_barrier(0);
    short8 af[2], bfv[6];
#pragma unroll
    for (int fm = 0; fm < 2; ++fm)
      af[fm] = *(const short8*)&Al[cur][(wm * 32 + fm * 16 + lr) * 32 + coff];
#pragma unroll
    for (int fn = 0; fn < 6; ++fn)
      bfv[fn] = *(const short8*)&Bl[cur][(wn * 96 + fn * 16 + lr) * 32 + coff];
    __builtin_amdgcn_s_setprio(1);
#pragma unroll
    for (int fm = 0; fm < 2; ++fm)
#pragma unroll
      for (int fn = 0; fn < 6; ++fn)
        acc[fm][fn] = __builtin_amdgcn_mfma_f32_16x16x32_bf16(af[fm], bfv[fn], acc[fm][fn], 0, 0, 0);
    __builtin_amdgcn_s_setprio(0);
    __builtin_amdgcn_sched_barrier(0);
    __builtin_amdgcn_s_barrier();
    __builtin_amdgcn_sched_barrier(0);
  }

#pragma unroll
  for (int fm = 0; fm < 2; ++fm) {
#pragma unroll
    for (int fn = 0; fn < 6; ++fn) {
      int col = n0 + wn * 96 + fn * 16 + lr;
      int colp = n0 + wn * 96 + ((fn >> 1) << 5) +
                 ((lr >> 2) << 3) + ((fn & 1) << 2) + (lr & 3);
      float bias;
      if (MODE == 0) bias = (col < 192) ? b0[col] : ((col < 384) ? 0.f : b1[col - 384]);
      else           bias = b0[col];
#pragma unroll
      for (int r = 0; r < 4; ++r) {
        int row = m0 + wm * 32 + fm * 16 + lg * 4 + r;
        float v = acc[fm][fn][r] + bias;
        if (MODE == 1) v = v / (1.f + __expf(-v));   // silu
        out[(size_t)row * NTOT + colp] = f2bf(v);
      }
    }
  }
}

// ---------------------------------------------------------------------------
// gload_lds 2-phase GEMM + T5 setprio. MODE 2: proj (may alias A in-place)
template<int KTOT, int MODE>
__global__ __launch_bounds__(512, 4) void gemm_g512(
    const ushort_t* __restrict__ Ab, const ushort_t* __restrict__ W,
    const float* __restrict__ b0, const float* __restrict__ b1,
    ushort_t* out, int NTOT) {
  __shared__ ushort_t Al[2][4096];
  __shared__ ushort_t Bl[2][6144];
  int t = threadIdx.x;
  int m0 = blockIdx.x * 128, n0 = blockIdx.y * 192;
  int lane = t & 63, wid = t >> 6;
  int wm = wid >> 1, wn = wid & 1;
  int lr = lane & 15, lg = lane >> 4;

  bool stager = (t < 256);
  int sw = (t & 255) >> 6;
  int rloc = lane >> 2;
  int csrc = (lane & 3) ^ ((lane >> 3) & 3);
  int ca = sw * 2, cb = sw * 3;
  const ushort_t* sA0 = Ab + (size_t)(m0 + ca * 16      + rloc) * KTOT + csrc * 8;
  const ushort_t* sA1 = Ab + (size_t)(m0 + ca * 16 + 16 + rloc) * KTOT + csrc * 8;
  const ushort_t* sB0 = W  + (size_t)(n0 + cb * 16      + rloc) * KTOT + csrc * 8;
  const ushort_t* sB1 = W  + (size_t)(n0 + cb * 16 + 16 + rloc) * KTOT + csrc * 8;
  const ushort_t* sB2 = W  + (size_t)(n0 + cb * 16 + 32 + rloc) * KTOT + csrc * 8;

  auto STAGE = [&](int buf, int kt) {
    GLOAD(sA0 + kt, &Al[buf][(ca + 0) * 512]);
    GLOAD(sA1 + kt, &Al[buf][(ca + 1) * 512]);
    GLOAD(sB0 + kt, &Bl[buf][(cb + 0) * 512]);
    GLOAD(sB1 + kt, &Bl[buf][(cb + 1) * 512]);
    GLOAD(sB2 + kt, &Bl[buf][(cb + 2) * 512]);
  };

  int coff = (lg ^ ((lr >> 1) & 3)) * 8;

  f32x4 acc[2][6];
#pragma unroll
  for (int a = 0; a < 2; ++a)
#pragma unroll
    for (int b = 0; b < 6; ++b) acc[a][b] = (f32x4){0.f, 0.f, 0.f, 0.f};

  const int NT = KTOT / 32;
  if (stager) STAGE(0, 0);
  __syncthreads();
  int cur = 0;
  for (int it = 0; it < NT; ++it) {
    if (stager && it + 1 < NT) STAGE(cur ^ 1, (it + 1) * 32);
    short8 af[2], bfv[6];
#pragma unroll
    for (int fm = 0; fm < 2; ++fm)
      af[fm] = *(const short8*)&Al[cur][(wm * 32 + fm * 16 + lr) * 32 + coff];
#pragma unroll
    for (int fn = 0; fn < 6; ++fn)
      bfv[fn] = *(const short8*)&Bl[cur][(wn * 96 + fn * 16 + lr) * 32 + coff];
    __builtin_amdgcn_s_setprio(1);
#pragma unroll
    for (int fm = 0; fm < 2; ++fm)
#pragma unroll
      for (int fn = 0; fn < 6; ++fn)
        acc[fm][fn] = __builtin_amdgcn_mfma_f32_16x16x32_bf16(af[fm], bfv[fn], acc[fm][fn], 0, 0, 0);
    __builtin_amdgcn_s_setprio(0);
    __syncthreads();
    cur ^= 1;
  }

#pragma unroll
  for (int fm = 0; fm < 2; ++fm) {
#pragma unroll
    for (int fn = 0; fn < 6; ++fn) {
      int col = n0 + wn * 96 + fn * 16 + lr;
      int colp = n0 + wn * 96 + ((fn >> 1) << 5) +
                 ((lr >> 2) << 3) + ((fn & 1) << 2) + (lr & 3);
      float bias;
      if (MODE == 0) bias = (col < 192) ? b0[col] : ((col < 384) ? 0.f : b1[col - 384]);
      else           bias = b0[col];
#pragma unroll
      for (int r = 0; r < 4; ++r) {
        int row = m0 + wm * 32 + fm * 16 + lg * 4 + r;
        float v = acc[fm][fn][r] + bias;
        if (MODE == 1) v = v / (1.f + __expf(-v));
        out[(size_t)row * NTOT + colp] = f2bf(v);
      }
    }
  }
}

// ---------------------------------------------------------------------------
// fc2 (K=768) gload 2-phase + fused LN2 + residual + T5 setprio.
__global__ __launch_bounds__(512, 4) void gemm_g512_lnfc2(
    const ushort_t* __restrict__ Ab, const ushort_t* __restrict__ W,
    const float* __restrict__ bias, const float* __restrict__ gamma,
    const float* __restrict__ beta, const ushort_t* __restrict__ residb,
    float* __restrict__ outf) {
  const int KTOT = 768;
  __shared__ ushort_t Al[2][4096];
  __shared__ ushort_t Bl[2][6144];
  int t = threadIdx.x;
  int m0 = blockIdx.x * 128;
  int lane = t & 63, wid = t >> 6;
  int wm = wid >> 1, wn = wid & 1;
  int lr = lane & 15, lg = lane >> 4;

  bool stager = (t < 256);
  int sw = (t & 255) >> 6;
  int rloc = lane >> 2;
  int csrc = (lane & 3) ^ ((lane >> 3) & 3);
  int ca = sw * 2, cb = sw * 3;
  const ushort_t* sA0 = Ab + (size_t)(m0 + ca * 16      + rloc) * KTOT + csrc * 8;
  const ushort_t* sA1 = Ab + (size_t)(m0 + ca * 16 + 16 + rloc) * KTOT + csrc * 8;
  const ushort_t* sB0 = W  + (size_t)(cb * 16      + rloc) * KTOT + csrc * 8;
  const ushort_t* sB1 = W  + (size_t)(cb * 16 + 16 + rloc) * KTOT + csrc * 8;
  const ushort_t* sB2 = W  + (size_t)(cb * 16 + 32 + rloc) * KTOT + csrc * 8;

  auto STAGE = [&](int buf, int kt) {
    GLOAD(sA0 + kt, &Al[buf][(ca + 0) * 512]);
    GLOAD(sA1 + kt, &Al[buf][(ca + 1) * 512]);
    GLOAD(sB0 + kt, &Bl[buf][(cb + 0) * 512]);
    GLOAD(sB1 + kt, &Bl[buf][(cb + 1) * 512]);
    GLOAD(sB2 + kt, &Bl[buf][(cb + 2) * 512]);
  };

  int coff = (lg ^ ((lr >> 1) & 3)) * 8;

  f32x4 acc[2][6];
#pragma unroll
  for (int a = 0; a < 2; ++a)
#pragma unroll
    for (int b = 0; b < 6; ++b) acc[a][b] = (f32x4){0.f, 0.f, 0.f, 0.f};

  const int NT = KTOT / 32;
  if (stager) STAGE(0, 0);
  __syncthreads();
  int cur = 0;
  for (int it = 0; it < NT; ++it) {
    if (stager && it + 1 < NT) STAGE(cur ^ 1, (it + 1) * 32);
    short8 af[2], bfv[6];
#pragma unroll
    for (int fm = 0; fm < 2; ++fm)
      af[fm] = *(const short8*)&Al[cur][(wm * 32 + fm * 16 + lr) * 32 + coff];
#pragma unroll
    for (int fn = 0; fn < 6; ++fn)
      bfv[fn] = *(const short8*)&Bl[cur][(wn * 96 + fn * 16 + lr) * 32 + coff];
    __builtin_amdgcn_s_setprio(1);
#pragma unroll
    for (int fm = 0; fm < 2; ++fm)
#pragma unroll
      for (int fn = 0; fn < 6; ++fn)
        acc[fm][fn] = __builtin_amdgcn_mfma_f32_16x16x32_bf16(af[fm], bfv[fn], acc[fm][fn], 0, 0, 0);
    __builtin_amdgcn_s_setprio(0);
    __syncthreads();
    cur ^= 1;
  }

  float* part = (float*)&Bl[0][0];
#pragma unroll
  for (int fm = 0; fm < 2; ++fm) {
#pragma unroll
    for (int r = 0; r < 4; ++r) {
      float s1 = 0.f, s2 = 0.f;
#pragma unroll
      for (int fn = 0; fn < 6; ++fn) {
        int col = wn * 96 + fn * 16 + lr;
        float v = acc[fm][fn][r] + bias[col];
        acc[fm][fn][r] = v;
        s1 += v; s2 += v * v;
      }
#pragma unroll
      for (int off = 1; off < 16; off <<= 1) {
        s1 += __shfl_xor(s1, off);
        s2 += __shfl_xor(s2, off);
      }
      if (lr == 0) {
        int lrow = wm * 32 + fm * 16 + lg * 4 + r;
        part[(wn * 128 + lrow) * 2 + 0] = s1;
        part[(wn * 128 + lrow) * 2 + 1] = s2;
      }
    }
  }
  __syncthreads();
#pragma unroll
  for (int fm = 0; fm < 2; ++fm) {
#pragma unroll
    for (int r = 0; r < 4; ++r) {
      int lrow = wm * 32 + fm * 16 + lg * 4 + r;
      float s1 = part[lrow * 2 + 0] + part[(128 + lrow) * 2 + 0];
      float s2 = part[lrow * 2 + 1] + part[(128 + lrow) * 2 + 1];
      float mean = s1 * (1.f / 192.f);
      float var  = s2 * (1.f / 192.f) - mean * mean;
      float rstd = rsqrtf(fmaxf(var, 0.f) + 1e-5f);
      size_t og = (size_t)(m0 + lrow) * 192;
#pragma unroll
      for (int fn = 0; fn < 6; ++fn) {
        int col = wn * 96 + fn * 16 + lr;
        int colp = (col & ~31) + slot32(col & 31);
        float l = (acc[fm][fn][r] - mean) * rstd * gamma[col] + beta[col];
        outf[og + col] = bf2f(residb[og + colp]) + l;
      }
    }
  }
}

// ---------------------------------------------------------------------------
// Streaming LayerNorm + residual for proj output (perm-aware). (R20 verbatim)
__global__ __launch_bounds__(256) void ln_resid_kernel(
    const ushort_t* __restrict__ pre, const float* __restrict__ residf,
    const float* __restrict__ gamma, const float* __restrict__ beta,
    ushort_t* __restrict__ outb) {
  int m = (blockIdx.x * 256 + threadIdx.x) >> 6;   // row
  int lane = threadIdx.x & 63;
  int c0 = lane, c1 = lane + 64, c2 = lane + 128;
  int s0 = (c0 & ~31) + slot32(c0 & 31);
  int s1c = (c1 & ~31) + slot32(c1 & 31);
  int s2c = (c2 & ~31) + slot32(c2 & 31);
  const ushort_t* p = pre + (size_t)m * 192;
  float v0 = bf2f(p[s0]), v1 = bf2f(p[s1c]), v2 = bf2f(p[s2c]);
  float s1 = v0 + v1 + v2;
  float s2 = v0 * v0 + v1 * v1 + v2 * v2;
#pragma unroll
  for (int o = 1; o < 64; o <<= 1) {
    s1 += __shfl_xor(s1, o);
    s2 += __shfl_xor(s2, o);
  }
  float mean = s1 * (1.f / 192.f);
  float var  = s2 * (1.f / 192.f) - mean * mean;
  float rstd = rsqrtf(fmaxf(var, 0.f) + 1e-5f);
  float l0 = (v0 - mean) * rstd * gamma[c0] + beta[c0];
  float l1 = (v1 - mean) * rstd * gamma[c1] + beta[c1];
  float l2 = (v2 - mean) * rstd * gamma[c2] + beta[c2];
  size_t og = (size_t)img_pos(m) * 192;
  outb[og + s0]  = f2bf(residf[og + c0] + l0);
  outb[og + s1c] = f2bf(residf[og + c1] + l1);
  outb[og + s2c] = f2bf(residf[og + c2] + l2);
}

// ---------------------------------------------------------------------------
// Attention (MFMA) + T5 setprio + T1 XCD-chunked head-adjacent swizzle.
// 1-D grid 12288; idx=(lin&7)*1536+lin/8; win=idx/6, head=idx%6.
__global__ __launch_bounds__(256) void attn_kernel(
    const ushort_t* __restrict__ qkv, const float* __restrict__ logit_scale,
    const float* __restrict__ tab_s, ushort_t* __restrict__ attn_out) {
  __shared__ ushort_t qs[64][40];
  __shared__ ushort_t ksl[64][40];
  __shared__ ushort_t vsl[32][80];
  __shared__ ushort_t ps[64][80];
  __shared__ float tab_l[169];
  int lin = blockIdx.x;                      // 0..12287, 12288%8==0
  int idx = (lin & 7) * 1536 + (lin >> 3);   // xcd-chunked, bijective
  int win = idx / 6, head = idx - win * 6;   // heads of a window adjacent
  int t = threadIdx.x;
  int wi = win & 63;
  int wh0 = (wi >> 3) * 7, ww0 = (wi & 7) * 7;
  size_t base = (size_t)win * 49 * 576 + head * 32;

  for (int u = t; u < 169; u += 256) tab_l[u] = tab_s[head * 169 + u];

  for (int u = t; u < 240; u += 256) {
    int arr = u / 120, v = u - arr * 120;
    int r = 49 + (v >> 3), c4 = (v & 7) << 2;
    ushort_t* p = arr ? &ksl[r][c4] : &qs[r][c4];
    *(ushort4*)p = make_ushort4(0, 0, 0, 0);
  }

  for (int u = t; u < 2048; u += 256) {
    int key = u >> 5, d = u & 31;
    ushort_t val = 0;
    if (key < 49) val = qkv[base + (size_t)key * 576 + 384 + d];
    int kk = key & 31;
    int pc = ((key >> 5) << 5) + 8 * ((kk >> 2) & 3) + 4 * (kk >> 4) + (kk & 3);
    vsl[d][pc] = val;
  }

  float scale = __expf(fminf(logit_scale[head], 4.605170186f));  // ln(100)

  if (t < 196) {
    int r = t >> 2, c = t & 3;
    const ushort_t* qp = qkv + base + (size_t)r * 576 + c * 8;
    ushort4 qa = *(const ushort4*)qp,         qb = *(const ushort4*)(qp + 4);
    ushort4 ka = *(const ushort4*)(qp + 192), kb = *(const ushort4*)(qp + 196);
    float qf[8] = {bf2f(qa.x), bf2f(qa.y), bf2f(qa.z), bf2f(qa.w),
                   bf2f(qb.x), bf2f(qb.y), bf2f(qb.z), bf2f(qb.w)};
    float kf[8] = {bf2f(ka.x), bf2f(ka.y), bf2f(ka.z), bf2f(ka.w),
                   bf2f(kb.x), bf2f(kb.y), bf2f(kb.z), bf2f(kb.w)};
    float sq = 0.f, sk = 0.f;
#pragma unroll
    for (int d = 0; d < 8; ++d) { sq += qf[d] * qf[d]; sk += kf[d] * kf[d]; }
    sq += __shfl_xor(sq, 1); sq += __shfl_xor(sq, 2);
    sk += __shfl_xor(sk, 1); sk += __shfl_xor(sk, 2);
    float rq = scale / fmaxf(sqrtf(sq), 1e-12f);
    float rk = 1.f   / fmaxf(sqrtf(sk), 1e-12f);
    ushort_t* qd = &qs[r][c * 8];
    *(ushort4*)(qd + 0) = make_ushort4(f2bf(qf[0]*rq), f2bf(qf[1]*rq), f2bf(qf[2]*rq), f2bf(qf[3]*rq));
    *(ushort4*)(qd + 4) = make_ushort4(f2bf(qf[4]*rq), f2bf(qf[5]*rq), f2bf(qf[6]*rq), f2bf(qf[7]*rq));
    ushort_t* kd = &ksl[r][c * 8];
    *(ushort4*)(kd + 0) = make_ushort4(f2bf(kf[0]*rk), f2bf(kf[1]*rk), f2bf(kf[2]*rk), f2bf(kf[3]*rk));
    *(ushort4*)(kd + 4) = make_ushort4(f2bf(kf[4]*rk), f2bf(kf[5]*rk), f2bf(kf[6]*rk), f2bf(kf[7]*rk));
  }
  __syncthreads();

  int lane = t & 63, w = t >> 6;
  int lr = lane & 15, lg = lane >> 4;

  short8 aq = *(const short8*)&qs[w * 16 + lr][lg * 8];
  f32x4 acc[4];
  __builtin_amdgcn_s_setprio(1);
#pragma unroll
  for (int fn = 0; fn < 4; ++fn) {
    acc[fn] = (f32x4){0.f, 0.f, 0.f, 0.f};
    short8 bk = *(const short8*)&ksl[fn * 16 + lr][lg * 8];
    acc[fn] = __builtin_amdgcn_mfma_f32_16x16x32_bf16(aq, bk, acc[fn], 0, 0, 0);
  }
  __builtin_amdgcn_s_setprio(0);

  float rsum[4];
#pragma unroll
  for (int r = 0; r < 4; ++r) {
    int row = w * 16 + lg * 4 + r;
    int rd = (row * 9363) >> 16, rm = row - 7 * rd;
    int gr = region3(wh0 + rd) * 3 + region3(ww0 + rm);
    bool rv = row < 49;
    float sv[4];
#pragma unroll
    for (int fn = 0; fn < 4; ++fn) {
      int col = fn * 16 + lr;
      int jd = (col * 9363) >> 16, jm = col - 7 * jd;
      int gj = region3(wh0 + jd) * 3 + region3(ww0 + jm);
      bool cv = rv && (col < 49);
      int idx2 = cv ? (rd - jd + 6) * 13 + (rm - jm + 6) : 0;
      float s = acc[fn][r] + tab_l[idx2] + (gr == gj ? 0.f : -100.f);
      sv[fn] = cv ? s : -1e30f;
    }
    float m = fmaxf(fmaxf(sv[0], sv[1]), fmaxf(sv[2], sv[3]));
#pragma unroll
    for (int o = 1; o < 16; o <<= 1) m = fmaxf(m, __shfl_xor(m, o));
    float sum = 0.f;
#pragma unroll
    for (int fn = 0; fn < 4; ++fn) {
      float e = __expf(sv[fn] - m);
      sum += e;
      int pc = ((fn >> 1) << 5) + 8 * (lr >> 2) + ((fn & 1) << 2) + (lr & 3);
      ps[row][pc] = f2bf(e);
    }
#pragma unroll
    for (int o = 1; o < 16; o <<= 1) sum += __shfl_xor(sum, o);
    rsum[r] = 1.f / sum;
  }
  __syncthreads();

  short8 ap0 = *(const short8*)&ps[w * 16 + lr][lg * 8];
  short8 ap1 = *(const short8*)&ps[w * 16 + lr][32 + lg * 8];
  f32x4 o2[2];
  __builtin_amdgcn_s_setprio(1);
#pragma unroll
  for (int f = 0; f < 2; ++f) {
    o2[f] = (f32x4){0.f, 0.f, 0.f, 0.f};
    short8 bv0 = *(const short8*)&vsl[f * 16 + lr][lg * 8];
    short8 bv1 = *(const short8*)&vsl[f * 16 + lr][32 + lg * 8];
    o2[f] = __builtin_amdgcn_mfma_f32_16x16x32_bf16(ap0, bv0, o2[f], 0, 0, 0);
    o2[f] = __builtin_amdgcn_mfma_f32_16x16x32_bf16(ap1, bv1, o2[f], 0, 0, 0);
  }
  __builtin_amdgcn_s_setprio(0);
#pragma unroll
  for (int f = 0; f < 2; ++f) {
#pragma unroll
    for (int r = 0; r < 4; ++r) {
      int row = w * 16 + lg * 4 + r;
      if (row < 49)
        attn_out[((size_t)win * 49 + row) * 192 + head * 32 + f * 16 + lr] =
            f2bf(o2[f][r] * rsum[r]);
    }
  }
}

// ---------------------------------------------------------------------------
extern "C" void kernel_launch(void* const* d_in, const int* in_sizes, int n_in,
                              void* d_out, int out_size, void* d_ws, size_t ws_size,
                              hipStream_t stream) {
  (void)in_sizes; (void)n_in; (void)out_size; (void)ws_size;
  const float* x    = (const float*)d_in[0];
  const float* qkvw = (const float*)d_in[1];
  const float* qb   = (const float*)d_in[2];
  const float* vb   = (const float*)d_in[3];
  const float* ls   = (const float*)d_in[4];
  const float* cw1  = (const float*)d_in[5];
  const float* cb1  = (const float*)d_in[6];
  const float* cw2  = (const float*)d_in[7];
  const float* pw   = (const float*)d_in[8];
  const float* pb   = (const float*)d_in[9];
  const float* n1g  = (const float*)d_in[10];
  const float* n1b  = (const float*)d_in[11];
  const float* n2g  = (const float*)d_in[12];
  const float* n2b  = (const float*)d_in[13];
  const float* f1w  = (const float*)d_in[14];
  const float* f1b  = (const float*)d_in[15];
  const float* f2w  = (const float*)d_in[16];
  const float* f2b  = (const float*)d_in[17];
  float* out = (float*)d_out;

  char* ws = (char*)d_ws;
  ushort_t* wq_bf = (ushort_t*)ws;                 // 110592 (perm K=192)
  ushort_t* wp_bf = wq_bf + 110592;                // 36864  (perm K=192)
  ushort_t* w1_bf = wp_bf + 36864;                 // 147456 (perm K=192)
  ushort_t* w2_bf = w1_bf + 147456;                // 147456 (perm K=768)
  float*    tab_s = (float*)(w2_bf + 147456);      // 6*169 floats
  const size_t OFF_BIG = 1 << 20;
  ushort_t* qkv_out = (ushort_t*)(ws + OFF_BIG);
  ushort_t* xw_bf   = (ushort_t*)(ws + OFF_BIG + 115605504);
  ushort_t* attn_o  = (ushort_t*)(ws + OFF_BIG + 115605504);
  ushort_t* x1_bf   = (ushort_t*)(ws + OFF_BIG + 154140672);
  ushort_t* hmid    = (ushort_t*)(ws + OFF_BIG);   // 100352*768 bf16 over R1+R2

  cvt_perm_all<<<1728, 256, 0, stream>>>(qkvw, pw, f1w, f2w, wq_bf, wp_bf, w1_bf, w2_bf);
  cpb_kernel<<<169, 256, 0, stream>>>(cw1, cb1, cw2, tab_s);
  gather_cvt_kernel<<<9408, 256, 0, stream>>>(x, xw_bf);

  // qkv (p3 pipeline + setprio + XCD swizzle, y-fastest)
  gemm_p3<192, 0, 3><<<2352, 512, 0, stream>>>(xw_bf, wq_bf, qb, vb, qkv_out, 576);
  // attention (+ setprio + XCD head-adjacent swizzle)
  attn_kernel<<<12288, 256, 0, stream>>>(qkv_out, ls, tab_s, attn_o);
  // proj (pre-LN, in-place over attn_o) + perm-aware LN1/residual
  gemm_g512<192, 2><<<dim3(784, 1), 512, 0, stream>>>(attn_o, wp_bf, pb, nullptr, attn_o, 192);
  ln_resid_kernel<<<25088, 256, 0, stream>>>(attn_o, x, n1g, n1b, x1_bf);
  // fc1 (silu, p3 pipeline + setprio + XCD swizzle, y-fastest)
  gemm_p3<192, 1, 4><<<3136, 512, 0, stream>>>(x1_bf, w1_bf, f1b, nullptr, hmid, 768);
  // fc2 + LN2 + residual fused -> d_out fp32 (+ setprio)
  gemm_g512_lnfc2<<<784, 512, 0, stream>>>(hmid, w2_bf, f2b, n2g, n2b, x1_bf, out);
}